// Round 8
// baseline (3061.459 us; speedup 1.0000x reference)
//
#include <hip/hip_runtime.h>
#include <hip/hip_bf16.h>

typedef __hip_bfloat16 bf16;
typedef unsigned char u8;
typedef __attribute__((ext_vector_type(8))) short short8;
typedef __attribute__((ext_vector_type(16))) float f32x16;
#define DI __device__ __forceinline__

union BF8 { int4 v; short8 s; bf16 h[8]; };
union BF4 { unsigned long long u; bf16 h[4]; };

// ws layout (bytes):
// phase A (xpose/proj/attn):
//   Xt bf16 [2][128 b][1024 pos][128 ic]   @ 0            (67,108,864)
//   projchunk bf16 [6][128][32][1024]      @ 67,108,864   (50,331,648)
//   cA bf16 [128][256][1024]               @ 117,440,512  (67,108,864)
//   cB u8   [128][256][1024]               @ 184,549,376  (33,554,432)  ends 218,103,808
//   wproj bf16 [6][128][128]               @ 218,103,808  (196,608)
// phase B (transpose): cAT bf16 @ 0 (67,108,864), cBT u8 @ 67,108,864 (33,554,432)
// phase C (convs): x3 @100,663,296  x5 @134,217,728  x7 @167,772,160  x1 @201,326,592
// parts f32 @ 234,881,024 (32 KB)
// wb3/wb5/wb7 bf16 [tap][64 icg][128 oc][8 ic] @ 234,913,792 / 236,093,440 / 239,370,240
// wb1 bf16 [64 icg][128 oc][8 ic] @ 245,792,768  (end 245,923,840)

// ---------------------------------------------------------------- weight prep
__global__ __launch_bounds__(256) void prep_w_kernel(
    const float* __restrict__ w3, const float* __restrict__ w5,
    const float* __restrict__ w7, const float* __restrict__ w1,
    const float* __restrict__ wq_st, const float* __restrict__ wk_st,
    const float* __restrict__ wv_st, const float* __restrict__ wq_phy,
    const float* __restrict__ wk_phy, const float* __restrict__ wv_phy,
    bf16* __restrict__ wb3, bf16* __restrict__ wb5,
    bf16* __restrict__ wb7, bf16* __restrict__ wb1, bf16* __restrict__ wp)
{
  const int N3 = 9 * 65536, N5 = 25 * 65536, N7 = 49 * 65536, N1 = 65536;
  const int NP = 6 * 16384;
  const int total = N3 + N5 + N7 + N1 + NP;
  for (int i = blockIdx.x * 256 + threadIdx.x; i < total; i += gridDim.x * 256) {
    if (i < N3) {
      int tap = i >> 16, rem = i & 65535;
      int icg = rem >> 10, oc = (rem >> 3) & 127, j = rem & 7;
      wb3[i] = __float2bfloat16(w3[(size_t)(oc * 512 + icg * 8 + j) * 9 + tap]);
    } else if (i < N3 + N5) {
      int k = i - N3; int tap = k >> 16, rem = k & 65535;
      int icg = rem >> 10, oc = (rem >> 3) & 127, j = rem & 7;
      wb5[k] = __float2bfloat16(w5[(size_t)(oc * 512 + icg * 8 + j) * 25 + tap]);
    } else if (i < N3 + N5 + N7) {
      int k = i - N3 - N5; int tap = k >> 16, rem = k & 65535;
      int icg = rem >> 10, oc = (rem >> 3) & 127, j = rem & 7;
      wb7[k] = __float2bfloat16(w7[(size_t)(oc * 512 + icg * 8 + j) * 49 + tap]);
    } else if (i < N3 + N5 + N7 + N1) {
      int k = i - N3 - N5 - N7;
      int icg = k >> 10, oc = (k >> 3) & 127, j = k & 7;
      wb1[k] = __float2bfloat16(w1[(size_t)oc * 512 + icg * 8 + j]);
    } else {
      int k = i - N3 - N5 - N7 - N1;
      int m = k >> 14, r = k & 16383;
      float v;
      switch (m) {
        case 0: v = wq_st[r]; break;
        case 1: v = wk_st[r]; break;
        case 2: v = wv_st[r]; break;
        case 3: v = wq_phy[r]; break;
        case 4: v = wk_phy[r]; break;
        default: v = wv_phy[r]; break;
      }
      wp[k] = __float2bfloat16(v);
    }
  }
}

// ---------------------------------------------------------------- input transpose
__global__ __launch_bounds__(256) void xpose_in_kernel(
    const float* __restrict__ st, const float* __restrict__ phy,
    bf16* __restrict__ Xt)
{
  __shared__ __align__(16) short Tb[64 * 72];
  const int x = blockIdx.x, b = blockIdx.y;
  const int t = x >> 5, rem = x & 31;
  const int ict = rem >> 4, post = rem & 15;
  const int ic0 = ict * 64, pos0 = post * 64;
  const int tid = threadIdx.x;
  const int rowi = tid >> 2, sub = tid & 3;
  const float* X = t ? phy : st;

  const float* src = X + ((size_t)b * 128 + ic0 + rowi) * 1024 + pos0 + sub * 16;
  #pragma unroll
  for (int q = 0; q < 4; ++q) {
    float4 v = *(const float4*)(src + q * 4);
    BF4 pk;
    pk.h[0] = __float2bfloat16(v.x); pk.h[1] = __float2bfloat16(v.y);
    pk.h[2] = __float2bfloat16(v.z); pk.h[3] = __float2bfloat16(v.w);
    *(unsigned long long*)&Tb[rowi * 72 + sub * 16 + q * 4] = pk.u;
  }
  __syncthreads();
  short tmp[16];
  #pragma unroll
  for (int j = 0; j < 16; ++j) tmp[j] = Tb[(sub * 16 + j) * 72 + rowi];
  bf16* dst = Xt + (((size_t)t * 128 + b) * 1024 + pos0 + rowi) * 128 + ic0 + sub * 16;
  *(int4*)dst       = ((int4*)tmp)[0];
  *(int4*)(dst + 8) = ((int4*)tmp)[1];
}

// ---------------------------------------------------------------- MFMA projections (32-ch chunk)
__global__ __launch_bounds__(256) void proj_mfma(
    const bf16* __restrict__ Xt, const bf16* __restrict__ wproj,
    const float* __restrict__ b0, const float* __restrict__ b1,
    const float* __restrict__ b2, const float* __restrict__ b3,
    const float* __restrict__ b4, const float* __restrict__ b5,
    bf16* __restrict__ pc, int cb)
{
  const int pt = blockIdx.x, b = blockIdx.y;
  const int tid = threadIdx.x, wave = tid >> 6, lane = tid & 63;
  const int col = lane & 31, kg = lane >> 5;
  const int pos = pt * 128 + wave * 32 + col;

  f32x16 acc[6];
  #pragma unroll
  for (int m = 0; m < 6; ++m)
    #pragma unroll
    for (int e = 0; e < 16; ++e) acc[m][e] = 0.f;

  const bf16* xst = Xt + ((size_t)b * 1024 + pos) * 128 + kg * 8;
  const bf16* xph = xst + (size_t)128 * 1024 * 128;
  const bf16* wl = wproj + (size_t)(cb + col) * 128 + kg * 8;

  #pragma unroll
  for (int kst = 0; kst < 8; ++kst) {
    short8 bst = *(const short8*)&xst[kst * 16];
    short8 bph = *(const short8*)&xph[kst * 16];
    #pragma unroll
    for (int m = 0; m < 6; ++m) {
      BF8 a; a.v = *(const int4*)&wl[(size_t)m * 16384 + kst * 16];
      acc[m] = __builtin_amdgcn_mfma_f32_32x32x16_bf16(a.s, m < 3 ? bst : bph, acc[m], 0, 0, 0);
    }
  }
  const float* biases[6] = { b0, b1, b2, b3, b4, b5 };
  #pragma unroll
  for (int m = 0; m < 6; ++m) {
    #pragma unroll
    for (int r = 0; r < 16; ++r) {
      const int ocl = (r & 3) + 8 * (r >> 2) + 4 * kg;
      float v = acc[m][r] + biases[m][cb + ocl];
      pc[(((size_t)m * 128 + b) * 32 + ocl) * 1024 + pos] = __float2bfloat16(v);
    }
  }
}

// ---------------------------------------------------------------- attention helpers (bf16 LDS)
DI void mm32b(const bf16* A, const bf16* Bm, float acc[4][4], int r0, int c0)
{
  #pragma unroll 4
  for (int w = 0; w < 32; ++w) {
    BF4 qa, kb;
    qa.u = *(const unsigned long long*)(A + w * 40 + r0);
    kb.u = *(const unsigned long long*)(Bm + w * 40 + c0);
    float qv[4], kv[4];
    #pragma unroll
    for (int j = 0; j < 4; ++j) {
      qv[j] = __bfloat162float(qa.h[j]);
      kv[j] = __bfloat162float(kb.h[j]);
    }
    #pragma unroll
    for (int i = 0; i < 4; ++i)
      #pragma unroll
      for (int j = 0; j < 4; ++j)
        acc[i][j] = fmaf(qv[i], kv[j], acc[i][j]);
  }
}

DI void softmax4(float acc[4][4])
{
  #pragma unroll
  for (int i = 0; i < 4; ++i) {
    float m = fmaxf(fmaxf(acc[i][0], acc[i][1]), fmaxf(acc[i][2], acc[i][3]));
    m = fmaxf(m, __shfl_xor(m, 1));
    m = fmaxf(m, __shfl_xor(m, 2));
    m = fmaxf(m, __shfl_xor(m, 4));
    float s = 0.f;
    #pragma unroll
    for (int j = 0; j < 4; ++j) { acc[i][j] = __expf(acc[i][j] - m); s += acc[i][j]; }
    s += __shfl_xor(s, 1); s += __shfl_xor(s, 2); s += __shfl_xor(s, 4);
    float rs = 1.0f / s;
    #pragma unroll
    for (int j = 0; j < 4; ++j) acc[i][j] *= rs;
  }
}

template<bool U8OUT>
DI void attn_one(const bf16* Qt, const bf16* K, const bf16* V, bf16 (*At)[40],
                 const float* resid, void* outp, int r0, int c0)
{
  float acc[4][4] = {};
  mm32b(Qt, K, acc, r0, c0);
  softmax4(acc);
  __syncthreads();
  #pragma unroll
  for (int j = 0; j < 4; ++j) {
    BF4 pk;
    #pragma unroll
    for (int i = 0; i < 4; ++i) pk.h[i] = __float2bfloat16(acc[i][j]);
    *(unsigned long long*)&At[c0 + j][r0] = pk.u;
  }
  __syncthreads();
  float o[4][4] = {};
  mm32b(&At[0][0], V, o, r0, c0);
  softmax4(o);
  if constexpr (!U8OUT) {
    bf16* op = (bf16*)outp;
    if (resid) {
      #pragma unroll
      for (int i = 0; i < 4; ++i) {
        float4 rv = *(const float4*)&resid[(r0 + i) * 32 + c0];
        o[i][0] += rv.x; o[i][1] += rv.y; o[i][2] += rv.z; o[i][3] += rv.w;
      }
    }
    #pragma unroll
    for (int i = 0; i < 4; ++i) {
      BF4 pk;
      #pragma unroll
      for (int j = 0; j < 4; ++j) pk.h[j] = __float2bfloat16(o[i][j]);
      *(unsigned long long*)&op[(r0 + i) * 32 + c0] = pk.u;
    }
  } else {
    u8* op = (u8*)outp;
    #pragma unroll
    for (int i = 0; i < 4; ++i) {
      unsigned pk = 0;
      #pragma unroll
      for (int j = 0; j < 4; ++j) {
        unsigned bv = (unsigned)fminf(o[i][j] * 256.f + 0.5f, 255.f);
        pk |= bv << (8 * j);
      }
      *(unsigned*)&op[(r0 + i) * 32 + c0] = pk;
    }
  }
}

// ---------------------------------------------------------------- attention (32-ch chunk)
__global__ __launch_bounds__(64) void attn_chunk_kernel(
    const bf16* __restrict__ pc,
    const float* __restrict__ st, const float* __restrict__ phy,
    bf16* __restrict__ cA, u8* __restrict__ cB, int cb)
{
  __shared__ __align__(16) bf16 Qst[32][40], Qph[32][40];
  __shared__ __align__(16) bf16 Kst[32][40], Kph[32][40];
  __shared__ __align__(16) bf16 Vst[32][40], Vph[32][40];
  __shared__ __align__(16) bf16 At[32][40];
  const int cl = blockIdx.x, b = blockIdx.y;
  const int c = cb + cl;
  const int lane = threadIdx.x;
  const size_t mstride = (size_t)128 * 32 * 1024;
  const bf16* p0 = pc + ((size_t)b * 32 + cl) * 1024;
  const size_t bc = ((size_t)b * 128 + c) * 1024;

  #pragma unroll
  for (int it = 0; it < 2; ++it) {
    int e8 = (it * 64 + lane) * 8;
    int h = e8 >> 5, w0 = e8 & 31;
    BF8 q1, k1, v1, q2, k2, v2;
    q1.v = *(const int4*)&p0[e8];
    k1.v = *(const int4*)&p0[mstride + e8];
    v1.v = *(const int4*)&p0[2 * mstride + e8];
    q2.v = *(const int4*)&p0[3 * mstride + e8];
    k2.v = *(const int4*)&p0[4 * mstride + e8];
    v2.v = *(const int4*)&p0[5 * mstride + e8];
    *(int4*)&Kst[h][w0] = k1.v;
    *(int4*)&Vst[h][w0] = v1.v;
    *(int4*)&Kph[h][w0] = k2.v;
    *(int4*)&Vph[h][w0] = v2.v;
    #pragma unroll
    for (int j = 0; j < 8; ++j) {
      Qst[w0 + j][h] = q1.h[j];
      Qph[w0 + j][h] = q2.h[j];
    }
  }
  __syncthreads();
  const int r0 = (lane >> 3) * 4, c0 = (lane & 7) * 4;
  bf16* aA = cA + (size_t)b * 256 * 1024 + (size_t)c * 1024;
  u8*   aB = cB + (size_t)b * 256 * 1024 + (size_t)c * 1024;

  attn_one<false>(&Qst[0][0], &Kst[0][0], &Vst[0][0], At, st + bc,  aA,              r0, c0);
  attn_one<false>(&Qph[0][0], &Kph[0][0], &Vph[0][0], At, phy + bc, aA + 128 * 1024, r0, c0);
  attn_one<true >(&Qph[0][0], &Kst[0][0], &Vst[0][0], At, nullptr,  aB,              r0, c0);
  attn_one<true >(&Qst[0][0], &Kph[0][0], &Vph[0][0], At, nullptr,  aB + 128 * 1024, r0, c0);
}

// ---------------------------------------------------------------- concat transpose -> [b][pos][ch]
__global__ __launch_bounds__(256) void transpose_kernel(
    const bf16* __restrict__ cA, const u8* __restrict__ cB,
    bf16* __restrict__ cAT, u8* __restrict__ cBT)
{
  __shared__ __align__(16) short Tb[64 * 72];
  __shared__ __align__(16) u8 T8[64 * 80];
  const int x = blockIdx.x, b = blockIdx.y;
  const int cht = x >> 4, post = x & 15;
  const int pos0 = post * 64;
  const int tid = threadIdx.x;
  const int rowi = tid >> 2, sub = tid & 3;

  if (cht < 4) {
    const int ch0 = cht * 64;
    const bf16* src = cA + ((size_t)b * 256 + ch0 + rowi) * 1024 + pos0 + sub * 16;
    *(int4*)&Tb[rowi * 72 + sub * 16]     = *(const int4*)src;
    *(int4*)&Tb[rowi * 72 + sub * 16 + 8] = *(const int4*)(src + 8);
    __syncthreads();
    short tmp[16];
    #pragma unroll
    for (int j = 0; j < 16; ++j) tmp[j] = Tb[(sub * 16 + j) * 72 + rowi];
    bf16* dst = cAT + ((size_t)b * 1024 + pos0 + rowi) * 256 + ch0 + sub * 16;
    *(int4*)dst       = ((int4*)tmp)[0];
    *(int4*)(dst + 8) = ((int4*)tmp)[1];
  } else {
    const int ch0 = (cht - 4) * 64;
    const u8* src = cB + ((size_t)b * 256 + ch0 + rowi) * 1024 + pos0 + sub * 16;
    *(int4*)&T8[rowi * 80 + sub * 16] = *(const int4*)src;
    __syncthreads();
    u8 tmp[16];
    #pragma unroll
    for (int j = 0; j < 16; ++j) tmp[j] = T8[(sub * 16 + j) * 80 + rowi];
    u8* dst = cBT + ((size_t)b * 1024 + pos0 + rowi) * 256 + ch0 + sub * 16;
    *(int4*)dst = *(int4*)tmp;
  }
}

// ---------------------------------------------------------------- staging helper
template<int PCX, int NIT, int H0>
DI void stage_tile(const bf16* cAT, const u8* cBT, short* Xs,
                   int b, int r0, int ic0, int tid)
{
  for (int e = tid; e < NIT; e += 256) {
    int i = e / (PCX * 4);
    int rem = e - i * (PCX * 4);
    int cx = rem >> 2, part = rem & 3;
    int ir = r0 - H0 + i, c = cx - H0;
    int4 val = make_int4(0, 0, 0, 0);
    if ((unsigned)ir < 32u && (unsigned)c < 32u) {
      size_t pbase = ((size_t)b * 1024 + ir * 32 + c) * 256;
      if (ic0 < 256) {
        val = *(const int4*)&cAT[pbase + ic0 + part * 8];
      } else {
        unsigned long long u = *(const unsigned long long*)&cBT[pbase + (ic0 - 256) + part * 8];
        BF8 t;
        #pragma unroll
        for (int j = 0; j < 8; ++j)
          t.h[j] = __float2bfloat16((float)((u >> (8 * j)) & 255u) * 0.00390625f);
        val = t.v;
      }
    }
    *(int4*)&Xs[(i * PCX + cx) * 40 + part * 8] = val;
  }
}

// ---------------------------------------------------------------- MFMA conv, ob=2 (KS=1,3)
// 2 blocks/CU, grid (4, b): block = 64 oc x 16 rows.
template<int KS>
__global__ __launch_bounds__(256, 2) void conv_mfma(
    const bf16* __restrict__ cAT, const u8* __restrict__ cBT,
    const bf16* __restrict__ wt, const float* __restrict__ bias,
    bf16* __restrict__ xout, float* __restrict__ partials)
{
  constexpr int H0 = KS / 2;
  constexpr int PCX = 32 + 2 * H0;
  constexpr int ROWS = 16 + 2 * H0;
  constexpr int NIT = ROWS * PCX * 4;
  __shared__ __align__(16) short Xs[ROWS * PCX * 40];
  __shared__ float rs[256], rq[256];
  const int tix = blockIdx.x, b = blockIdx.y;
  const int ot = tix >> 1, rt = tix & 1;
  const int oc0 = ot * 64, r0 = rt * 16;
  const int tid = threadIdx.x;
  const int wv = tid >> 6, lane = tid & 63;
  const int col = lane & 31, kg = lane >> 5;

  f32x16 acc[2][4];
  #pragma unroll
  for (int i = 0; i < 2; ++i)
    #pragma unroll
    for (int j = 0; j < 4; ++j)
      #pragma unroll
      for (int e = 0; e < 16; ++e) acc[i][j][e] = 0.f;

  for (int cc = 0; cc < 16; ++cc) {
    const int ic0 = cc * 32;
    stage_tile<PCX, NIT, H0>(cAT, cBT, Xs, b, r0, ic0, tid);
    __syncthreads();

    #pragma unroll 1
    for (int ky = 0; ky < KS; ++ky) {
      #pragma unroll
      for (int kx = 0; kx < KS; ++kx) {
        const int tap = ky * KS + kx;
        BF8 a[2][2];
        #pragma unroll
        for (int ob = 0; ob < 2; ++ob)
          #pragma unroll
          for (int kt = 0; kt < 2; ++kt) {
            int icg = cc * 4 + kt * 2 + kg;
            a[ob][kt].v = *(const int4*)&wt[(((size_t)tap * 64 + icg) * 128 + oc0 + ob * 32 + col) * 8];
          }
        #pragma unroll
        for (int rr = 0; rr < 4; ++rr) {
          int entry = ((wv * 4 + rr + ky) * PCX + col + kx) * 40;
          #pragma unroll
          for (int kt = 0; kt < 2; ++kt) {
            short8 bf = *(const short8*)&Xs[entry + (kt * 2 + kg) * 8];
            acc[0][rr] = __builtin_amdgcn_mfma_f32_32x32x16_bf16(a[0][kt].s, bf, acc[0][rr], 0, 0, 0);
            acc[1][rr] = __builtin_amdgcn_mfma_f32_32x32x16_bf16(a[1][kt].s, bf, acc[1][rr], 0, 0, 0);
          }
        }
      }
    }
    __syncthreads();
  }

  float lsum = 0.f, lsq = 0.f;
  #pragma unroll
  for (int ob = 0; ob < 2; ++ob)
    #pragma unroll
    for (int rr = 0; rr < 4; ++rr) {
      const int row = r0 + wv * 4 + rr;
      #pragma unroll
      for (int r = 0; r < 16; ++r) {
        const int oc = oc0 + ob * 32 + (r & 3) + 8 * (r >> 2) + 4 * kg;
        float v = acc[ob][rr][r];
        if (bias) v += bias[oc];
        xout[((size_t)b * 128 + oc) * 1024 + row * 32 + col] = __float2bfloat16(v);
        lsum += v; lsq += v * v;
      }
    }
  rs[tid] = lsum; rq[tid] = lsq;
  __syncthreads();
  for (int s = 128; s > 0; s >>= 1) {
    if (tid < s) { rs[tid] += rs[tid + s]; rq[tid] += rq[tid + s]; }
    __syncthreads();
  }
  if (tid == 0) {
    partials[((size_t)b * 4 + tix) * 2]     = rs[0];
    partials[((size_t)b * 4 + tix) * 2 + 1] = rq[0];
  }
}

// ---------------------------------------------------------------- MFMA conv, ob=4 (KS=5,7)
// 1 block/CU (256 VGPR acc), grid (2, b): block = 128 oc x 16 rows.
// Halves LDS B-fragment traffic per MFMA vs ob=2 (B reused 4x).
template<int KS>
__global__ __launch_bounds__(256, 1) void conv_mfma4(
    const bf16* __restrict__ cAT, const u8* __restrict__ cBT,
    const bf16* __restrict__ wt, bf16* __restrict__ xout,
    float* __restrict__ partials)
{
  constexpr int H0 = KS / 2;
  constexpr int PCX = 32 + 2 * H0;
  constexpr int ROWS = 16 + 2 * H0;
  constexpr int NIT = ROWS * PCX * 4;
  __shared__ __align__(16) short Xs[ROWS * PCX * 40];
  __shared__ float rs[256], rq[256];
  const int rt = blockIdx.x, b = blockIdx.y;
  const int r0 = rt * 16;
  const int tid = threadIdx.x;
  const int wv = tid >> 6, lane = tid & 63;
  const int col = lane & 31, kg = lane >> 5;

  f32x16 acc[4][4];   // [ob][rr] = 256 VGPR
  #pragma unroll
  for (int i = 0; i < 4; ++i)
    #pragma unroll
    for (int j = 0; j < 4; ++j)
      #pragma unroll
      for (int e = 0; e < 16; ++e) acc[i][j][e] = 0.f;

  for (int cc = 0; cc < 16; ++cc) {
    const int ic0 = cc * 32;
    stage_tile<PCX, NIT, H0>(cAT, cBT, Xs, b, r0, ic0, tid);
    __syncthreads();

    #pragma unroll 1
    for (int ky = 0; ky < KS; ++ky) {
      #pragma unroll 1
      for (int kx = 0; kx < KS; ++kx) {
        const int tap = ky * KS + kx;
        BF8 a[4][2];
        #pragma unroll
        for (int ob = 0; ob < 4; ++ob)
          #pragma unroll
          for (int kt = 0; kt < 2; ++kt) {
            int icg = cc * 4 + kt * 2 + kg;
            a[ob][kt].v = *(const int4*)&wt[(((size_t)tap * 64 + icg) * 128 + ob * 32 + col) * 8];
          }
        #pragma unroll
        for (int rr = 0; rr < 4; ++rr) {
          int entry = ((wv * 4 + rr + ky) * PCX + col + kx) * 40;
          #pragma unroll
          for (int kt = 0; kt < 2; ++kt) {
            short8 bf = *(const short8*)&Xs[entry + (kt * 2 + kg) * 8];
            acc[0][rr] = __builtin_amdgcn_mfma_f32_32x32x16_bf16(a[0][kt].s, bf, acc[0][rr], 0, 0, 0);
            acc[1][rr] = __builtin_amdgcn_mfma_f32_32x32x16_bf16(a[1][kt].s, bf, acc[1][rr], 0, 0, 0);
            acc[2][rr] = __builtin_amdgcn_mfma_f32_32x32x16_bf16(a[2][kt].s, bf, acc[2][rr], 0, 0, 0);
            acc[3][rr] = __builtin_amdgcn_mfma_f32_32x32x16_bf16(a[3][kt].s, bf, acc[3][rr], 0, 0, 0);
          }
        }
      }
    }
    __syncthreads();
  }

  float lsum = 0.f, lsq = 0.f;
  #pragma unroll
  for (int ob = 0; ob < 4; ++ob)
    #pragma unroll
    for (int rr = 0; rr < 4; ++rr) {
      const int row = r0 + wv * 4 + rr;
      #pragma unroll
      for (int r = 0; r < 16; ++r) {
        const int oc = ob * 32 + (r & 3) + 8 * (r >> 2) + 4 * kg;
        float v = acc[ob][rr][r];
        xout[((size_t)b * 128 + oc) * 1024 + row * 32 + col] = __float2bfloat16(v);
        lsum += v; lsq += v * v;
      }
    }
  rs[tid] = lsum; rq[tid] = lsq;
  __syncthreads();
  for (int s = 128; s > 0; s >>= 1) {
    if (tid < s) { rs[tid] += rs[tid + s]; rq[tid] += rq[tid + s]; }
    __syncthreads();
  }
  if (tid == 0) {
    partials[((size_t)b * 2 + rt) * 2]     = rs[0];
    partials[((size_t)b * 2 + rt) * 2 + 1] = rq[0];
  }
}

// ---------------------------------------------------------------- LN + combine
// p3/p1: 4 partials per batch; p5/p7: 2 partials per batch.
__global__ __launch_bounds__(256) void final_kernel(
    const bf16* __restrict__ x3, const bf16* __restrict__ x5,
    const bf16* __restrict__ x7, const bf16* __restrict__ x1c,
    const float* __restrict__ p3, const float* __restrict__ p5,
    const float* __restrict__ p7, const float* __restrict__ p1,
    const float* __restrict__ g3, const float* __restrict__ be3,
    const float* __restrict__ g5, const float* __restrict__ be5,
    const float* __restrict__ g7, const float* __restrict__ be7,
    const float* __restrict__ g1, const float* __restrict__ be1,
    float* __restrict__ out)
{
  const int blk = blockIdx.x, b = blockIdx.y, tid = threadIdx.x;
  float s3 = 0, q3 = 0, s5 = 0, q5 = 0, s7 = 0, q7 = 0, s1 = 0, q1 = 0;
  #pragma unroll
  for (int i = 0; i < 4; ++i) {
    int o = (b * 4 + i) * 2;
    s3 += p3[o]; q3 += p3[o + 1];
    s1 += p1[o]; q1 += p1[o + 1];
  }
  #pragma unroll
  for (int i = 0; i < 2; ++i) {
    int o = (b * 2 + i) * 2;
    s5 += p5[o]; q5 += p5[o + 1];
    s7 += p7[o]; q7 += p7[o + 1];
  }
  const float inv = 1.0f / 131072.0f;
  float mu3 = s3 * inv, r3 = rsqrtf(fmaxf(q3 * inv - mu3 * mu3, 0.f) + 1e-5f);
  float mu5 = s5 * inv, r5 = rsqrtf(fmaxf(q5 * inv - mu5 * mu5, 0.f) + 1e-5f);
  float mu7 = s7 * inv, r7 = rsqrtf(fmaxf(q7 * inv - mu7 * mu7, 0.f) + 1e-5f);
  float mu1 = s1 * inv, r1 = rsqrtf(fmaxf(q1 * inv - mu1 * mu1, 0.f) + 1e-5f);
  const size_t bb = (size_t)b * 131072;
  for (int it = 0; it < 8; ++it) {
    int e0 = (it * 2048 + blk * 256 + tid) * 8;
    BF8 a3, a5, a7, a1;
    a3.v = *(const int4*)&x3[bb + e0];
    a5.v = *(const int4*)&x5[bb + e0];
    a7.v = *(const int4*)&x7[bb + e0];
    a1.v = *(const int4*)&x1c[bb + e0];
    float G3[8], B3[8], G5[8], B5[8], G7[8], B7[8], G1[8], B1[8];
    *(float4*)&G3[0] = *(const float4*)&g3[e0];  *(float4*)&G3[4] = *(const float4*)&g3[e0 + 4];
    *(float4*)&B3[0] = *(const float4*)&be3[e0]; *(float4*)&B3[4] = *(const float4*)&be3[e0 + 4];
    *(float4*)&G5[0] = *(const float4*)&g5[e0];  *(float4*)&G5[4] = *(const float4*)&g5[e0 + 4];
    *(float4*)&B5[0] = *(const float4*)&be5[e0]; *(float4*)&B5[4] = *(const float4*)&be5[e0 + 4];
    *(float4*)&G7[0] = *(const float4*)&g7[e0];  *(float4*)&G7[4] = *(const float4*)&g7[e0 + 4];
    *(float4*)&B7[0] = *(const float4*)&be7[e0]; *(float4*)&B7[4] = *(const float4*)&be7[e0 + 4];
    *(float4*)&G1[0] = *(const float4*)&g1[e0];  *(float4*)&G1[4] = *(const float4*)&g1[e0 + 4];
    *(float4*)&B1[0] = *(const float4*)&be1[e0]; *(float4*)&B1[4] = *(const float4*)&be1[e0 + 4];
    float res[8];
    #pragma unroll
    for (int j = 0; j < 8; ++j) {
      float v3 = (__bfloat162float(a3.h[j]) - mu3) * r3 * G3[j] + B3[j];
      float v5 = (__bfloat162float(a5.h[j]) - mu5) * r5 * G5[j] + B5[j];
      float v7 = (__bfloat162float(a7.h[j]) - mu7) * r7 * G7[j] + B7[j];
      float m = (v3 + v5 + v7) * (1.0f / 3.0f);
      float sg = 1.0f / (1.0f + __expf(-m));
      float v1 = (__bfloat162float(a1.h[j]) - mu1) * r1 * G1[j] + B1[j];
      res[j] = sg + v1;
    }
    *(float4*)&out[bb + e0]     = make_float4(res[0], res[1], res[2], res[3]);
    *(float4*)&out[bb + e0 + 4] = make_float4(res[4], res[5], res[6], res[7]);
  }
}

// ---------------------------------------------------------------- launch
extern "C" void kernel_launch(void* const* d_in, const int* in_sizes, int n_in,
                              void* d_out, int out_size, void* d_ws, size_t ws_size,
                              hipStream_t stream)
{
  (void)in_sizes; (void)n_in; (void)out_size; (void)ws_size;
  const float* st     = (const float*)d_in[0];
  const float* phy    = (const float*)d_in[1];
  const float* wq_st  = (const float*)d_in[2];
  const float* bq_st  = (const float*)d_in[3];
  const float* wk_st  = (const float*)d_in[4];
  const float* bk_st  = (const float*)d_in[5];
  const float* wv_st  = (const float*)d_in[6];
  const float* bv_st  = (const float*)d_in[7];
  const float* wq_phy = (const float*)d_in[8];
  const float* bq_phy = (const float*)d_in[9];
  const float* wk_phy = (const float*)d_in[10];
  const float* bk_phy = (const float*)d_in[11];
  const float* wv_phy = (const float*)d_in[12];
  const float* bv_phy = (const float*)d_in[13];
  const float* w3  = (const float*)d_in[14];
  const float* g3  = (const float*)d_in[15];
  const float* be3 = (const float*)d_in[16];
  const float* w5  = (const float*)d_in[17];
  const float* g5  = (const float*)d_in[18];
  const float* be5 = (const float*)d_in[19];
  const float* w7  = (const float*)d_in[20];
  const float* g7  = (const float*)d_in[21];
  const float* be7 = (const float*)d_in[22];
  const float* w1  = (const float*)d_in[23];
  const float* g1  = (const float*)d_in[24];
  const float* be1 = (const float*)d_in[25];
  const float* b1  = (const float*)d_in[26];

  char* ws = (char*)d_ws;
  bf16* Xt        = (bf16*)ws;                       // phase A
  bf16* projchunk = (bf16*)(ws + 67108864ULL);       // phase A
  bf16* cA        = (bf16*)(ws + 117440512ULL);      // phase A
  u8*   cB        = (u8*)(ws + 184549376ULL);        // phase A
  bf16* wproj     = (bf16*)(ws + 218103808ULL);      // phase A (dead gap)
  bf16* cAT       = (bf16*)ws;                       // phase B/C
  u8*   cBT       = (u8*)(ws + 67108864ULL);         // phase B/C
  bf16* x3b       = (bf16*)(ws + 100663296ULL);
  bf16* x5b       = (bf16*)(ws + 134217728ULL);
  bf16* x7b       = (bf16*)(ws + 167772160ULL);
  bf16* x1b       = (bf16*)(ws + 201326592ULL);
  float* parts    = (float*)(ws + 234881024ULL);
  bf16* wb3       = (bf16*)(ws + 234913792ULL);
  bf16* wb5       = (bf16*)(ws + 236093440ULL);
  bf16* wb7       = (bf16*)(ws + 239370240ULL);
  bf16* wb1       = (bf16*)(ws + 245792768ULL);

  prep_w_kernel<<<dim3(2048), 256, 0, stream>>>(w3, w5, w7, w1,
      wq_st, wk_st, wv_st, wq_phy, wk_phy, wv_phy,
      wb3, wb5, wb7, wb1, wproj);
  xpose_in_kernel<<<dim3(64, 128), 256, 0, stream>>>(st, phy, Xt);

  for (int g = 0; g < 4; ++g) {
    proj_mfma<<<dim3(8, 128), 256, 0, stream>>>(Xt, wproj,
        bq_st, bk_st, bv_st, bq_phy, bk_phy, bv_phy, projchunk, g * 32);
    attn_chunk_kernel<<<dim3(32, 128), 64, 0, stream>>>(projchunk, st, phy,
        cA, cB, g * 32);
  }
  transpose_kernel<<<dim3(128, 128), 256, 0, stream>>>(cA, cB, cAT, cBT);

  conv_mfma<3><<<dim3(4, 128), 256, 0, stream>>>(cAT, cBT, wb3, nullptr, x3b, parts);
  conv_mfma4<5><<<dim3(2, 128), 256, 0, stream>>>(cAT, cBT, wb5, x5b, parts + 2048);
  conv_mfma4<7><<<dim3(2, 128), 256, 0, stream>>>(cAT, cBT, wb7, x7b, parts + 4096);
  conv_mfma<1><<<dim3(4, 128), 256, 0, stream>>>(cAT, cBT, wb1, b1, x1b, parts + 6144);

  final_kernel<<<dim3(8, 128), 256, 0, stream>>>(x3b, x5b, x7b, x1b,
      parts, parts + 2048, parts + 4096, parts + 6144,
      g3, be3, g5, be5, g7, be7, g1, be1, (float*)d_out);
}

// Round 9
// 1826.522 us; speedup vs baseline: 1.6761x; 1.6761x over previous
//
#include <hip/hip_runtime.h>
#include <hip/hip_bf16.h>

typedef __hip_bfloat16 bf16;
typedef unsigned char u8;
typedef unsigned long long u64;
typedef __attribute__((ext_vector_type(8))) short short8;
typedef __attribute__((ext_vector_type(16))) float f32x16;
#define DI __device__ __forceinline__

union BF8 { int4 v; short8 s; bf16 h[8]; };
union BF4 { u64 u; bf16 h[4]; };
union I4LL { int4 v; long l[2]; };

// ws layout (bytes):
// phase A: Xt bf16 @0 (67,108,864) | projchunk @67,108,864 (50,331,648)
//          cA @117,440,512 (67,108,864) | cB @184,549,376 (33,554,432)
//          wproj @218,103,808 (196,608)
// phase B: transpose writes cAT @0 (67,108,864), cBT @67,108,864 (33,554,432)
//          (over dead Xt/projchunk); then to_fp8 reads cAT/cBT, writes
//          cAT8 fp8 [b][pos][512] @100,663,296 (67,108,864) (over dead projtail/cA)
// phase C: conv5->x5 @167,772,160; conv7->x7 @201,326,592 (read cAT8)
//          then conv3->x3 @100,663,296 (OVER dead cAT8), conv1->x1 @134,217,728
// parts @234,881,024 (32 KB)
// wb3 bf16 @234,913,792 | wf5 fp8 @236,093,440 | wf7 fp8 @239,370,240 | wb1 bf16 @245,792,768

DI u8 f32_fp8(float v) {
  return (u8)(__builtin_amdgcn_cvt_pk_fp8_f32(v, 0.f, 0, false) & 0xff);
}

// ---------------------------------------------------------------- weight prep
// wb3/wb1 bf16 [tap][64 icg][128 oc][8 ic]; wf5/wf7 fp8 x256:
//   byte addr = (((tap*16+cc)*2+kg)*128+oc)*16 + kt*8 + j, ic = cc*32+kt*16+kg*8+j
__global__ __launch_bounds__(256) void prep_w_kernel(
    const float* __restrict__ w3, const float* __restrict__ w5,
    const float* __restrict__ w7, const float* __restrict__ w1,
    const float* __restrict__ wq_st, const float* __restrict__ wk_st,
    const float* __restrict__ wv_st, const float* __restrict__ wq_phy,
    const float* __restrict__ wk_phy, const float* __restrict__ wv_phy,
    bf16* __restrict__ wb3, u8* __restrict__ wf5,
    u8* __restrict__ wf7, bf16* __restrict__ wb1, bf16* __restrict__ wp)
{
  const int N3 = 9 * 65536, N5 = 25 * 65536, N7 = 49 * 65536, N1 = 65536;
  const int NP = 6 * 16384;
  const int total = N3 + N5 + N7 + N1 + NP;
  for (int i = blockIdx.x * 256 + threadIdx.x; i < total; i += gridDim.x * 256) {
    if (i < N3) {
      int tap = i >> 16, rem = i & 65535;
      int icg = rem >> 10, oc = (rem >> 3) & 127, j = rem & 7;
      wb3[i] = __float2bfloat16(w3[(size_t)(oc * 512 + icg * 8 + j) * 9 + tap]);
    } else if (i < N3 + N5) {
      int k = i - N3; int tap = k >> 16, rem = k & 65535;
      int cc = rem >> 12, r2 = rem & 4095;
      int kg = r2 >> 11, r3 = r2 & 2047;
      int oc = r3 >> 4, r4 = r3 & 15;
      int kt = r4 >> 3, j = r4 & 7;
      int ic = cc * 32 + kt * 16 + kg * 8 + j;
      wf5[k] = f32_fp8(w5[(size_t)(oc * 512 + ic) * 25 + tap] * 256.0f);
    } else if (i < N3 + N5 + N7) {
      int k = i - N3 - N5; int tap = k >> 16, rem = k & 65535;
      int cc = rem >> 12, r2 = rem & 4095;
      int kg = r2 >> 11, r3 = r2 & 2047;
      int oc = r3 >> 4, r4 = r3 & 15;
      int kt = r4 >> 3, j = r4 & 7;
      int ic = cc * 32 + kt * 16 + kg * 8 + j;
      wf7[k] = f32_fp8(w7[(size_t)(oc * 512 + ic) * 49 + tap] * 256.0f);
    } else if (i < N3 + N5 + N7 + N1) {
      int k = i - N3 - N5 - N7;
      int icg = k >> 10, oc = (k >> 3) & 127, j = k & 7;
      wb1[k] = __float2bfloat16(w1[(size_t)oc * 512 + icg * 8 + j]);
    } else {
      int k = i - N3 - N5 - N7 - N1;
      int m = k >> 14, r = k & 16383;
      float v;
      switch (m) {
        case 0: v = wq_st[r]; break;
        case 1: v = wk_st[r]; break;
        case 2: v = wv_st[r]; break;
        case 3: v = wq_phy[r]; break;
        case 4: v = wk_phy[r]; break;
        default: v = wv_phy[r]; break;
      }
      wp[k] = __float2bfloat16(v);
    }
  }
}

// ---------------------------------------------------------------- input transpose
__global__ __launch_bounds__(256) void xpose_in_kernel(
    const float* __restrict__ st, const float* __restrict__ phy,
    bf16* __restrict__ Xt)
{
  __shared__ __align__(16) short Tb[64 * 72];
  const int x = blockIdx.x, b = blockIdx.y;
  const int t = x >> 5, rem = x & 31;
  const int ict = rem >> 4, post = rem & 15;
  const int ic0 = ict * 64, pos0 = post * 64;
  const int tid = threadIdx.x;
  const int rowi = tid >> 2, sub = tid & 3;
  const float* X = t ? phy : st;

  const float* src = X + ((size_t)b * 128 + ic0 + rowi) * 1024 + pos0 + sub * 16;
  #pragma unroll
  for (int q = 0; q < 4; ++q) {
    float4 v = *(const float4*)(src + q * 4);
    BF4 pk;
    pk.h[0] = __float2bfloat16(v.x); pk.h[1] = __float2bfloat16(v.y);
    pk.h[2] = __float2bfloat16(v.z); pk.h[3] = __float2bfloat16(v.w);
    *(u64*)&Tb[rowi * 72 + sub * 16 + q * 4] = pk.u;
  }
  __syncthreads();
  short tmp[16];
  #pragma unroll
  for (int j = 0; j < 16; ++j) tmp[j] = Tb[(sub * 16 + j) * 72 + rowi];
  bf16* dst = Xt + (((size_t)t * 128 + b) * 1024 + pos0 + rowi) * 128 + ic0 + sub * 16;
  *(int4*)dst       = ((int4*)tmp)[0];
  *(int4*)(dst + 8) = ((int4*)tmp)[1];
}

// ---------------------------------------------------------------- MFMA projections
__global__ __launch_bounds__(256) void proj_mfma(
    const bf16* __restrict__ Xt, const bf16* __restrict__ wproj,
    const float* __restrict__ b0, const float* __restrict__ b1,
    const float* __restrict__ b2, const float* __restrict__ b3,
    const float* __restrict__ b4, const float* __restrict__ b5,
    bf16* __restrict__ pc, int cb)
{
  const int pt = blockIdx.x, b = blockIdx.y;
  const int tid = threadIdx.x, wave = tid >> 6, lane = tid & 63;
  const int col = lane & 31, kg = lane >> 5;
  const int pos = pt * 128 + wave * 32 + col;

  f32x16 acc[6];
  #pragma unroll
  for (int m = 0; m < 6; ++m)
    #pragma unroll
    for (int e = 0; e < 16; ++e) acc[m][e] = 0.f;

  const bf16* xst = Xt + ((size_t)b * 1024 + pos) * 128 + kg * 8;
  const bf16* xph = xst + (size_t)128 * 1024 * 128;
  const bf16* wl = wproj + (size_t)(cb + col) * 128 + kg * 8;

  #pragma unroll
  for (int kst = 0; kst < 8; ++kst) {
    short8 bst = *(const short8*)&xst[kst * 16];
    short8 bph = *(const short8*)&xph[kst * 16];
    #pragma unroll
    for (int m = 0; m < 6; ++m) {
      BF8 a; a.v = *(const int4*)&wl[(size_t)m * 16384 + kst * 16];
      acc[m] = __builtin_amdgcn_mfma_f32_32x32x16_bf16(a.s, m < 3 ? bst : bph, acc[m], 0, 0, 0);
    }
  }
  const float* biases[6] = { b0, b1, b2, b3, b4, b5 };
  #pragma unroll
  for (int m = 0; m < 6; ++m) {
    #pragma unroll
    for (int r = 0; r < 16; ++r) {
      const int ocl = (r & 3) + 8 * (r >> 2) + 4 * kg;
      float v = acc[m][r] + biases[m][cb + ocl];
      pc[(((size_t)m * 128 + b) * 32 + ocl) * 1024 + pos] = __float2bfloat16(v);
    }
  }
}

// ---------------------------------------------------------------- attention helpers
DI void mm32b(const bf16* A, const bf16* Bm, float acc[4][4], int r0, int c0)
{
  #pragma unroll 4
  for (int w = 0; w < 32; ++w) {
    BF4 qa, kb;
    qa.u = *(const u64*)(A + w * 40 + r0);
    kb.u = *(const u64*)(Bm + w * 40 + c0);
    float qv[4], kv[4];
    #pragma unroll
    for (int j = 0; j < 4; ++j) {
      qv[j] = __bfloat162float(qa.h[j]);
      kv[j] = __bfloat162float(kb.h[j]);
    }
    #pragma unroll
    for (int i = 0; i < 4; ++i)
      #pragma unroll
      for (int j = 0; j < 4; ++j)
        acc[i][j] = fmaf(qv[i], kv[j], acc[i][j]);
  }
}

DI void softmax4(float acc[4][4])
{
  #pragma unroll
  for (int i = 0; i < 4; ++i) {
    float m = fmaxf(fmaxf(acc[i][0], acc[i][1]), fmaxf(acc[i][2], acc[i][3]));
    m = fmaxf(m, __shfl_xor(m, 1));
    m = fmaxf(m, __shfl_xor(m, 2));
    m = fmaxf(m, __shfl_xor(m, 4));
    float s = 0.f;
    #pragma unroll
    for (int j = 0; j < 4; ++j) { acc[i][j] = __expf(acc[i][j] - m); s += acc[i][j]; }
    s += __shfl_xor(s, 1); s += __shfl_xor(s, 2); s += __shfl_xor(s, 4);
    float rs = 1.0f / s;
    #pragma unroll
    for (int j = 0; j < 4; ++j) acc[i][j] *= rs;
  }
}

template<bool U8OUT>
DI void attn_one(const bf16* Qt, const bf16* K, const bf16* V, bf16 (*At)[40],
                 const float* resid, void* outp, int r0, int c0)
{
  float acc[4][4] = {};
  mm32b(Qt, K, acc, r0, c0);
  softmax4(acc);
  __syncthreads();
  #pragma unroll
  for (int j = 0; j < 4; ++j) {
    BF4 pk;
    #pragma unroll
    for (int i = 0; i < 4; ++i) pk.h[i] = __float2bfloat16(acc[i][j]);
    *(u64*)&At[c0 + j][r0] = pk.u;
  }
  __syncthreads();
  float o[4][4] = {};
  mm32b(&At[0][0], V, o, r0, c0);
  softmax4(o);
  if constexpr (!U8OUT) {
    bf16* op = (bf16*)outp;
    if (resid) {
      #pragma unroll
      for (int i = 0; i < 4; ++i) {
        float4 rv = *(const float4*)&resid[(r0 + i) * 32 + c0];
        o[i][0] += rv.x; o[i][1] += rv.y; o[i][2] += rv.z; o[i][3] += rv.w;
      }
    }
    #pragma unroll
    for (int i = 0; i < 4; ++i) {
      BF4 pk;
      #pragma unroll
      for (int j = 0; j < 4; ++j) pk.h[j] = __float2bfloat16(o[i][j]);
      *(u64*)&op[(r0 + i) * 32 + c0] = pk.u;
    }
  } else {
    u8* op = (u8*)outp;
    #pragma unroll
    for (int i = 0; i < 4; ++i) {
      unsigned pk = 0;
      #pragma unroll
      for (int j = 0; j < 4; ++j) {
        unsigned bv = (unsigned)fminf(o[i][j] * 256.f + 0.5f, 255.f);
        pk |= bv << (8 * j);
      }
      *(unsigned*)&op[(r0 + i) * 32 + c0] = pk;
    }
  }
}

// ---------------------------------------------------------------- attention
__global__ __launch_bounds__(64) void attn_chunk_kernel(
    const bf16* __restrict__ pc,
    const float* __restrict__ st, const float* __restrict__ phy,
    bf16* __restrict__ cA, u8* __restrict__ cB, int cb)
{
  __shared__ __align__(16) bf16 Qst[32][40], Qph[32][40];
  __shared__ __align__(16) bf16 Kst[32][40], Kph[32][40];
  __shared__ __align__(16) bf16 Vst[32][40], Vph[32][40];
  __shared__ __align__(16) bf16 At[32][40];
  const int cl = blockIdx.x, b = blockIdx.y;
  const int c = cb + cl;
  const int lane = threadIdx.x;
  const size_t mstride = (size_t)128 * 32 * 1024;
  const bf16* p0 = pc + ((size_t)b * 32 + cl) * 1024;
  const size_t bc = ((size_t)b * 128 + c) * 1024;

  #pragma unroll
  for (int it = 0; it < 2; ++it) {
    int e8 = (it * 64 + lane) * 8;
    int h = e8 >> 5, w0 = e8 & 31;
    BF8 q1, k1, v1, q2, k2, v2;
    q1.v = *(const int4*)&p0[e8];
    k1.v = *(const int4*)&p0[mstride + e8];
    v1.v = *(const int4*)&p0[2 * mstride + e8];
    q2.v = *(const int4*)&p0[3 * mstride + e8];
    k2.v = *(const int4*)&p0[4 * mstride + e8];
    v2.v = *(const int4*)&p0[5 * mstride + e8];
    *(int4*)&Kst[h][w0] = k1.v;
    *(int4*)&Vst[h][w0] = v1.v;
    *(int4*)&Kph[h][w0] = k2.v;
    *(int4*)&Vph[h][w0] = v2.v;
    #pragma unroll
    for (int j = 0; j < 8; ++j) {
      Qst[w0 + j][h] = q1.h[j];
      Qph[w0 + j][h] = q2.h[j];
    }
  }
  __syncthreads();
  const int r0 = (lane >> 3) * 4, c0 = (lane & 7) * 4;
  bf16* aA = cA + (size_t)b * 256 * 1024 + (size_t)c * 1024;
  u8*   aB = cB + (size_t)b * 256 * 1024 + (size_t)c * 1024;

  attn_one<false>(&Qst[0][0], &Kst[0][0], &Vst[0][0], At, st + bc,  aA,              r0, c0);
  attn_one<false>(&Qph[0][0], &Kph[0][0], &Vph[0][0], At, phy + bc, aA + 128 * 1024, r0, c0);
  attn_one<true >(&Qph[0][0], &Kst[0][0], &Vst[0][0], At, nullptr,  aB,              r0, c0);
  attn_one<true >(&Qst[0][0], &Kph[0][0], &Vph[0][0], At, nullptr,  aB + 128 * 1024, r0, c0);
}

// ---------------------------------------------------------------- concat transpose
__global__ __launch_bounds__(256) void transpose_kernel(
    const bf16* __restrict__ cA, const u8* __restrict__ cB,
    bf16* __restrict__ cAT, u8* __restrict__ cBT)
{
  __shared__ __align__(16) short Tb[64 * 72];
  __shared__ __align__(16) u8 T8[64 * 80];
  const int x = blockIdx.x, b = blockIdx.y;
  const int cht = x >> 4, post = x & 15;
  const int pos0 = post * 64;
  const int tid = threadIdx.x;
  const int rowi = tid >> 2, sub = tid & 3;

  if (cht < 4) {
    const int ch0 = cht * 64;
    const bf16* src = cA + ((size_t)b * 256 + ch0 + rowi) * 1024 + pos0 + sub * 16;
    *(int4*)&Tb[rowi * 72 + sub * 16]     = *(const int4*)src;
    *(int4*)&Tb[rowi * 72 + sub * 16 + 8] = *(const int4*)(src + 8);
    __syncthreads();
    short tmp[16];
    #pragma unroll
    for (int j = 0; j < 16; ++j) tmp[j] = Tb[(sub * 16 + j) * 72 + rowi];
    bf16* dst = cAT + ((size_t)b * 1024 + pos0 + rowi) * 256 + ch0 + sub * 16;
    *(int4*)dst       = ((int4*)tmp)[0];
    *(int4*)(dst + 8) = ((int4*)tmp)[1];
  } else {
    const int ch0 = (cht - 4) * 64;
    const u8* src = cB + ((size_t)b * 256 + ch0 + rowi) * 1024 + pos0 + sub * 16;
    *(int4*)&T8[rowi * 80 + sub * 16] = *(const int4*)src;
    __syncthreads();
    u8 tmp[16];
    #pragma unroll
    for (int j = 0; j < 16; ++j) tmp[j] = T8[(sub * 16 + j) * 80 + rowi];
    u8* dst = cBT + ((size_t)b * 1024 + pos0 + rowi) * 256 + ch0 + sub * 16;
    *(int4*)dst = *(int4*)tmp;
  }
}

// ---------------------------------------------------------------- fp8 conversion pass
// cAT/cBT (pos-major) -> cAT8 [b][pos][512], x16 scale, 32-ch chunks permuted:
// stored byte = kg*16 + kt*8 + j for ic-within-chunk = kt*16 + kg*8 + j.
__global__ __launch_bounds__(256) void to_fp8_kernel(
    const bf16* __restrict__ cAT, const u8* __restrict__ cBT,
    u8* __restrict__ cAT8)
{
  const int idx = blockIdx.x * 256 + threadIdx.x;   // 16384 blocks x 256
  const int g = idx & 31;                           // 16-ch group
  const size_t bp = (size_t)(idx >> 5);             // b*1024+pos
  const int c0 = g * 16;
  float v[16];
  if (c0 < 256) {
    BF8 lo, hi;
    lo.v = *(const int4*)&cAT[bp * 256 + c0];
    hi.v = *(const int4*)&cAT[bp * 256 + c0 + 8];
    #pragma unroll
    for (int j = 0; j < 8; ++j) {
      v[j]     = __bfloat162float(lo.h[j]) * 16.0f;
      v[8 + j] = __bfloat162float(hi.h[j]) * 16.0f;
    }
  } else {
    u64 raw0 = *(const u64*)&cBT[bp * 256 + (c0 - 256)];
    u64 raw1 = *(const u64*)&cBT[bp * 256 + (c0 - 256) + 8];
    #pragma unroll
    for (int j = 0; j < 8; ++j) {
      v[j]     = (float)((raw0 >> (8 * j)) & 255u) * 0.0625f;
      v[8 + j] = (float)((raw1 >> (8 * j)) & 255u) * 0.0625f;
    }
  }
  unsigned lo0 = (__builtin_amdgcn_cvt_pk_fp8_f32(v[0], v[1], 0, false) & 0xffff)
               | ((__builtin_amdgcn_cvt_pk_fp8_f32(v[2], v[3], 0, false) & 0xffff) << 16);
  unsigned hi0 = (__builtin_amdgcn_cvt_pk_fp8_f32(v[4], v[5], 0, false) & 0xffff)
               | ((__builtin_amdgcn_cvt_pk_fp8_f32(v[6], v[7], 0, false) & 0xffff) << 16);
  unsigned lo1 = (__builtin_amdgcn_cvt_pk_fp8_f32(v[8], v[9], 0, false) & 0xffff)
               | ((__builtin_amdgcn_cvt_pk_fp8_f32(v[10], v[11], 0, false) & 0xffff) << 16);
  unsigned hi1 = (__builtin_amdgcn_cvt_pk_fp8_f32(v[12], v[13], 0, false) & 0xffff)
               | ((__builtin_amdgcn_cvt_pk_fp8_f32(v[14], v[15], 0, false) & 0xffff) << 16);
  u64 run0 = (u64)lo0 | ((u64)hi0 << 32);   // ch c0..c0+7
  u64 run1 = (u64)lo1 | ((u64)hi1 << 32);   // ch c0+8..c0+15
  const int sp = (c0 >> 4) & 1;             // which 16 within the 32-chunk
  u8* d = cAT8 + bp * 512 + (c0 & ~31);
  *(u64*)(d + 8 * sp)      = run0;          // kg=0 half, kt=sp
  *(u64*)(d + 16 + 8 * sp) = run1;          // kg=1 half, kt=sp
}

// ---------------------------------------------------------------- staging (bf16 convs)
template<int PCX, int NIT, int H0>
DI void stage_tile(const bf16* cAT, const u8* cBT, short* Xs,
                   int b, int r0, int ic0, int tid)
{
  for (int e = tid; e < NIT; e += 256) {
    int i = e / (PCX * 4);
    int rem = e - i * (PCX * 4);
    int cx = rem >> 2, part = rem & 3;
    int ir = r0 - H0 + i, c = cx - H0;
    int4 val = make_int4(0, 0, 0, 0);
    if ((unsigned)ir < 32u && (unsigned)c < 32u) {
      size_t pbase = ((size_t)b * 1024 + ir * 32 + c) * 256;
      if (ic0 < 256) {
        val = *(const int4*)&cAT[pbase + ic0 + part * 8];
      } else {
        u64 u = *(const u64*)&cBT[pbase + (ic0 - 256) + part * 8];
        BF8 t;
        #pragma unroll
        for (int j = 0; j < 8; ++j)
          t.h[j] = __float2bfloat16((float)((u >> (8 * j)) & 255u) * 0.00390625f);
        val = t.v;
      }
    }
    *(int4*)&Xs[(i * PCX + cx) * 40 + part * 8] = val;
  }
}

// ---------------------------------------------------------------- bf16 MFMA conv (KS=1,3)
template<int KS>
__global__ __launch_bounds__(256, 2) void conv_mfma(
    const bf16* __restrict__ cAT, const u8* __restrict__ cBT,
    const bf16* __restrict__ wt, const float* __restrict__ bias,
    bf16* __restrict__ xout, float* __restrict__ partials)
{
  constexpr int H0 = KS / 2;
  constexpr int PCX = 32 + 2 * H0;
  constexpr int ROWS = 16 + 2 * H0;
  constexpr int NIT = ROWS * PCX * 4;
  __shared__ __align__(16) short Xs[ROWS * PCX * 40];
  __shared__ float rs[256], rq[256];
  const int tix = blockIdx.x, b = blockIdx.y;
  const int ot = tix >> 1, rt = tix & 1;
  const int oc0 = ot * 64, r0 = rt * 16;
  const int tid = threadIdx.x;
  const int wv = tid >> 6, lane = tid & 63;
  const int col = lane & 31, kg = lane >> 5;

  f32x16 acc[2][4];
  #pragma unroll
  for (int i = 0; i < 2; ++i)
    #pragma unroll
    for (int j = 0; j < 4; ++j)
      #pragma unroll
      for (int e = 0; e < 16; ++e) acc[i][j][e] = 0.f;

  for (int cc = 0; cc < 16; ++cc) {
    const int ic0 = cc * 32;
    stage_tile<PCX, NIT, H0>(cAT, cBT, Xs, b, r0, ic0, tid);
    __syncthreads();

    #pragma unroll 1
    for (int ky = 0; ky < KS; ++ky) {
      #pragma unroll
      for (int kx = 0; kx < KS; ++kx) {
        const int tap = ky * KS + kx;
        BF8 a[2][2];
        #pragma unroll
        for (int ob = 0; ob < 2; ++ob)
          #pragma unroll
          for (int kt = 0; kt < 2; ++kt) {
            int icg = cc * 4 + kt * 2 + kg;
            a[ob][kt].v = *(const int4*)&wt[(((size_t)tap * 64 + icg) * 128 + oc0 + ob * 32 + col) * 8];
          }
        #pragma unroll
        for (int rr = 0; rr < 4; ++rr) {
          int entry = ((wv * 4 + rr + ky) * PCX + col + kx) * 40;
          #pragma unroll
          for (int kt = 0; kt < 2; ++kt) {
            short8 bf = *(const short8*)&Xs[entry + (kt * 2 + kg) * 8];
            acc[0][rr] = __builtin_amdgcn_mfma_f32_32x32x16_bf16(a[0][kt].s, bf, acc[0][rr], 0, 0, 0);
            acc[1][rr] = __builtin_amdgcn_mfma_f32_32x32x16_bf16(a[1][kt].s, bf, acc[1][rr], 0, 0, 0);
          }
        }
      }
    }
    __syncthreads();
  }

  float lsum = 0.f, lsq = 0.f;
  #pragma unroll
  for (int ob = 0; ob < 2; ++ob)
    #pragma unroll
    for (int rr = 0; rr < 4; ++rr) {
      const int row = r0 + wv * 4 + rr;
      #pragma unroll
      for (int r = 0; r < 16; ++r) {
        const int oc = oc0 + ob * 32 + (r & 3) + 8 * (r >> 2) + 4 * kg;
        float v = acc[ob][rr][r];
        if (bias) v += bias[oc];
        xout[((size_t)b * 128 + oc) * 1024 + row * 32 + col] = __float2bfloat16(v);
        lsum += v; lsq += v * v;
      }
    }
  rs[tid] = lsum; rq[tid] = lsq;
  __syncthreads();
  for (int s = 128; s > 0; s >>= 1) {
    if (tid < s) { rs[tid] += rs[tid + s]; rq[tid] += rq[tid + s]; }
    __syncthreads();
  }
  if (tid == 0) {
    partials[((size_t)b * 4 + tix) * 2]     = rs[0];
    partials[((size_t)b * 4 + tix) * 2 + 1] = rq[0];
  }
}

// ---------------------------------------------------------------- fp8 MFMA conv (KS=5,7)
// ob=2, rr=4, 2 blocks/CU. 8-bit operands: per tap/CU L1 ~128cy, LDS ~256cy,
// MFMA 256cy -> balanced. Entry = 32 B data + 16 pad (48: 16B-aligned, 12-dword
// stride tiles all 32 banks over 8 lanes). acc scaled by 1/4096 (w x256, x x16).
template<int KS>
__global__ __launch_bounds__(256, 2) void conv_mfma8(
    const u8* __restrict__ cAT8, const u8* __restrict__ wf,
    bf16* __restrict__ xout, float* __restrict__ partials)
{
  constexpr int H0 = KS / 2;
  constexpr int PCX = 32 + 2 * H0;
  constexpr int ROWS = 16 + 2 * H0;
  constexpr int NIT = ROWS * PCX * 2;              // 16-B units
  __shared__ __align__(16) u8 Xs[ROWS * PCX * 48];
  __shared__ float rs[256], rq[256];
  const int tix = blockIdx.x, b = blockIdx.y;
  const int ot = tix >> 1, rt = tix & 1;
  const int oc0 = ot * 64, r0 = rt * 16;
  const int tid = threadIdx.x;
  const int wv = tid >> 6, lane = tid & 63;
  const int col = lane & 31, kg = lane >> 5;

  f32x16 acc[2][4];
  #pragma unroll
  for (int i = 0; i < 2; ++i)
    #pragma unroll
    for (int j = 0; j < 4; ++j)
      #pragma unroll
      for (int e = 0; e < 16; ++e) acc[i][j][e] = 0.f;

  for (int cc = 0; cc < 16; ++cc) {
    const int ic0 = cc * 32;
    for (int e = tid; e < NIT; e += 256) {
      int entry = e >> 1, hf = e & 1;
      int i = entry / PCX, cx = entry - i * PCX;
      int ir = r0 - H0 + i, c = cx - H0;
      int4 val = make_int4(0, 0, 0, 0);
      if ((unsigned)ir < 32u && (unsigned)c < 32u)
        val = *(const int4*)&cAT8[((size_t)b * 1024 + ir * 32 + c) * 512 + ic0 + hf * 16];
      *(int4*)&Xs[entry * 48 + hf * 16] = val;
    }
    __syncthreads();

    #pragma unroll 1
    for (int ky = 0; ky < KS; ++ky) {
      #pragma unroll
      for (int kx = 0; kx < KS; ++kx) {
        const int tap = ky * KS + kx;
        I4LL a[2];
        #pragma unroll
        for (int ob = 0; ob < 2; ++ob)
          a[ob].v = *(const int4*)&wf[((((size_t)tap * 16 + cc) * 2 + kg) * 128 + oc0 + ob * 32 + col) * 16];
        #pragma unroll
        for (int rr = 0; rr < 4; ++rr) {
          int entry = (wv * 4 + rr + ky) * PCX + col + kx;
          I4LL bfr;
          bfr.v = *(const int4*)&Xs[entry * 48 + kg * 16];
          acc[0][rr] = __builtin_amdgcn_mfma_f32_32x32x16_fp8_fp8(a[0].l[0], bfr.l[0], acc[0][rr], 0, 0, 0);
          acc[1][rr] = __builtin_amdgcn_mfma_f32_32x32x16_fp8_fp8(a[1].l[0], bfr.l[0], acc[1][rr], 0, 0, 0);
          acc[0][rr] = __builtin_amdgcn_mfma_f32_32x32x16_fp8_fp8(a[0].l[1], bfr.l[1], acc[0][rr], 0, 0, 0);
          acc[1][rr] = __builtin_amdgcn_mfma_f32_32x32x16_fp8_fp8(a[1].l[1], bfr.l[1], acc[1][rr], 0, 0, 0);
        }
      }
    }
    __syncthreads();
  }

  float lsum = 0.f, lsq = 0.f;
  #pragma unroll
  for (int ob = 0; ob < 2; ++ob)
    #pragma unroll
    for (int rr = 0; rr < 4; ++rr) {
      const int row = r0 + wv * 4 + rr;
      #pragma unroll
      for (int r = 0; r < 16; ++r) {
        const int oc = oc0 + ob * 32 + (r & 3) + 8 * (r >> 2) + 4 * kg;
        float v = acc[ob][rr][r] * (1.0f / 4096.0f);
        xout[((size_t)b * 128 + oc) * 1024 + row * 32 + col] = __float2bfloat16(v);
        lsum += v; lsq += v * v;
      }
    }
  rs[tid] = lsum; rq[tid] = lsq;
  __syncthreads();
  for (int s = 128; s > 0; s >>= 1) {
    if (tid < s) { rs[tid] += rs[tid + s]; rq[tid] += rq[tid + s]; }
    __syncthreads();
  }
  if (tid == 0) {
    partials[((size_t)b * 4 + tix) * 2]     = rs[0];
    partials[((size_t)b * 4 + tix) * 2 + 1] = rq[0];
  }
}

// ---------------------------------------------------------------- LN + combine (4 partials each)
__global__ __launch_bounds__(256) void final_kernel(
    const bf16* __restrict__ x3, const bf16* __restrict__ x5,
    const bf16* __restrict__ x7, const bf16* __restrict__ x1c,
    const float* __restrict__ p3, const float* __restrict__ p5,
    const float* __restrict__ p7, const float* __restrict__ p1,
    const float* __restrict__ g3, const float* __restrict__ be3,
    const float* __restrict__ g5, const float* __restrict__ be5,
    const float* __restrict__ g7, const float* __restrict__ be7,
    const float* __restrict__ g1, const float* __restrict__ be1,
    float* __restrict__ out)
{
  const int blk = blockIdx.x, b = blockIdx.y, tid = threadIdx.x;
  float s3 = 0, q3 = 0, s5 = 0, q5 = 0, s7 = 0, q7 = 0, s1 = 0, q1 = 0;
  #pragma unroll
  for (int i = 0; i < 4; ++i) {
    int o = (b * 4 + i) * 2;
    s3 += p3[o]; q3 += p3[o + 1];
    s5 += p5[o]; q5 += p5[o + 1];
    s7 += p7[o]; q7 += p7[o + 1];
    s1 += p1[o]; q1 += p1[o + 1];
  }
  const float inv = 1.0f / 131072.0f;
  float mu3 = s3 * inv, r3 = rsqrtf(fmaxf(q3 * inv - mu3 * mu3, 0.f) + 1e-5f);
  float mu5 = s5 * inv, r5 = rsqrtf(fmaxf(q5 * inv - mu5 * mu5, 0.f) + 1e-5f);
  float mu7 = s7 * inv, r7 = rsqrtf(fmaxf(q7 * inv - mu7 * mu7, 0.f) + 1e-5f);
  float mu1 = s1 * inv, r1 = rsqrtf(fmaxf(q1 * inv - mu1 * mu1, 0.f) + 1e-5f);
  const size_t bb = (size_t)b * 131072;
  for (int it = 0; it < 8; ++it) {
    int e0 = (it * 2048 + blk * 256 + tid) * 8;
    BF8 a3, a5, a7, a1;
    a3.v = *(const int4*)&x3[bb + e0];
    a5.v = *(const int4*)&x5[bb + e0];
    a7.v = *(const int4*)&x7[bb + e0];
    a1.v = *(const int4*)&x1c[bb + e0];
    float G3[8], B3[8], G5[8], B5[8], G7[8], B7[8], G1[8], B1[8];
    *(float4*)&G3[0] = *(const float4*)&g3[e0];  *(float4*)&G3[4] = *(const float4*)&g3[e0 + 4];
    *(float4*)&B3[0] = *(const float4*)&be3[e0]; *(float4*)&B3[4] = *(const float4*)&be3[e0 + 4];
    *(float4*)&G5[0] = *(const float4*)&g5[e0];  *(float4*)&G5[4] = *(const float4*)&g5[e0 + 4];
    *(float4*)&B5[0] = *(const float4*)&be5[e0]; *(float4*)&B5[4] = *(const float4*)&be5[e0 + 4];
    *(float4*)&G7[0] = *(const float4*)&g7[e0];  *(float4*)&G7[4] = *(const float4*)&g7[e0 + 4];
    *(float4*)&B7[0] = *(const float4*)&be7[e0]; *(float4*)&B7[4] = *(const float4*)&be7[e0 + 4];
    *(float4*)&G1[0] = *(const float4*)&g1[e0];  *(float4*)&G1[4] = *(const float4*)&g1[e0 + 4];
    *(float4*)&B1[0] = *(const float4*)&be1[e0]; *(float4*)&B1[4] = *(const float4*)&be1[e0 + 4];
    float res[8];
    #pragma unroll
    for (int j = 0; j < 8; ++j) {
      float v3 = (__bfloat162float(a3.h[j]) - mu3) * r3 * G3[j] + B3[j];
      float v5 = (__bfloat162float(a5.h[j]) - mu5) * r5 * G5[j] + B5[j];
      float v7 = (__bfloat162float(a7.h[j]) - mu7) * r7 * G7[j] + B7[j];
      float m = (v3 + v5 + v7) * (1.0f / 3.0f);
      float sg = 1.0f / (1.0f + __expf(-m));
      float v1 = (__bfloat162float(a1.h[j]) - mu1) * r1 * G1[j] + B1[j];
      res[j] = sg + v1;
    }
    *(float4*)&out[bb + e0]     = make_float4(res[0], res[1], res[2], res[3]);
    *(float4*)&out[bb + e0 + 4] = make_float4(res[4], res[5], res[6], res[7]);
  }
}

// ---------------------------------------------------------------- launch
extern "C" void kernel_launch(void* const* d_in, const int* in_sizes, int n_in,
                              void* d_out, int out_size, void* d_ws, size_t ws_size,
                              hipStream_t stream)
{
  (void)in_sizes; (void)n_in; (void)out_size; (void)ws_size;
  const float* st     = (const float*)d_in[0];
  const float* phy    = (const float*)d_in[1];
  const float* wq_st  = (const float*)d_in[2];
  const float* bq_st  = (const float*)d_in[3];
  const float* wk_st  = (const float*)d_in[4];
  const float* bk_st  = (const float*)d_in[5];
  const float* wv_st  = (const float*)d_in[6];
  const float* bv_st  = (const float*)d_in[7];
  const float* wq_phy = (const float*)d_in[8];
  const float* bq_phy = (const float*)d_in[9];
  const float* wk_phy = (const float*)d_in[10];
  const float* bk_phy = (const float*)d_in[11];
  const float* wv_phy = (const float*)d_in[12];
  const float* bv_phy = (const float*)d_in[13];
  const float* w3  = (const float*)d_in[14];
  const float* g3  = (const float*)d_in[15];
  const float* be3 = (const float*)d_in[16];
  const float* w5  = (const float*)d_in[17];
  const float* g5  = (const float*)d_in[18];
  const float* be5 = (const float*)d_in[19];
  const float* w7  = (const float*)d_in[20];
  const float* g7  = (const float*)d_in[21];
  const float* be7 = (const float*)d_in[22];
  const float* w1  = (const float*)d_in[23];
  const float* g1  = (const float*)d_in[24];
  const float* be1 = (const float*)d_in[25];
  const float* b1  = (const float*)d_in[26];

  char* ws = (char*)d_ws;
  bf16* Xt        = (bf16*)ws;                       // phase A
  bf16* projchunk = (bf16*)(ws + 67108864ULL);       // phase A
  bf16* cA        = (bf16*)(ws + 117440512ULL);      // phase A
  u8*   cB        = (u8*)(ws + 184549376ULL);        // phase A
  bf16* wproj     = (bf16*)(ws + 218103808ULL);
  bf16* cAT       = (bf16*)ws;                       // phase B/C
  u8*   cBT       = (u8*)(ws + 67108864ULL);         // phase B/C
  u8*   cAT8      = (u8*)(ws + 100663296ULL);        // fp8 concat (phase B/C)
  bf16* x5b       = (bf16*)(ws + 167772160ULL);
  bf16* x7b       = (bf16*)(ws + 201326592ULL);
  bf16* x3b       = (bf16*)(ws + 100663296ULL);      // overlays dead cAT8
  bf16* x1b       = (bf16*)(ws + 134217728ULL);      // overlays dead cAT8
  float* parts    = (float*)(ws + 234881024ULL);
  bf16* wb3       = (bf16*)(ws + 234913792ULL);
  u8*   wf5       = (u8*)(ws + 236093440ULL);
  u8*   wf7       = (u8*)(ws + 239370240ULL);
  bf16* wb1       = (bf16*)(ws + 245792768ULL);

  prep_w_kernel<<<dim3(2048), 256, 0, stream>>>(w3, w5, w7, w1,
      wq_st, wk_st, wv_st, wq_phy, wk_phy, wv_phy,
      wb3, wf5, wf7, wb1, wproj);
  xpose_in_kernel<<<dim3(64, 128), 256, 0, stream>>>(st, phy, Xt);

  for (int g = 0; g < 4; ++g) {
    proj_mfma<<<dim3(8, 128), 256, 0, stream>>>(Xt, wproj,
        bq_st, bk_st, bv_st, bq_phy, bk_phy, bv_phy, projchunk, g * 32);
    attn_chunk_kernel<<<dim3(32, 128), 64, 0, stream>>>(projchunk, st, phy,
        cA, cB, g * 32);
  }
  transpose_kernel<<<dim3(128, 128), 256, 0, stream>>>(cA, cB, cAT, cBT);
  to_fp8_kernel<<<dim3(16384), 256, 0, stream>>>(cAT, cBT, cAT8);

  conv_mfma8<5><<<dim3(4, 128), 256, 0, stream>>>(cAT8, wf5, x5b, parts + 2048);
  conv_mfma8<7><<<dim3(4, 128), 256, 0, stream>>>(cAT8, wf7, x7b, parts + 4096);
  conv_mfma<3><<<dim3(4, 128), 256, 0, stream>>>(cAT, cBT, wb3, nullptr, x3b, parts);
  conv_mfma<1><<<dim3(4, 128), 256, 0, stream>>>(cAT, cBT, wb1, b1, x1b, parts + 6144);

  final_kernel<<<dim3(8, 128), 256, 0, stream>>>(x3b, x5b, x7b, x1b,
      parts, parts + 2048, parts + 4096, parts + 6144,
      g3, be3, g5, be5, g7, be7, g1, be1, (float*)d_out);
}

// Round 10
// 1762.134 us; speedup vs baseline: 1.7374x; 1.0365x over previous
//
#include <hip/hip_runtime.h>
#include <hip/hip_bf16.h>

typedef __hip_bfloat16 bf16;
typedef unsigned char u8;
typedef unsigned long long u64;
typedef __attribute__((ext_vector_type(8))) short short8;
typedef __attribute__((ext_vector_type(16))) float f32x16;
#define DI __device__ __forceinline__

union BF8 { int4 v; short8 s; bf16 h[8]; };
union BF4 { u64 u; bf16 h[4]; };
union I4LL { int4 v; long l[2]; };

// ws layout (bytes):
// phase A: Xt @0 (67,108,864) | projchunk @67,108,864 (50,331,648)
//          cA @117,440,512 (67,108,864) | cB @184,549,376 (33,554,432)
//          wproj @218,103,808 (196,608)
// phase B: transpose -> cAT @0, cBT @67,108,864 (over dead Xt/projchunk)
//          to_fp8 -> cAT8 fp8 [b][pos][512] @117,440,512 (over dead cA)
// phase C: conv1 (bf16, reads cAT/cBT) -> x1 @184,549,376 (over dead cB)
//          then conv3/5/7 (fp8, read cAT8) -> x3 @0, x5 @33,554,432,
//          x7 @67,108,864 (over dead cAT/cBT; after conv1)
// parts @234,881,024 (32 KB)
// wf3 fp8 @234,913,792 | wf5 fp8 @236,093,440 | wf7 fp8 @239,370,240
// wb1 bf16 @245,792,768  (end 245,923,840)

DI u8 f32_fp8(float v) {
  return (u8)(__builtin_amdgcn_cvt_pk_fp8_f32(v, 0.f, 0, false) & 0xff);
}

// ---------------------------------------------------------------- weight prep
// wf3/5/7 fp8 x256: byte = (((tap*16+cc)*2+kg)*128+oc)*16 + kt*8 + j,
//   ic = cc*32 + kt*16 + kg*8 + j.  wb1 bf16 [64 icg][128 oc][8 ic].
__global__ __launch_bounds__(256) void prep_w_kernel(
    const float* __restrict__ w3, const float* __restrict__ w5,
    const float* __restrict__ w7, const float* __restrict__ w1,
    const float* __restrict__ wq_st, const float* __restrict__ wk_st,
    const float* __restrict__ wv_st, const float* __restrict__ wq_phy,
    const float* __restrict__ wk_phy, const float* __restrict__ wv_phy,
    u8* __restrict__ wf3, u8* __restrict__ wf5,
    u8* __restrict__ wf7, bf16* __restrict__ wb1, bf16* __restrict__ wp)
{
  const int N3 = 9 * 65536, N5 = 25 * 65536, N7 = 49 * 65536, N1 = 65536;
  const int NP = 6 * 16384;
  const int total = N3 + N5 + N7 + N1 + NP;
  for (int i = blockIdx.x * 256 + threadIdx.x; i < total; i += gridDim.x * 256) {
    if (i < N3 + N5 + N7) {
      const float* w; int k; int taps;
      u8* dst;
      if (i < N3)           { w = w3; k = i;            taps = 9;  dst = wf3; }
      else if (i < N3 + N5) { w = w5; k = i - N3;       taps = 25; dst = wf5; }
      else                  { w = w7; k = i - N3 - N5;  taps = 49; dst = wf7; }
      int tap = k >> 16, rem = k & 65535;
      int cc = rem >> 12, r2 = rem & 4095;
      int kg = r2 >> 11, r3 = r2 & 2047;
      int oc = r3 >> 4, r4 = r3 & 15;
      int kt = r4 >> 3, j = r4 & 7;
      int ic = cc * 32 + kt * 16 + kg * 8 + j;
      dst[k] = f32_fp8(w[(size_t)(oc * 512 + ic) * taps + tap] * 256.0f);
    } else if (i < N3 + N5 + N7 + N1) {
      int k = i - N3 - N5 - N7;
      int icg = k >> 10, oc = (k >> 3) & 127, j = k & 7;
      wb1[k] = __float2bfloat16(w1[(size_t)oc * 512 + icg * 8 + j]);
    } else {
      int k = i - N3 - N5 - N7 - N1;
      int m = k >> 14, r = k & 16383;
      float v;
      switch (m) {
        case 0: v = wq_st[r]; break;
        case 1: v = wk_st[r]; break;
        case 2: v = wv_st[r]; break;
        case 3: v = wq_phy[r]; break;
        case 4: v = wk_phy[r]; break;
        default: v = wv_phy[r]; break;
      }
      wp[k] = __float2bfloat16(v);
    }
  }
}

// ---------------------------------------------------------------- input transpose
__global__ __launch_bounds__(256) void xpose_in_kernel(
    const float* __restrict__ st, const float* __restrict__ phy,
    bf16* __restrict__ Xt)
{
  __shared__ __align__(16) short Tb[64 * 72];
  const int x = blockIdx.x, b = blockIdx.y;
  const int t = x >> 5, rem = x & 31;
  const int ict = rem >> 4, post = rem & 15;
  const int ic0 = ict * 64, pos0 = post * 64;
  const int tid = threadIdx.x;
  const int rowi = tid >> 2, sub = tid & 3;
  const float* X = t ? phy : st;

  const float* src = X + ((size_t)b * 128 + ic0 + rowi) * 1024 + pos0 + sub * 16;
  #pragma unroll
  for (int q = 0; q < 4; ++q) {
    float4 v = *(const float4*)(src + q * 4);
    BF4 pk;
    pk.h[0] = __float2bfloat16(v.x); pk.h[1] = __float2bfloat16(v.y);
    pk.h[2] = __float2bfloat16(v.z); pk.h[3] = __float2bfloat16(v.w);
    *(u64*)&Tb[rowi * 72 + sub * 16 + q * 4] = pk.u;
  }
  __syncthreads();
  short tmp[16];
  #pragma unroll
  for (int j = 0; j < 16; ++j) tmp[j] = Tb[(sub * 16 + j) * 72 + rowi];
  bf16* dst = Xt + (((size_t)t * 128 + b) * 1024 + pos0 + rowi) * 128 + ic0 + sub * 16;
  *(int4*)dst       = ((int4*)tmp)[0];
  *(int4*)(dst + 8) = ((int4*)tmp)[1];
}

// ---------------------------------------------------------------- MFMA projections
__global__ __launch_bounds__(256) void proj_mfma(
    const bf16* __restrict__ Xt, const bf16* __restrict__ wproj,
    const float* __restrict__ b0, const float* __restrict__ b1,
    const float* __restrict__ b2, const float* __restrict__ b3,
    const float* __restrict__ b4, const float* __restrict__ b5,
    bf16* __restrict__ pc, int cb)
{
  const int pt = blockIdx.x, b = blockIdx.y;
  const int tid = threadIdx.x, wave = tid >> 6, lane = tid & 63;
  const int col = lane & 31, kg = lane >> 5;
  const int pos = pt * 128 + wave * 32 + col;

  f32x16 acc[6];
  #pragma unroll
  for (int m = 0; m < 6; ++m)
    #pragma unroll
    for (int e = 0; e < 16; ++e) acc[m][e] = 0.f;

  const bf16* xst = Xt + ((size_t)b * 1024 + pos) * 128 + kg * 8;
  const bf16* xph = xst + (size_t)128 * 1024 * 128;
  const bf16* wl = wproj + (size_t)(cb + col) * 128 + kg * 8;

  #pragma unroll
  for (int kst = 0; kst < 8; ++kst) {
    short8 bst = *(const short8*)&xst[kst * 16];
    short8 bph = *(const short8*)&xph[kst * 16];
    #pragma unroll
    for (int m = 0; m < 6; ++m) {
      BF8 a; a.v = *(const int4*)&wl[(size_t)m * 16384 + kst * 16];
      acc[m] = __builtin_amdgcn_mfma_f32_32x32x16_bf16(a.s, m < 3 ? bst : bph, acc[m], 0, 0, 0);
    }
  }
  const float* biases[6] = { b0, b1, b2, b3, b4, b5 };
  #pragma unroll
  for (int m = 0; m < 6; ++m) {
    #pragma unroll
    for (int r = 0; r < 16; ++r) {
      const int ocl = (r & 3) + 8 * (r >> 2) + 4 * kg;
      float v = acc[m][r] + biases[m][cb + ocl];
      pc[(((size_t)m * 128 + b) * 32 + ocl) * 1024 + pos] = __float2bfloat16(v);
    }
  }
}

// ---------------------------------------------------------------- MFMA attention
// One wave per (b,c). A-frag layout (lane&31=row, (lane>>5)*8+j=k) is the
// conv-verified mapping. Row-softmax = shfl_xor over 32 lanes holding the
// row's 32 columns (masks 1..16 stay within each half-wave).
DI void softmax_rows(float p[16])
{
  #pragma unroll
  for (int r = 0; r < 16; ++r) {
    float m = p[r];
    m = fmaxf(m, __shfl_xor(m, 1));
    m = fmaxf(m, __shfl_xor(m, 2));
    m = fmaxf(m, __shfl_xor(m, 4));
    m = fmaxf(m, __shfl_xor(m, 8));
    m = fmaxf(m, __shfl_xor(m, 16));
    float e = __expf(p[r] - m);
    float s = e;
    s += __shfl_xor(s, 1); s += __shfl_xor(s, 2); s += __shfl_xor(s, 4);
    s += __shfl_xor(s, 8); s += __shfl_xor(s, 16);
    p[r] = __fdividef(e, s);
  }
}

template<bool U8OUT>
DI void attn_one_mfma(const BF8& qa0, const BF8& qa1,
                      const bf16* __restrict__ KT, const bf16* __restrict__ VT,
                      bf16* __restrict__ P,
                      const float* __restrict__ resid, void* outp, int lane)
{
  const int col = lane & 31, kg = lane >> 5;
  f32x16 acc;
  #pragma unroll
  for (int e = 0; e < 16; ++e) acc[e] = 0.f;
  BF8 kb0, kb1;
  kb0.v = *(const int4*)&KT[col * 40 + kg * 8];
  kb1.v = *(const int4*)&KT[col * 40 + 16 + kg * 8];
  acc = __builtin_amdgcn_mfma_f32_32x32x16_bf16(qa0.s, kb0.s, acc, 0, 0, 0);
  acc = __builtin_amdgcn_mfma_f32_32x32x16_bf16(qa1.s, kb1.s, acc, 0, 0, 0);
  float p[16];
  #pragma unroll
  for (int r = 0; r < 16; ++r) p[r] = acc[r];
  softmax_rows(p);
  __syncthreads();                       // WAR: previous attn's P reads done
  #pragma unroll
  for (int r = 0; r < 16; ++r) {
    int row = (r & 3) + 8 * (r >> 2) + 4 * kg;
    P[row * 40 + col] = __float2bfloat16(p[r]);
  }
  __syncthreads();                       // RAW: P visible to all lanes
  BF8 pa0, pa1, vb0, vb1;
  pa0.v = *(const int4*)&P[col * 40 + kg * 8];
  pa1.v = *(const int4*)&P[col * 40 + 16 + kg * 8];
  vb0.v = *(const int4*)&VT[col * 40 + kg * 8];
  vb1.v = *(const int4*)&VT[col * 40 + 16 + kg * 8];
  #pragma unroll
  for (int e = 0; e < 16; ++e) acc[e] = 0.f;
  acc = __builtin_amdgcn_mfma_f32_32x32x16_bf16(pa0.s, vb0.s, acc, 0, 0, 0);
  acc = __builtin_amdgcn_mfma_f32_32x32x16_bf16(pa1.s, vb1.s, acc, 0, 0, 0);
  #pragma unroll
  for (int r = 0; r < 16; ++r) p[r] = acc[r];
  softmax_rows(p);
  if constexpr (!U8OUT) {
    bf16* op = (bf16*)outp;
    #pragma unroll
    for (int r = 0; r < 16; ++r) {
      int row = (r & 3) + 8 * (r >> 2) + 4 * kg;
      int off = row * 32 + col;
      op[off] = __float2bfloat16(p[r] + resid[off]);
    }
  } else {
    u8* op = (u8*)outp;
    #pragma unroll
    for (int r = 0; r < 16; ++r) {
      int row = (r & 3) + 8 * (r >> 2) + 4 * kg;
      op[row * 32 + col] = (u8)fminf(p[r] * 256.f + 0.5f, 255.f);
    }
  }
}

__global__ __launch_bounds__(64) void attn_mfma_kernel(
    const bf16* __restrict__ pc,
    const float* __restrict__ st, const float* __restrict__ phy,
    bf16* __restrict__ cA, u8* __restrict__ cB, int cb)
{
  __shared__ __align__(16) bf16 KTst[32 * 40], VTst[32 * 40];
  __shared__ __align__(16) bf16 KTph[32 * 40], VTph[32 * 40];
  __shared__ __align__(16) bf16 P[32 * 40];
  const int cl = blockIdx.x, b = blockIdx.y;
  const int c = cb + cl;
  const int lane = threadIdx.x;
  const size_t mstride = (size_t)128 * 32 * 1024;
  const bf16* p0 = pc + ((size_t)b * 32 + cl) * 1024;
  const size_t bc = ((size_t)b * 128 + c) * 1024;

  // stage K/V transposed: KT[kk][w] = K[w][kk]
  {
    const int w = lane >> 1, k0 = (lane & 1) * 16;
    const int off = w * 32 + k0;
    bf16* dsts[4] = { KTst, VTst, KTph, VTph };
    const int ms[4] = { 1, 2, 4, 5 };
    #pragma unroll
    for (int t = 0; t < 4; ++t) {
      BF8 r0, r1;
      r0.v = *(const int4*)&p0[(size_t)ms[t] * mstride + off];
      r1.v = *(const int4*)&p0[(size_t)ms[t] * mstride + off + 8];
      #pragma unroll
      for (int j = 0; j < 8; ++j) {
        dsts[t][(k0 + j) * 40 + w]     = r0.h[j];
        dsts[t][(k0 + 8 + j) * 40 + w] = r1.h[j];
      }
    }
  }
  const int col = lane & 31, kg = lane >> 5;
  BF8 qst0, qst1, qph0, qph1;
  qst0.v = *(const int4*)&p0[col * 32 + kg * 8];
  qst1.v = *(const int4*)&p0[col * 32 + 16 + kg * 8];
  qph0.v = *(const int4*)&p0[3 * mstride + col * 32 + kg * 8];
  qph1.v = *(const int4*)&p0[3 * mstride + col * 32 + 16 + kg * 8];
  __syncthreads();

  bf16* aA = cA + (size_t)b * 256 * 1024 + (size_t)c * 1024;
  u8*   aB = cB + (size_t)b * 256 * 1024 + (size_t)c * 1024;
  attn_one_mfma<false>(qst0, qst1, KTst, VTst, P, st + bc,  aA,          lane);
  attn_one_mfma<false>(qph0, qph1, KTph, VTph, P, phy + bc, aA + 131072, lane);
  attn_one_mfma<true >(qph0, qph1, KTst, VTst, P, nullptr,  aB,          lane);
  attn_one_mfma<true >(qst0, qst1, KTph, VTph, P, nullptr,  aB + 131072, lane);
}

// ---------------------------------------------------------------- concat transpose
__global__ __launch_bounds__(256) void transpose_kernel(
    const bf16* __restrict__ cA, const u8* __restrict__ cB,
    bf16* __restrict__ cAT, u8* __restrict__ cBT)
{
  __shared__ __align__(16) short Tb[64 * 72];
  __shared__ __align__(16) u8 T8[64 * 80];
  const int x = blockIdx.x, b = blockIdx.y;
  const int cht = x >> 4, post = x & 15;
  const int pos0 = post * 64;
  const int tid = threadIdx.x;
  const int rowi = tid >> 2, sub = tid & 3;

  if (cht < 4) {
    const int ch0 = cht * 64;
    const bf16* src = cA + ((size_t)b * 256 + ch0 + rowi) * 1024 + pos0 + sub * 16;
    *(int4*)&Tb[rowi * 72 + sub * 16]     = *(const int4*)src;
    *(int4*)&Tb[rowi * 72 + sub * 16 + 8] = *(const int4*)(src + 8);
    __syncthreads();
    short tmp[16];
    #pragma unroll
    for (int j = 0; j < 16; ++j) tmp[j] = Tb[(sub * 16 + j) * 72 + rowi];
    bf16* dst = cAT + ((size_t)b * 1024 + pos0 + rowi) * 256 + ch0 + sub * 16;
    *(int4*)dst       = ((int4*)tmp)[0];
    *(int4*)(dst + 8) = ((int4*)tmp)[1];
  } else {
    const int ch0 = (cht - 4) * 64;
    const u8* src = cB + ((size_t)b * 256 + ch0 + rowi) * 1024 + pos0 + sub * 16;
    *(int4*)&T8[rowi * 80 + sub * 16] = *(const int4*)src;
    __syncthreads();
    u8 tmp[16];
    #pragma unroll
    for (int j = 0; j < 16; ++j) tmp[j] = T8[(sub * 16 + j) * 80 + rowi];
    u8* dst = cBT + ((size_t)b * 1024 + pos0 + rowi) * 256 + ch0 + sub * 16;
    *(int4*)dst = *(int4*)tmp;
  }
}

// ---------------------------------------------------------------- fp8 conversion pass
__global__ __launch_bounds__(256) void to_fp8_kernel(
    const bf16* __restrict__ cAT, const u8* __restrict__ cBT,
    u8* __restrict__ cAT8)
{
  const int idx = blockIdx.x * 256 + threadIdx.x;
  const int g = idx & 31;
  const size_t bp = (size_t)(idx >> 5);
  const int c0 = g * 16;
  float v[16];
  if (c0 < 256) {
    BF8 lo, hi;
    lo.v = *(const int4*)&cAT[bp * 256 + c0];
    hi.v = *(const int4*)&cAT[bp * 256 + c0 + 8];
    #pragma unroll
    for (int j = 0; j < 8; ++j) {
      v[j]     = __bfloat162float(lo.h[j]) * 16.0f;
      v[8 + j] = __bfloat162float(hi.h[j]) * 16.0f;
    }
  } else {
    u64 raw0 = *(const u64*)&cBT[bp * 256 + (c0 - 256)];
    u64 raw1 = *(const u64*)&cBT[bp * 256 + (c0 - 256) + 8];
    #pragma unroll
    for (int j = 0; j < 8; ++j) {
      v[j]     = (float)((raw0 >> (8 * j)) & 255u) * 0.0625f;
      v[8 + j] = (float)((raw1 >> (8 * j)) & 255u) * 0.0625f;
    }
  }
  unsigned lo0 = (__builtin_amdgcn_cvt_pk_fp8_f32(v[0], v[1], 0, false) & 0xffff)
               | ((__builtin_amdgcn_cvt_pk_fp8_f32(v[2], v[3], 0, false) & 0xffff) << 16);
  unsigned hi0 = (__builtin_amdgcn_cvt_pk_fp8_f32(v[4], v[5], 0, false) & 0xffff)
               | ((__builtin_amdgcn_cvt_pk_fp8_f32(v[6], v[7], 0, false) & 0xffff) << 16);
  unsigned lo1 = (__builtin_amdgcn_cvt_pk_fp8_f32(v[8], v[9], 0, false) & 0xffff)
               | ((__builtin_amdgcn_cvt_pk_fp8_f32(v[10], v[11], 0, false) & 0xffff) << 16);
  unsigned hi1 = (__builtin_amdgcn_cvt_pk_fp8_f32(v[12], v[13], 0, false) & 0xffff)
               | ((__builtin_amdgcn_cvt_pk_fp8_f32(v[14], v[15], 0, false) & 0xffff) << 16);
  u64 run0 = (u64)lo0 | ((u64)hi0 << 32);
  u64 run1 = (u64)lo1 | ((u64)hi1 << 32);
  const int sp = (c0 >> 4) & 1;
  u8* d = cAT8 + bp * 512 + (c0 & ~31);
  *(u64*)(d + 8 * sp)      = run0;
  *(u64*)(d + 16 + 8 * sp) = run1;
}

// ---------------------------------------------------------------- staging (bf16)
template<int PCX, int NIT, int H0>
DI void stage_tile(const bf16* cAT, const u8* cBT, short* Xs,
                   int b, int r0, int ic0, int tid)
{
  for (int e = tid; e < NIT; e += 256) {
    int i = e / (PCX * 4);
    int rem = e - i * (PCX * 4);
    int cx = rem >> 2, part = rem & 3;
    int ir = r0 - H0 + i, c = cx - H0;
    int4 val = make_int4(0, 0, 0, 0);
    if ((unsigned)ir < 32u && (unsigned)c < 32u) {
      size_t pbase = ((size_t)b * 1024 + ir * 32 + c) * 256;
      if (ic0 < 256) {
        val = *(const int4*)&cAT[pbase + ic0 + part * 8];
      } else {
        u64 u = *(const u64*)&cBT[pbase + (ic0 - 256) + part * 8];
        BF8 t;
        #pragma unroll
        for (int j = 0; j < 8; ++j)
          t.h[j] = __float2bfloat16((float)((u >> (8 * j)) & 255u) * 0.00390625f);
        val = t.v;
      }
    }
    *(int4*)&Xs[(i * PCX + cx) * 40 + part * 8] = val;
  }
}

// ---------------------------------------------------------------- bf16 MFMA conv (conv1)
template<int KS>
__global__ __launch_bounds__(256, 2) void conv_mfma(
    const bf16* __restrict__ cAT, const u8* __restrict__ cBT,
    const bf16* __restrict__ wt, const float* __restrict__ bias,
    bf16* __restrict__ xout, float* __restrict__ partials)
{
  constexpr int H0 = KS / 2;
  constexpr int PCX = 32 + 2 * H0;
  constexpr int ROWS = 16 + 2 * H0;
  constexpr int NIT = ROWS * PCX * 4;
  __shared__ __align__(16) short Xs[ROWS * PCX * 40];
  __shared__ float rs[256], rq[256];
  const int tix = blockIdx.x, b = blockIdx.y;
  const int ot = tix >> 1, rt = tix & 1;
  const int oc0 = ot * 64, r0 = rt * 16;
  const int tid = threadIdx.x;
  const int wv = tid >> 6, lane = tid & 63;
  const int col = lane & 31, kg = lane >> 5;

  f32x16 acc[2][4];
  #pragma unroll
  for (int i = 0; i < 2; ++i)
    #pragma unroll
    for (int j = 0; j < 4; ++j)
      #pragma unroll
      for (int e = 0; e < 16; ++e) acc[i][j][e] = 0.f;

  for (int cc = 0; cc < 16; ++cc) {
    const int ic0 = cc * 32;
    stage_tile<PCX, NIT, H0>(cAT, cBT, Xs, b, r0, ic0, tid);
    __syncthreads();

    #pragma unroll 1
    for (int ky = 0; ky < KS; ++ky) {
      #pragma unroll
      for (int kx = 0; kx < KS; ++kx) {
        const int tap = ky * KS + kx;
        BF8 a[2][2];
        #pragma unroll
        for (int ob = 0; ob < 2; ++ob)
          #pragma unroll
          for (int kt = 0; kt < 2; ++kt) {
            int icg = cc * 4 + kt * 2 + kg;
            a[ob][kt].v = *(const int4*)&wt[(((size_t)tap * 64 + icg) * 128 + oc0 + ob * 32 + col) * 8];
          }
        #pragma unroll
        for (int rr = 0; rr < 4; ++rr) {
          int entry = ((wv * 4 + rr + ky) * PCX + col + kx) * 40;
          #pragma unroll
          for (int kt = 0; kt < 2; ++kt) {
            short8 bf = *(const short8*)&Xs[entry + (kt * 2 + kg) * 8];
            acc[0][rr] = __builtin_amdgcn_mfma_f32_32x32x16_bf16(a[0][kt].s, bf, acc[0][rr], 0, 0, 0);
            acc[1][rr] = __builtin_amdgcn_mfma_f32_32x32x16_bf16(a[1][kt].s, bf, acc[1][rr], 0, 0, 0);
          }
        }
      }
    }
    __syncthreads();
  }

  float lsum = 0.f, lsq = 0.f;
  #pragma unroll
  for (int ob = 0; ob < 2; ++ob)
    #pragma unroll
    for (int rr = 0; rr < 4; ++rr) {
      const int row = r0 + wv * 4 + rr;
      #pragma unroll
      for (int r = 0; r < 16; ++r) {
        const int oc = oc0 + ob * 32 + (r & 3) + 8 * (r >> 2) + 4 * kg;
        float v = acc[ob][rr][r];
        if (bias) v += bias[oc];
        xout[((size_t)b * 128 + oc) * 1024 + row * 32 + col] = __float2bfloat16(v);
        lsum += v; lsq += v * v;
      }
    }
  rs[tid] = lsum; rq[tid] = lsq;
  __syncthreads();
  for (int s = 128; s > 0; s >>= 1) {
    if (tid < s) { rs[tid] += rs[tid + s]; rq[tid] += rq[tid + s]; }
    __syncthreads();
  }
  if (tid == 0) {
    partials[((size_t)b * 4 + tix) * 2]     = rs[0];
    partials[((size_t)b * 4 + tix) * 2 + 1] = rq[0];
  }
}

// ---------------------------------------------------------------- fp8 MFMA conv (KS=3,5,7)
template<int KS>
__global__ __launch_bounds__(256, 2) void conv_mfma8(
    const u8* __restrict__ cAT8, const u8* __restrict__ wf,
    bf16* __restrict__ xout, float* __restrict__ partials)
{
  constexpr int H0 = KS / 2;
  constexpr int PCX = 32 + 2 * H0;
  constexpr int ROWS = 16 + 2 * H0;
  constexpr int NIT = ROWS * PCX * 2;
  __shared__ __align__(16) u8 Xs[ROWS * PCX * 48];
  __shared__ float rs[256], rq[256];
  const int tix = blockIdx.x, b = blockIdx.y;
  const int ot = tix >> 1, rt = tix & 1;
  const int oc0 = ot * 64, r0 = rt * 16;
  const int tid = threadIdx.x;
  const int wv = tid >> 6, lane = tid & 63;
  const int col = lane & 31, kg = lane >> 5;

  f32x16 acc[2][4];
  #pragma unroll
  for (int i = 0; i < 2; ++i)
    #pragma unroll
    for (int j = 0; j < 4; ++j)
      #pragma unroll
      for (int e = 0; e < 16; ++e) acc[i][j][e] = 0.f;

  for (int cc = 0; cc < 16; ++cc) {
    const int ic0 = cc * 32;
    for (int e = tid; e < NIT; e += 256) {
      int entry = e >> 1, hf = e & 1;
      int i = entry / PCX, cx = entry - i * PCX;
      int ir = r0 - H0 + i, c = cx - H0;
      int4 val = make_int4(0, 0, 0, 0);
      if ((unsigned)ir < 32u && (unsigned)c < 32u)
        val = *(const int4*)&cAT8[((size_t)b * 1024 + ir * 32 + c) * 512 + ic0 + hf * 16];
      *(int4*)&Xs[entry * 48 + hf * 16] = val;
    }
    __syncthreads();

    #pragma unroll 1
    for (int ky = 0; ky < KS; ++ky) {
      #pragma unroll
      for (int kx = 0; kx < KS; ++kx) {
        const int tap = ky * KS + kx;
        I4LL a[2];
        #pragma unroll
        for (int ob = 0; ob < 2; ++ob)
          a[ob].v = *(const int4*)&wf[((((size_t)tap * 16 + cc) * 2 + kg) * 128 + oc0 + ob * 32 + col) * 16];
        #pragma unroll
        for (int rr = 0; rr < 4; ++rr) {
          int entry = (wv * 4 + rr + ky) * PCX + col + kx;
          I4LL bfr;
          bfr.v = *(const int4*)&Xs[entry * 48 + kg * 16];
          acc[0][rr] = __builtin_amdgcn_mfma_f32_32x32x16_fp8_fp8(a[0].l[0], bfr.l[0], acc[0][rr], 0, 0, 0);
          acc[1][rr] = __builtin_amdgcn_mfma_f32_32x32x16_fp8_fp8(a[1].l[0], bfr.l[0], acc[1][rr], 0, 0, 0);
          acc[0][rr] = __builtin_amdgcn_mfma_f32_32x32x16_fp8_fp8(a[0].l[1], bfr.l[1], acc[0][rr], 0, 0, 0);
          acc[1][rr] = __builtin_amdgcn_mfma_f32_32x32x16_fp8_fp8(a[1].l[1], bfr.l[1], acc[1][rr], 0, 0, 0);
        }
      }
    }
    __syncthreads();
  }

  float lsum = 0.f, lsq = 0.f;
  #pragma unroll
  for (int ob = 0; ob < 2; ++ob)
    #pragma unroll
    for (int rr = 0; rr < 4; ++rr) {
      const int row = r0 + wv * 4 + rr;
      #pragma unroll
      for (int r = 0; r < 16; ++r) {
        const int oc = oc0 + ob * 32 + (r & 3) + 8 * (r >> 2) + 4 * kg;
        float v = acc[ob][rr][r] * (1.0f / 4096.0f);
        xout[((size_t)b * 128 + oc) * 1024 + row * 32 + col] = __float2bfloat16(v);
        lsum += v; lsq += v * v;
      }
    }
  rs[tid] = lsum; rq[tid] = lsq;
  __syncthreads();
  for (int s = 128; s > 0; s >>= 1) {
    if (tid < s) { rs[tid] += rs[tid + s]; rq[tid] += rq[tid + s]; }
    __syncthreads();
  }
  if (tid == 0) {
    partials[((size_t)b * 4 + tix) * 2]     = rs[0];
    partials[((size_t)b * 4 + tix) * 2 + 1] = rq[0];
  }
}

// ---------------------------------------------------------------- LN + combine
__global__ __launch_bounds__(256) void final_kernel(
    const bf16* __restrict__ x3, const bf16* __restrict__ x5,
    const bf16* __restrict__ x7, const bf16* __restrict__ x1c,
    const float* __restrict__ p3, const float* __restrict__ p5,
    const float* __restrict__ p7, const float* __restrict__ p1,
    const float* __restrict__ g3, const float* __restrict__ be3,
    const float* __restrict__ g5, const float* __restrict__ be5,
    const float* __restrict__ g7, const float* __restrict__ be7,
    const float* __restrict__ g1, const float* __restrict__ be1,
    float* __restrict__ out)
{
  const int blk = blockIdx.x, b = blockIdx.y, tid = threadIdx.x;
  float s3 = 0, q3 = 0, s5 = 0, q5 = 0, s7 = 0, q7 = 0, s1 = 0, q1 = 0;
  #pragma unroll
  for (int i = 0; i < 4; ++i) {
    int o = (b * 4 + i) * 2;
    s3 += p3[o]; q3 += p3[o + 1];
    s5 += p5[o]; q5 += p5[o + 1];
    s7 += p7[o]; q7 += p7[o + 1];
    s1 += p1[o]; q1 += p1[o + 1];
  }
  const float inv = 1.0f / 131072.0f;
  float mu3 = s3 * inv, r3 = rsqrtf(fmaxf(q3 * inv - mu3 * mu3, 0.f) + 1e-5f);
  float mu5 = s5 * inv, r5 = rsqrtf(fmaxf(q5 * inv - mu5 * mu5, 0.f) + 1e-5f);
  float mu7 = s7 * inv, r7 = rsqrtf(fmaxf(q7 * inv - mu7 * mu7, 0.f) + 1e-5f);
  float mu1 = s1 * inv, r1 = rsqrtf(fmaxf(q1 * inv - mu1 * mu1, 0.f) + 1e-5f);
  const size_t bb = (size_t)b * 131072;
  for (int it = 0; it < 8; ++it) {
    int e0 = (it * 2048 + blk * 256 + tid) * 8;
    BF8 a3, a5, a7, a1;
    a3.v = *(const int4*)&x3[bb + e0];
    a5.v = *(const int4*)&x5[bb + e0];
    a7.v = *(const int4*)&x7[bb + e0];
    a1.v = *(const int4*)&x1c[bb + e0];
    float G3[8], B3[8], G5[8], B5[8], G7[8], B7[8], G1[8], B1[8];
    *(float4*)&G3[0] = *(const float4*)&g3[e0];  *(float4*)&G3[4] = *(const float4*)&g3[e0 + 4];
    *(float4*)&B3[0] = *(const float4*)&be3[e0]; *(float4*)&B3[4] = *(const float4*)&be3[e0 + 4];
    *(float4*)&G5[0] = *(const float4*)&g5[e0];  *(float4*)&G5[4] = *(const float4*)&g5[e0 + 4];
    *(float4*)&B5[0] = *(const float4*)&be5[e0]; *(float4*)&B5[4] = *(const float4*)&be5[e0 + 4];
    *(float4*)&G7[0] = *(const float4*)&g7[e0];  *(float4*)&G7[4] = *(const float4*)&g7[e0 + 4];
    *(float4*)&B7[0] = *(const float4*)&be7[e0]; *(float4*)&B7[4] = *(const float4*)&be7[e0 + 4];
    *(float4*)&G1[0] = *(const float4*)&g1[e0];  *(float4*)&G1[4] = *(const float4*)&g1[e0 + 4];
    *(float4*)&B1[0] = *(const float4*)&be1[e0]; *(float4*)&B1[4] = *(const float4*)&be1[e0 + 4];
    float res[8];
    #pragma unroll
    for (int j = 0; j < 8; ++j) {
      float v3 = (__bfloat162float(a3.h[j]) - mu3) * r3 * G3[j] + B3[j];
      float v5 = (__bfloat162float(a5.h[j]) - mu5) * r5 * G5[j] + B5[j];
      float v7 = (__bfloat162float(a7.h[j]) - mu7) * r7 * G7[j] + B7[j];
      float m = (v3 + v5 + v7) * (1.0f / 3.0f);
      float sg = 1.0f / (1.0f + __expf(-m));
      float v1 = (__bfloat162float(a1.h[j]) - mu1) * r1 * G1[j] + B1[j];
      res[j] = sg + v1;
    }
    *(float4*)&out[bb + e0]     = make_float4(res[0], res[1], res[2], res[3]);
    *(float4*)&out[bb + e0 + 4] = make_float4(res[4], res[5], res[6], res[7]);
  }
}

// ---------------------------------------------------------------- launch
extern "C" void kernel_launch(void* const* d_in, const int* in_sizes, int n_in,
                              void* d_out, int out_size, void* d_ws, size_t ws_size,
                              hipStream_t stream)
{
  (void)in_sizes; (void)n_in; (void)out_size; (void)ws_size;
  const float* st     = (const float*)d_in[0];
  const float* phy    = (const float*)d_in[1];
  const float* wq_st  = (const float*)d_in[2];
  const float* bq_st  = (const float*)d_in[3];
  const float* wk_st  = (const float*)d_in[4];
  const float* bk_st  = (const float*)d_in[5];
  const float* wv_st  = (const float*)d_in[6];
  const float* bv_st  = (const float*)d_in[7];
  const float* wq_phy = (const float*)d_in[8];
  const float* bq_phy = (const float*)d_in[9];
  const float* wk_phy = (const float*)d_in[10];
  const float* bk_phy = (const float*)d_in[11];
  const float* wv_phy = (const float*)d_in[12];
  const float* bv_phy = (const float*)d_in[13];
  const float* w3  = (const float*)d_in[14];
  const float* g3  = (const float*)d_in[15];
  const float* be3 = (const float*)d_in[16];
  const float* w5  = (const float*)d_in[17];
  const float* g5  = (const float*)d_in[18];
  const float* be5 = (const float*)d_in[19];
  const float* w7  = (const float*)d_in[20];
  const float* g7  = (const float*)d_in[21];
  const float* be7 = (const float*)d_in[22];
  const float* w1  = (const float*)d_in[23];
  const float* g1  = (const float*)d_in[24];
  const float* be1 = (const float*)d_in[25];
  const float* b1  = (const float*)d_in[26];

  char* ws = (char*)d_ws;
  // phase A
  bf16* Xt        = (bf16*)ws;
  bf16* projchunk = (bf16*)(ws + 67108864ULL);
  bf16* cA        = (bf16*)(ws + 117440512ULL);
  u8*   cB        = (u8*)(ws + 184549376ULL);
  bf16* wproj     = (bf16*)(ws + 218103808ULL);
  // phase B/C
  bf16* cAT       = (bf16*)ws;
  u8*   cBT       = (u8*)(ws + 67108864ULL);
  u8*   cAT8      = (u8*)(ws + 117440512ULL);     // over dead cA
  bf16* x1b       = (bf16*)(ws + 184549376ULL);   // over dead cB (conv1 first)
  bf16* x3b       = (bf16*)ws;                    // over dead cAT (after conv1)
  bf16* x5b       = (bf16*)(ws + 33554432ULL);
  bf16* x7b       = (bf16*)(ws + 67108864ULL);    // over dead cBT
  float* parts    = (float*)(ws + 234881024ULL);
  u8*   wf3       = (u8*)(ws + 234913792ULL);
  u8*   wf5       = (u8*)(ws + 236093440ULL);
  u8*   wf7       = (u8*)(ws + 239370240ULL);
  bf16* wb1       = (bf16*)(ws + 245792768ULL);

  prep_w_kernel<<<dim3(2048), 256, 0, stream>>>(w3, w5, w7, w1,
      wq_st, wk_st, wv_st, wq_phy, wk_phy, wv_phy,
      wf3, wf5, wf7, wb1, wproj);
  xpose_in_kernel<<<dim3(64, 128), 256, 0, stream>>>(st, phy, Xt);

  for (int g = 0; g < 4; ++g) {
    proj_mfma<<<dim3(8, 128), 256, 0, stream>>>(Xt, wproj,
        bq_st, bk_st, bv_st, bq_phy, bk_phy, bv_phy, projchunk, g * 32);
    attn_mfma_kernel<<<dim3(32, 128), 64, 0, stream>>>(projchunk, st, phy,
        cA, cB, g * 32);
  }
  transpose_kernel<<<dim3(128, 128), 256, 0, stream>>>(cA, cB, cAT, cBT);
  to_fp8_kernel<<<dim3(16384), 256, 0, stream>>>(cAT, cBT, cAT8);

  conv_mfma<1><<<dim3(4, 128), 256, 0, stream>>>(cAT, cBT, wb1, b1, x1b, parts + 6144);
  conv_mfma8<3><<<dim3(4, 128), 256, 0, stream>>>(cAT8, wf3, x3b, parts);
  conv_mfma8<5><<<dim3(4, 128), 256, 0, stream>>>(cAT8, wf5, x5b, parts + 2048);
  conv_mfma8<7><<<dim3(4, 128), 256, 0, stream>>>(cAT8, wf7, x7b, parts + 4096);

  final_kernel<<<dim3(8, 128), 256, 0, stream>>>(x3b, x5b, x7b, x1b,
      parts, parts + 2048, parts + 4096, parts + 6144,
      g3, be3, g5, be5, g7, be7, g1, be1, (float*)d_out);
}

// Round 11
// 1731.699 us; speedup vs baseline: 1.7679x; 1.0176x over previous
//
#include <hip/hip_runtime.h>
#include <hip/hip_bf16.h>

typedef __hip_bfloat16 bf16;
typedef unsigned char u8;
typedef unsigned long long u64;
typedef __attribute__((ext_vector_type(8))) short short8;
typedef __attribute__((ext_vector_type(16))) float f32x16;
#define DI __device__ __forceinline__

union BF8 { int4 v; short8 s; bf16 h[8]; };
union BF4 { u64 u; bf16 h[4]; };
union I4LL { int4 v; long l[2]; };

// ws layout (bytes):
// phase A: Xt @0 (67,108,864) | projchunk @67,108,864 (50,331,648)
//          cA @117,440,512 (67,108,864) | cB @184,549,376 (33,554,432)
//          wproj @218,103,808 (196,608)
// phase B: transpose -> cAT @0, cBT @67,108,864 (over dead Xt/projchunk)
//          to_fp8 -> cAT8 fp8 [b][pos][512] @117,440,512 (over dead cA)
// phase C: conv1 (bf16, reads cAT/cBT) -> x1 @184,549,376 (over dead cB)
//          then conv3/5/7 (fp8, read cAT8) -> x3 @0, x5 @33,554,432,
//          x7 @67,108,864 (over dead cAT/cBT; after conv1)
// parts @234,881,024 (32 KB): conv3 @0, conv5 @+2048, conv7 @+4096, conv1 @+6144
// wf3 fp8 @234,913,792 | wf5 fp8 @236,093,440 | wf7 fp8 @239,370,240
// wb1 bf16 @245,792,768  (end 245,923,840)

DI u8 f32_fp8(float v) {
  return (u8)(__builtin_amdgcn_cvt_pk_fp8_f32(v, 0.f, 0, false) & 0xff);
}

// ---------------------------------------------------------------- weight prep
__global__ __launch_bounds__(256) void prep_w_kernel(
    const float* __restrict__ w3, const float* __restrict__ w5,
    const float* __restrict__ w7, const float* __restrict__ w1,
    const float* __restrict__ wq_st, const float* __restrict__ wk_st,
    const float* __restrict__ wv_st, const float* __restrict__ wq_phy,
    const float* __restrict__ wk_phy, const float* __restrict__ wv_phy,
    u8* __restrict__ wf3, u8* __restrict__ wf5,
    u8* __restrict__ wf7, bf16* __restrict__ wb1, bf16* __restrict__ wp)
{
  const int N3 = 9 * 65536, N5 = 25 * 65536, N7 = 49 * 65536, N1 = 65536;
  const int NP = 6 * 16384;
  const int total = N3 + N5 + N7 + N1 + NP;
  for (int i = blockIdx.x * 256 + threadIdx.x; i < total; i += gridDim.x * 256) {
    if (i < N3 + N5 + N7) {
      const float* w; int k; int taps;
      u8* dst;
      if (i < N3)           { w = w3; k = i;            taps = 9;  dst = wf3; }
      else if (i < N3 + N5) { w = w5; k = i - N3;       taps = 25; dst = wf5; }
      else                  { w = w7; k = i - N3 - N5;  taps = 49; dst = wf7; }
      int tap = k >> 16, rem = k & 65535;
      int cc = rem >> 12, r2 = rem & 4095;
      int kg = r2 >> 11, r3 = r2 & 2047;
      int oc = r3 >> 4, r4 = r3 & 15;
      int kt = r4 >> 3, j = r4 & 7;
      int ic = cc * 32 + kt * 16 + kg * 8 + j;
      dst[k] = f32_fp8(w[(size_t)(oc * 512 + ic) * taps + tap] * 256.0f);
    } else if (i < N3 + N5 + N7 + N1) {
      int k = i - N3 - N5 - N7;
      int icg = k >> 10, oc = (k >> 3) & 127, j = k & 7;
      wb1[k] = __float2bfloat16(w1[(size_t)oc * 512 + icg * 8 + j]);
    } else {
      int k = i - N3 - N5 - N7 - N1;
      int m = k >> 14, r = k & 16383;
      float v;
      switch (m) {
        case 0: v = wq_st[r]; break;
        case 1: v = wk_st[r]; break;
        case 2: v = wv_st[r]; break;
        case 3: v = wq_phy[r]; break;
        case 4: v = wk_phy[r]; break;
        default: v = wv_phy[r]; break;
      }
      wp[k] = __float2bfloat16(v);
    }
  }
}

// ---------------------------------------------------------------- input transpose
__global__ __launch_bounds__(256) void xpose_in_kernel(
    const float* __restrict__ st, const float* __restrict__ phy,
    bf16* __restrict__ Xt)
{
  __shared__ __align__(16) short Tb[64 * 72];
  const int x = blockIdx.x, b = blockIdx.y;
  const int t = x >> 5, rem = x & 31;
  const int ict = rem >> 4, post = rem & 15;
  const int ic0 = ict * 64, pos0 = post * 64;
  const int tid = threadIdx.x;
  const int rowi = tid >> 2, sub = tid & 3;
  const float* X = t ? phy : st;

  const float* src = X + ((size_t)b * 128 + ic0 + rowi) * 1024 + pos0 + sub * 16;
  #pragma unroll
  for (int q = 0; q < 4; ++q) {
    float4 v = *(const float4*)(src + q * 4);
    BF4 pk;
    pk.h[0] = __float2bfloat16(v.x); pk.h[1] = __float2bfloat16(v.y);
    pk.h[2] = __float2bfloat16(v.z); pk.h[3] = __float2bfloat16(v.w);
    *(u64*)&Tb[rowi * 72 + sub * 16 + q * 4] = pk.u;
  }
  __syncthreads();
  short tmp[16];
  #pragma unroll
  for (int j = 0; j < 16; ++j) tmp[j] = Tb[(sub * 16 + j) * 72 + rowi];
  bf16* dst = Xt + (((size_t)t * 128 + b) * 1024 + pos0 + rowi) * 128 + ic0 + sub * 16;
  *(int4*)dst       = ((int4*)tmp)[0];
  *(int4*)(dst + 8) = ((int4*)tmp)[1];
}

// ---------------------------------------------------------------- MFMA projections
__global__ __launch_bounds__(256) void proj_mfma(
    const bf16* __restrict__ Xt, const bf16* __restrict__ wproj,
    const float* __restrict__ b0, const float* __restrict__ b1,
    const float* __restrict__ b2, const float* __restrict__ b3,
    const float* __restrict__ b4, const float* __restrict__ b5,
    bf16* __restrict__ pc, int cb)
{
  const int pt = blockIdx.x, b = blockIdx.y;
  const int tid = threadIdx.x, wave = tid >> 6, lane = tid & 63;
  const int col = lane & 31, kg = lane >> 5;
  const int pos = pt * 128 + wave * 32 + col;

  f32x16 acc[6];
  #pragma unroll
  for (int m = 0; m < 6; ++m)
    #pragma unroll
    for (int e = 0; e < 16; ++e) acc[m][e] = 0.f;

  const bf16* xst = Xt + ((size_t)b * 1024 + pos) * 128 + kg * 8;
  const bf16* xph = xst + (size_t)128 * 1024 * 128;
  const bf16* wl = wproj + (size_t)(cb + col) * 128 + kg * 8;

  #pragma unroll
  for (int kst = 0; kst < 8; ++kst) {
    short8 bst = *(const short8*)&xst[kst * 16];
    short8 bph = *(const short8*)&xph[kst * 16];
    #pragma unroll
    for (int m = 0; m < 6; ++m) {
      BF8 a; a.v = *(const int4*)&wl[(size_t)m * 16384 + kst * 16];
      acc[m] = __builtin_amdgcn_mfma_f32_32x32x16_bf16(a.s, m < 3 ? bst : bph, acc[m], 0, 0, 0);
    }
  }
  const float* biases[6] = { b0, b1, b2, b3, b4, b5 };
  #pragma unroll
  for (int m = 0; m < 6; ++m) {
    #pragma unroll
    for (int r = 0; r < 16; ++r) {
      const int ocl = (r & 3) + 8 * (r >> 2) + 4 * kg;
      float v = acc[m][r] + biases[m][cb + ocl];
      pc[(((size_t)m * 128 + b) * 32 + ocl) * 1024 + pos] = __float2bfloat16(v);
    }
  }
}

// ---------------------------------------------------------------- MFMA attention
DI void softmax_rows(float p[16])
{
  #pragma unroll
  for (int r = 0; r < 16; ++r) {
    float m = p[r];
    m = fmaxf(m, __shfl_xor(m, 1));
    m = fmaxf(m, __shfl_xor(m, 2));
    m = fmaxf(m, __shfl_xor(m, 4));
    m = fmaxf(m, __shfl_xor(m, 8));
    m = fmaxf(m, __shfl_xor(m, 16));
    float e = __expf(p[r] - m);
    float s = e;
    s += __shfl_xor(s, 1); s += __shfl_xor(s, 2); s += __shfl_xor(s, 4);
    s += __shfl_xor(s, 8); s += __shfl_xor(s, 16);
    p[r] = __fdividef(e, s);
  }
}

template<bool U8OUT>
DI void attn_one_mfma(const BF8& qa0, const BF8& qa1,
                      const bf16* __restrict__ KT, const bf16* __restrict__ VT,
                      bf16* __restrict__ P,
                      const float* __restrict__ resid, void* outp, int lane)
{
  const int col = lane & 31, kg = lane >> 5;
  f32x16 acc;
  #pragma unroll
  for (int e = 0; e < 16; ++e) acc[e] = 0.f;
  BF8 kb0, kb1;
  kb0.v = *(const int4*)&KT[col * 40 + kg * 8];
  kb1.v = *(const int4*)&KT[col * 40 + 16 + kg * 8];
  acc = __builtin_amdgcn_mfma_f32_32x32x16_bf16(qa0.s, kb0.s, acc, 0, 0, 0);
  acc = __builtin_amdgcn_mfma_f32_32x32x16_bf16(qa1.s, kb1.s, acc, 0, 0, 0);
  float p[16];
  #pragma unroll
  for (int r = 0; r < 16; ++r) p[r] = acc[r];
  softmax_rows(p);
  __syncthreads();
  #pragma unroll
  for (int r = 0; r < 16; ++r) {
    int row = (r & 3) + 8 * (r >> 2) + 4 * kg;
    P[row * 40 + col] = __float2bfloat16(p[r]);
  }
  __syncthreads();
  BF8 pa0, pa1, vb0, vb1;
  pa0.v = *(const int4*)&P[col * 40 + kg * 8];
  pa1.v = *(const int4*)&P[col * 40 + 16 + kg * 8];
  vb0.v = *(const int4*)&VT[col * 40 + kg * 8];
  vb1.v = *(const int4*)&VT[col * 40 + 16 + kg * 8];
  #pragma unroll
  for (int e = 0; e < 16; ++e) acc[e] = 0.f;
  acc = __builtin_amdgcn_mfma_f32_32x32x16_bf16(pa0.s, vb0.s, acc, 0, 0, 0);
  acc = __builtin_amdgcn_mfma_f32_32x32x16_bf16(pa1.s, vb1.s, acc, 0, 0, 0);
  #pragma unroll
  for (int r = 0; r < 16; ++r) p[r] = acc[r];
  softmax_rows(p);
  if constexpr (!U8OUT) {
    bf16* op = (bf16*)outp;
    #pragma unroll
    for (int r = 0; r < 16; ++r) {
      int row = (r & 3) + 8 * (r >> 2) + 4 * kg;
      int off = row * 32 + col;
      op[off] = __float2bfloat16(p[r] + resid[off]);
    }
  } else {
    u8* op = (u8*)outp;
    #pragma unroll
    for (int r = 0; r < 16; ++r) {
      int row = (r & 3) + 8 * (r >> 2) + 4 * kg;
      op[row * 32 + col] = (u8)fminf(p[r] * 256.f + 0.5f, 255.f);
    }
  }
}

__global__ __launch_bounds__(64) void attn_mfma_kernel(
    const bf16* __restrict__ pc,
    const float* __restrict__ st, const float* __restrict__ phy,
    bf16* __restrict__ cA, u8* __restrict__ cB, int cb)
{
  __shared__ __align__(16) bf16 KTst[32 * 40], VTst[32 * 40];
  __shared__ __align__(16) bf16 KTph[32 * 40], VTph[32 * 40];
  __shared__ __align__(16) bf16 P[32 * 40];
  const int cl = blockIdx.x, b = blockIdx.y;
  const int c = cb + cl;
  const int lane = threadIdx.x;
  const size_t mstride = (size_t)128 * 32 * 1024;
  const bf16* p0 = pc + ((size_t)b * 32 + cl) * 1024;
  const size_t bc = ((size_t)b * 128 + c) * 1024;

  {
    const int w = lane >> 1, k0 = (lane & 1) * 16;
    const int off = w * 32 + k0;
    bf16* dsts[4] = { KTst, VTst, KTph, VTph };
    const int ms[4] = { 1, 2, 4, 5 };
    #pragma unroll
    for (int t = 0; t < 4; ++t) {
      BF8 r0, r1;
      r0.v = *(const int4*)&p0[(size_t)ms[t] * mstride + off];
      r1.v = *(const int4*)&p0[(size_t)ms[t] * mstride + off + 8];
      #pragma unroll
      for (int j = 0; j < 8; ++j) {
        dsts[t][(k0 + j) * 40 + w]     = r0.h[j];
        dsts[t][(k0 + 8 + j) * 40 + w] = r1.h[j];
      }
    }
  }
  const int col = lane & 31, kg = lane >> 5;
  BF8 qst0, qst1, qph0, qph1;
  qst0.v = *(const int4*)&p0[col * 32 + kg * 8];
  qst1.v = *(const int4*)&p0[col * 32 + 16 + kg * 8];
  qph0.v = *(const int4*)&p0[3 * mstride + col * 32 + kg * 8];
  qph1.v = *(const int4*)&p0[3 * mstride + col * 32 + 16 + kg * 8];
  __syncthreads();

  bf16* aA = cA + (size_t)b * 256 * 1024 + (size_t)c * 1024;
  u8*   aB = cB + (size_t)b * 256 * 1024 + (size_t)c * 1024;
  attn_one_mfma<false>(qst0, qst1, KTst, VTst, P, st + bc,  aA,          lane);
  attn_one_mfma<false>(qph0, qph1, KTph, VTph, P, phy + bc, aA + 131072, lane);
  attn_one_mfma<true >(qph0, qph1, KTst, VTst, P, nullptr,  aB,          lane);
  attn_one_mfma<true >(qst0, qst1, KTph, VTph, P, nullptr,  aB + 131072, lane);
}

// ---------------------------------------------------------------- concat transpose
__global__ __launch_bounds__(256) void transpose_kernel(
    const bf16* __restrict__ cA, const u8* __restrict__ cB,
    bf16* __restrict__ cAT, u8* __restrict__ cBT)
{
  __shared__ __align__(16) short Tb[64 * 72];
  __shared__ __align__(16) u8 T8[64 * 80];
  const int x = blockIdx.x, b = blockIdx.y;
  const int cht = x >> 4, post = x & 15;
  const int pos0 = post * 64;
  const int tid = threadIdx.x;
  const int rowi = tid >> 2, sub = tid & 3;

  if (cht < 4) {
    const int ch0 = cht * 64;
    const bf16* src = cA + ((size_t)b * 256 + ch0 + rowi) * 1024 + pos0 + sub * 16;
    *(int4*)&Tb[rowi * 72 + sub * 16]     = *(const int4*)src;
    *(int4*)&Tb[rowi * 72 + sub * 16 + 8] = *(const int4*)(src + 8);
    __syncthreads();
    short tmp[16];
    #pragma unroll
    for (int j = 0; j < 16; ++j) tmp[j] = Tb[(sub * 16 + j) * 72 + rowi];
    bf16* dst = cAT + ((size_t)b * 1024 + pos0 + rowi) * 256 + ch0 + sub * 16;
    *(int4*)dst       = ((int4*)tmp)[0];
    *(int4*)(dst + 8) = ((int4*)tmp)[1];
  } else {
    const int ch0 = (cht - 4) * 64;
    const u8* src = cB + ((size_t)b * 256 + ch0 + rowi) * 1024 + pos0 + sub * 16;
    *(int4*)&T8[rowi * 80 + sub * 16] = *(const int4*)src;
    __syncthreads();
    u8 tmp[16];
    #pragma unroll
    for (int j = 0; j < 16; ++j) tmp[j] = T8[(sub * 16 + j) * 80 + rowi];
    u8* dst = cBT + ((size_t)b * 1024 + pos0 + rowi) * 256 + ch0 + sub * 16;
    *(int4*)dst = *(int4*)tmp;
  }
}

// ---------------------------------------------------------------- fp8 conversion pass
__global__ __launch_bounds__(256) void to_fp8_kernel(
    const bf16* __restrict__ cAT, const u8* __restrict__ cBT,
    u8* __restrict__ cAT8)
{
  const int idx = blockIdx.x * 256 + threadIdx.x;
  const int g = idx & 31;
  const size_t bp = (size_t)(idx >> 5);
  const int c0 = g * 16;
  float v[16];
  if (c0 < 256) {
    BF8 lo, hi;
    lo.v = *(const int4*)&cAT[bp * 256 + c0];
    hi.v = *(const int4*)&cAT[bp * 256 + c0 + 8];
    #pragma unroll
    for (int j = 0; j < 8; ++j) {
      v[j]     = __bfloat162float(lo.h[j]) * 16.0f;
      v[8 + j] = __bfloat162float(hi.h[j]) * 16.0f;
    }
  } else {
    u64 raw0 = *(const u64*)&cBT[bp * 256 + (c0 - 256)];
    u64 raw1 = *(const u64*)&cBT[bp * 256 + (c0 - 256) + 8];
    #pragma unroll
    for (int j = 0; j < 8; ++j) {
      v[j]     = (float)((raw0 >> (8 * j)) & 255u) * 0.0625f;
      v[8 + j] = (float)((raw1 >> (8 * j)) & 255u) * 0.0625f;
    }
  }
  unsigned lo0 = (__builtin_amdgcn_cvt_pk_fp8_f32(v[0], v[1], 0, false) & 0xffff)
               | ((__builtin_amdgcn_cvt_pk_fp8_f32(v[2], v[3], 0, false) & 0xffff) << 16);
  unsigned hi0 = (__builtin_amdgcn_cvt_pk_fp8_f32(v[4], v[5], 0, false) & 0xffff)
               | ((__builtin_amdgcn_cvt_pk_fp8_f32(v[6], v[7], 0, false) & 0xffff) << 16);
  unsigned lo1 = (__builtin_amdgcn_cvt_pk_fp8_f32(v[8], v[9], 0, false) & 0xffff)
               | ((__builtin_amdgcn_cvt_pk_fp8_f32(v[10], v[11], 0, false) & 0xffff) << 16);
  unsigned hi1 = (__builtin_amdgcn_cvt_pk_fp8_f32(v[12], v[13], 0, false) & 0xffff)
               | ((__builtin_amdgcn_cvt_pk_fp8_f32(v[14], v[15], 0, false) & 0xffff) << 16);
  u64 run0 = (u64)lo0 | ((u64)hi0 << 32);
  u64 run1 = (u64)lo1 | ((u64)hi1 << 32);
  const int sp = (c0 >> 4) & 1;
  u8* d = cAT8 + bp * 512 + (c0 & ~31);
  *(u64*)(d + 8 * sp)      = run0;
  *(u64*)(d + 16 + 8 * sp) = run1;
}

// ---------------------------------------------------------------- staging (bf16)
template<int PCX, int NIT, int H0>
DI void stage_tile(const bf16* cAT, const u8* cBT, short* Xs,
                   int b, int r0, int ic0, int tid)
{
  for (int e = tid; e < NIT; e += 256) {
    int i = e / (PCX * 4);
    int rem = e - i * (PCX * 4);
    int cx = rem >> 2, part = rem & 3;
    int ir = r0 - H0 + i, c = cx - H0;
    int4 val = make_int4(0, 0, 0, 0);
    if ((unsigned)ir < 32u && (unsigned)c < 32u) {
      size_t pbase = ((size_t)b * 1024 + ir * 32 + c) * 256;
      if (ic0 < 256) {
        val = *(const int4*)&cAT[pbase + ic0 + part * 8];
      } else {
        u64 u = *(const u64*)&cBT[pbase + (ic0 - 256) + part * 8];
        BF8 t;
        #pragma unroll
        for (int j = 0; j < 8; ++j)
          t.h[j] = __float2bfloat16((float)((u >> (8 * j)) & 255u) * 0.00390625f);
        val = t.v;
      }
    }
    *(int4*)&Xs[(i * PCX + cx) * 40 + part * 8] = val;
  }
}

// ---------------------------------------------------------------- bf16 MFMA conv (conv1)
template<int KS>
__global__ __launch_bounds__(256, 2) void conv_mfma(
    const bf16* __restrict__ cAT, const u8* __restrict__ cBT,
    const bf16* __restrict__ wt, const float* __restrict__ bias,
    bf16* __restrict__ xout, float* __restrict__ partials)
{
  constexpr int H0 = KS / 2;
  constexpr int PCX = 32 + 2 * H0;
  constexpr int ROWS = 16 + 2 * H0;
  constexpr int NIT = ROWS * PCX * 4;
  __shared__ __align__(16) short Xs[ROWS * PCX * 40];
  __shared__ float rs[256], rq[256];
  const int tix = blockIdx.x, b = blockIdx.y;
  const int ot = tix >> 1, rt = tix & 1;
  const int oc0 = ot * 64, r0 = rt * 16;
  const int tid = threadIdx.x;
  const int wv = tid >> 6, lane = tid & 63;
  const int col = lane & 31, kg = lane >> 5;

  f32x16 acc[2][4];
  #pragma unroll
  for (int i = 0; i < 2; ++i)
    #pragma unroll
    for (int j = 0; j < 4; ++j)
      #pragma unroll
      for (int e = 0; e < 16; ++e) acc[i][j][e] = 0.f;

  for (int cc = 0; cc < 16; ++cc) {
    const int ic0 = cc * 32;
    stage_tile<PCX, NIT, H0>(cAT, cBT, Xs, b, r0, ic0, tid);
    __syncthreads();

    #pragma unroll 1
    for (int ky = 0; ky < KS; ++ky) {
      #pragma unroll
      for (int kx = 0; kx < KS; ++kx) {
        const int tap = ky * KS + kx;
        BF8 a[2][2];
        #pragma unroll
        for (int ob = 0; ob < 2; ++ob)
          #pragma unroll
          for (int kt = 0; kt < 2; ++kt) {
            int icg = cc * 4 + kt * 2 + kg;
            a[ob][kt].v = *(const int4*)&wt[(((size_t)tap * 64 + icg) * 128 + oc0 + ob * 32 + col) * 8];
          }
        #pragma unroll
        for (int rr = 0; rr < 4; ++rr) {
          int entry = ((wv * 4 + rr + ky) * PCX + col + kx) * 40;
          #pragma unroll
          for (int kt = 0; kt < 2; ++kt) {
            short8 bf = *(const short8*)&Xs[entry + (kt * 2 + kg) * 8];
            acc[0][rr] = __builtin_amdgcn_mfma_f32_32x32x16_bf16(a[0][kt].s, bf, acc[0][rr], 0, 0, 0);
            acc[1][rr] = __builtin_amdgcn_mfma_f32_32x32x16_bf16(a[1][kt].s, bf, acc[1][rr], 0, 0, 0);
          }
        }
      }
    }
    __syncthreads();
  }

  float lsum = 0.f, lsq = 0.f;
  #pragma unroll
  for (int ob = 0; ob < 2; ++ob)
    #pragma unroll
    for (int rr = 0; rr < 4; ++rr) {
      const int row = r0 + wv * 4 + rr;
      #pragma unroll
      for (int r = 0; r < 16; ++r) {
        const int oc = oc0 + ob * 32 + (r & 3) + 8 * (r >> 2) + 4 * kg;
        float v = acc[ob][rr][r];
        if (bias) v += bias[oc];
        xout[((size_t)b * 128 + oc) * 1024 + row * 32 + col] = __float2bfloat16(v);
        lsum += v; lsq += v * v;
      }
    }
  rs[tid] = lsum; rq[tid] = lsq;
  __syncthreads();
  for (int s = 128; s > 0; s >>= 1) {
    if (tid < s) { rs[tid] += rs[tid + s]; rq[tid] += rq[tid + s]; }
    __syncthreads();
  }
  if (tid == 0) {
    partials[((size_t)b * 4 + tix) * 2]     = rs[0];
    partials[((size_t)b * 4 + tix) * 2 + 1] = rq[0];
  }
}

// ---------------------------------------------------------------- fp8 MFMA conv (KS=3,5,7)
// 8-row tiles (rr=2), grid (8, b) = 1024 blocks -> 4 blocks/CU (16 waves/CU).
// Per tap: 2 A loads + 2 B ds_reads + 8 MFMAs in two independent streams of 4
// (chain distance 4). Pipes per CU per (tap,cc): MFMA ~1178cy > A 512 > B 256.
template<int KS>
__global__ __launch_bounds__(256, 4) void conv_mfma8(
    const u8* __restrict__ cAT8, const u8* __restrict__ wf,
    bf16* __restrict__ xout, float* __restrict__ partials)
{
  constexpr int H0 = KS / 2;
  constexpr int PCX = 32 + 2 * H0;
  constexpr int ROWS = 8 + 2 * H0;
  constexpr int NIT = ROWS * PCX * 2;
  __shared__ __align__(16) u8 Xs[ROWS * PCX * 48];
  __shared__ float rs[256], rq[256];
  const int tix = blockIdx.x, b = blockIdx.y;   // tix = ot*4 + rt
  const int ot = tix >> 2, rt = tix & 3;
  const int oc0 = ot * 64, r0 = rt * 8;
  const int tid = threadIdx.x;
  const int wv = tid >> 6, lane = tid & 63;
  const int col = lane & 31, kg = lane >> 5;

  f32x16 acc[2][2];   // [ob][rr]
  #pragma unroll
  for (int i = 0; i < 2; ++i)
    #pragma unroll
    for (int j = 0; j < 2; ++j)
      #pragma unroll
      for (int e = 0; e < 16; ++e) acc[i][j][e] = 0.f;

  for (int cc = 0; cc < 16; ++cc) {
    const int ic0 = cc * 32;
    for (int e = tid; e < NIT; e += 256) {
      int entry = e >> 1, hf = e & 1;
      int i = entry / PCX, cx = entry - i * PCX;
      int ir = r0 - H0 + i, c = cx - H0;
      int4 val = make_int4(0, 0, 0, 0);
      if ((unsigned)ir < 32u && (unsigned)c < 32u)
        val = *(const int4*)&cAT8[((size_t)b * 1024 + ir * 32 + c) * 512 + ic0 + hf * 16];
      *(int4*)&Xs[entry * 48 + hf * 16] = val;
    }
    __syncthreads();

    #pragma unroll 1
    for (int ky = 0; ky < KS; ++ky) {
      #pragma unroll
      for (int kx = 0; kx < KS; ++kx) {
        const int tap = ky * KS + kx;
        I4LL a0, a1, bf0, bf1;
        a0.v = *(const int4*)&wf[((((size_t)tap * 16 + cc) * 2 + kg) * 128 + oc0 + col) * 16];
        a1.v = *(const int4*)&wf[((((size_t)tap * 16 + cc) * 2 + kg) * 128 + oc0 + 32 + col) * 16];
        bf0.v = *(const int4*)&Xs[((wv * 2 + 0 + ky) * PCX + col + kx) * 48 + kg * 16];
        bf1.v = *(const int4*)&Xs[((wv * 2 + 1 + ky) * PCX + col + kx) * 48 + kg * 16];
        acc[0][0] = __builtin_amdgcn_mfma_f32_32x32x16_fp8_fp8(a0.l[0], bf0.l[0], acc[0][0], 0, 0, 0);
        acc[1][0] = __builtin_amdgcn_mfma_f32_32x32x16_fp8_fp8(a1.l[0], bf0.l[0], acc[1][0], 0, 0, 0);
        acc[0][1] = __builtin_amdgcn_mfma_f32_32x32x16_fp8_fp8(a0.l[0], bf1.l[0], acc[0][1], 0, 0, 0);
        acc[1][1] = __builtin_amdgcn_mfma_f32_32x32x16_fp8_fp8(a1.l[0], bf1.l[0], acc[1][1], 0, 0, 0);
        acc[0][0] = __builtin_amdgcn_mfma_f32_32x32x16_fp8_fp8(a0.l[1], bf0.l[1], acc[0][0], 0, 0, 0);
        acc[1][0] = __builtin_amdgcn_mfma_f32_32x32x16_fp8_fp8(a1.l[1], bf0.l[1], acc[1][0], 0, 0, 0);
        acc[0][1] = __builtin_amdgcn_mfma_f32_32x32x16_fp8_fp8(a0.l[1], bf1.l[1], acc[0][1], 0, 0, 0);
        acc[1][1] = __builtin_amdgcn_mfma_f32_32x32x16_fp8_fp8(a1.l[1], bf1.l[1], acc[1][1], 0, 0, 0);
      }
    }
    __syncthreads();
  }

  float lsum = 0.f, lsq = 0.f;
  #pragma unroll
  for (int ob = 0; ob < 2; ++ob)
    #pragma unroll
    for (int rr = 0; rr < 2; ++rr) {
      const int row = r0 + wv * 2 + rr;
      #pragma unroll
      for (int r = 0; r < 16; ++r) {
        const int oc = oc0 + ob * 32 + (r & 3) + 8 * (r >> 2) + 4 * kg;
        float v = acc[ob][rr][r] * (1.0f / 4096.0f);
        xout[((size_t)b * 128 + oc) * 1024 + row * 32 + col] = __float2bfloat16(v);
        lsum += v; lsq += v * v;
      }
    }
  rs[tid] = lsum; rq[tid] = lsq;
  __syncthreads();
  for (int s = 128; s > 0; s >>= 1) {
    if (tid < s) { rs[tid] += rs[tid + s]; rq[tid] += rq[tid + s]; }
    __syncthreads();
  }
  if (tid == 0) {
    partials[((size_t)b * 8 + tix) * 2]     = rs[0];
    partials[((size_t)b * 8 + tix) * 2 + 1] = rq[0];
  }
}

// ---------------------------------------------------------------- LN + combine
// p3/p5/p7: 8 partials per batch; p1: 4 per batch.
__global__ __launch_bounds__(256) void final_kernel(
    const bf16* __restrict__ x3, const bf16* __restrict__ x5,
    const bf16* __restrict__ x7, const bf16* __restrict__ x1c,
    const float* __restrict__ p3, const float* __restrict__ p5,
    const float* __restrict__ p7, const float* __restrict__ p1,
    const float* __restrict__ g3, const float* __restrict__ be3,
    const float* __restrict__ g5, const float* __restrict__ be5,
    const float* __restrict__ g7, const float* __restrict__ be7,
    const float* __restrict__ g1, const float* __restrict__ be1,
    float* __restrict__ out)
{
  const int blk = blockIdx.x, b = blockIdx.y, tid = threadIdx.x;
  float s3 = 0, q3 = 0, s5 = 0, q5 = 0, s7 = 0, q7 = 0, s1 = 0, q1 = 0;
  #pragma unroll
  for (int i = 0; i < 8; ++i) {
    int o = (b * 8 + i) * 2;
    s3 += p3[o]; q3 += p3[o + 1];
    s5 += p5[o]; q5 += p5[o + 1];
    s7 += p7[o]; q7 += p7[o + 1];
  }
  #pragma unroll
  for (int i = 0; i < 4; ++i) {
    int o = (b * 4 + i) * 2;
    s1 += p1[o]; q1 += p1[o + 1];
  }
  const float inv = 1.0f / 131072.0f;
  float mu3 = s3 * inv, r3 = rsqrtf(fmaxf(q3 * inv - mu3 * mu3, 0.f) + 1e-5f);
  float mu5 = s5 * inv, r5 = rsqrtf(fmaxf(q5 * inv - mu5 * mu5, 0.f) + 1e-5f);
  float mu7 = s7 * inv, r7 = rsqrtf(fmaxf(q7 * inv - mu7 * mu7, 0.f) + 1e-5f);
  float mu1 = s1 * inv, r1 = rsqrtf(fmaxf(q1 * inv - mu1 * mu1, 0.f) + 1e-5f);
  const size_t bb = (size_t)b * 131072;
  for (int it = 0; it < 8; ++it) {
    int e0 = (it * 2048 + blk * 256 + tid) * 8;
    BF8 a3, a5, a7, a1;
    a3.v = *(const int4*)&x3[bb + e0];
    a5.v = *(const int4*)&x5[bb + e0];
    a7.v = *(const int4*)&x7[bb + e0];
    a1.v = *(const int4*)&x1c[bb + e0];
    float G3[8], B3[8], G5[8], B5[8], G7[8], B7[8], G1[8], B1[8];
    *(float4*)&G3[0] = *(const float4*)&g3[e0];  *(float4*)&G3[4] = *(const float4*)&g3[e0 + 4];
    *(float4*)&B3[0] = *(const float4*)&be3[e0]; *(float4*)&B3[4] = *(const float4*)&be3[e0 + 4];
    *(float4*)&G5[0] = *(const float4*)&g5[e0];  *(float4*)&G5[4] = *(const float4*)&g5[e0 + 4];
    *(float4*)&B5[0] = *(const float4*)&be5[e0]; *(float4*)&B5[4] = *(const float4*)&be5[e0 + 4];
    *(float4*)&G7[0] = *(const float4*)&g7[e0];  *(float4*)&G7[4] = *(const float4*)&g7[e0 + 4];
    *(float4*)&B7[0] = *(const float4*)&be7[e0]; *(float4*)&B7[4] = *(const float4*)&be7[e0 + 4];
    *(float4*)&G1[0] = *(const float4*)&g1[e0];  *(float4*)&G1[4] = *(const float4*)&g1[e0 + 4];
    *(float4*)&B1[0] = *(const float4*)&be1[e0]; *(float4*)&B1[4] = *(const float4*)&be1[e0 + 4];
    float res[8];
    #pragma unroll
    for (int j = 0; j < 8; ++j) {
      float v3 = (__bfloat162float(a3.h[j]) - mu3) * r3 * G3[j] + B3[j];
      float v5 = (__bfloat162float(a5.h[j]) - mu5) * r5 * G5[j] + B5[j];
      float v7 = (__bfloat162float(a7.h[j]) - mu7) * r7 * G7[j] + B7[j];
      float m = (v3 + v5 + v7) * (1.0f / 3.0f);
      float sg = 1.0f / (1.0f + __expf(-m));
      float v1 = (__bfloat162float(a1.h[j]) - mu1) * r1 * G1[j] + B1[j];
      res[j] = sg + v1;
    }
    *(float4*)&out[bb + e0]     = make_float4(res[0], res[1], res[2], res[3]);
    *(float4*)&out[bb + e0 + 4] = make_float4(res[4], res[5], res[6], res[7]);
  }
}

// ---------------------------------------------------------------- launch
extern "C" void kernel_launch(void* const* d_in, const int* in_sizes, int n_in,
                              void* d_out, int out_size, void* d_ws, size_t ws_size,
                              hipStream_t stream)
{
  (void)in_sizes; (void)n_in; (void)out_size; (void)ws_size;
  const float* st     = (const float*)d_in[0];
  const float* phy    = (const float*)d_in[1];
  const float* wq_st  = (const float*)d_in[2];
  const float* bq_st  = (const float*)d_in[3];
  const float* wk_st  = (const float*)d_in[4];
  const float* bk_st  = (const float*)d_in[5];
  const float* wv_st  = (const float*)d_in[6];
  const float* bv_st  = (const float*)d_in[7];
  const float* wq_phy = (const float*)d_in[8];
  const float* bq_phy = (const float*)d_in[9];
  const float* wk_phy = (const float*)d_in[10];
  const float* bk_phy = (const float*)d_in[11];
  const float* wv_phy = (const float*)d_in[12];
  const float* bv_phy = (const float*)d_in[13];
  const float* w3  = (const float*)d_in[14];
  const float* g3  = (const float*)d_in[15];
  const float* be3 = (const float*)d_in[16];
  const float* w5  = (const float*)d_in[17];
  const float* g5  = (const float*)d_in[18];
  const float* be5 = (const float*)d_in[19];
  const float* w7  = (const float*)d_in[20];
  const float* g7  = (const float*)d_in[21];
  const float* be7 = (const float*)d_in[22];
  const float* w1  = (const float*)d_in[23];
  const float* g1  = (const float*)d_in[24];
  const float* be1 = (const float*)d_in[25];
  const float* b1  = (const float*)d_in[26];

  char* ws = (char*)d_ws;
  // phase A
  bf16* Xt        = (bf16*)ws;
  bf16* projchunk = (bf16*)(ws + 67108864ULL);
  bf16* cA        = (bf16*)(ws + 117440512ULL);
  u8*   cB        = (u8*)(ws + 184549376ULL);
  bf16* wproj     = (bf16*)(ws + 218103808ULL);
  // phase B/C
  bf16* cAT       = (bf16*)ws;
  u8*   cBT       = (u8*)(ws + 67108864ULL);
  u8*   cAT8      = (u8*)(ws + 117440512ULL);     // over dead cA
  bf16* x1b       = (bf16*)(ws + 184549376ULL);   // over dead cB (conv1 first)
  bf16* x3b       = (bf16*)ws;                    // over dead cAT (after conv1)
  bf16* x5b       = (bf16*)(ws + 33554432ULL);
  bf16* x7b       = (bf16*)(ws + 67108864ULL);    // over dead cBT
  float* parts    = (float*)(ws + 234881024ULL);
  u8*   wf3       = (u8*)(ws + 234913792ULL);
  u8*   wf5       = (u8*)(ws + 236093440ULL);
  u8*   wf7       = (u8*)(ws + 239370240ULL);
  bf16* wb1       = (bf16*)(ws + 245792768ULL);

  prep_w_kernel<<<dim3(2048), 256, 0, stream>>>(w3, w5, w7, w1,
      wq_st, wk_st, wv_st, wq_phy, wk_phy, wv_phy,
      wf3, wf5, wf7, wb1, wproj);
  xpose_in_kernel<<<dim3(64, 128), 256, 0, stream>>>(st, phy, Xt);

  for (int g = 0; g < 4; ++g) {
    proj_mfma<<<dim3(8, 128), 256, 0, stream>>>(Xt, wproj,
        bq_st, bk_st, bv_st, bq_phy, bk_phy, bv_phy, projchunk, g * 32);
    attn_mfma_kernel<<<dim3(32, 128), 64, 0, stream>>>(projchunk, st, phy,
        cA, cB, g * 32);
  }
  transpose_kernel<<<dim3(128, 128), 256, 0, stream>>>(cA, cB, cAT, cBT);
  to_fp8_kernel<<<dim3(16384), 256, 0, stream>>>(cAT, cBT, cAT8);

  conv_mfma<1><<<dim3(4, 128), 256, 0, stream>>>(cAT, cBT, wb1, b1, x1b, parts + 6144);
  conv_mfma8<3><<<dim3(8, 128), 256, 0, stream>>>(cAT8, wf3, x3b, parts);
  conv_mfma8<5><<<dim3(8, 128), 256, 0, stream>>>(cAT8, wf5, x5b, parts + 2048);
  conv_mfma8<7><<<dim3(8, 128), 256, 0, stream>>>(cAT8, wf7, x7b, parts + 4096);

  final_kernel<<<dim3(8, 128), 256, 0, stream>>>(x3b, x5b, x7b, x1b,
      parts, parts + 2048, parts + 4096, parts + 6144,
      g3, be3, g5, be5, g7, be7, g1, be1, (float*)d_out);
}

// Round 12
// 1640.169 us; speedup vs baseline: 1.8666x; 1.0558x over previous
//
#include <hip/hip_runtime.h>
#include <hip/hip_bf16.h>

typedef __hip_bfloat16 bf16;
typedef unsigned char u8;
typedef unsigned long long u64;
typedef __attribute__((ext_vector_type(8))) short short8;
typedef __attribute__((ext_vector_type(16))) float f32x16;
#define DI __device__ __forceinline__

union BF8 { int4 v; short8 s; bf16 h[8]; };
union BF4 { u64 u; bf16 h[4]; };
union I4LL { int4 v; long l[2]; };

// ws layout (bytes):
// phase A: Xt @0 (67,108,864) | projchunk @67,108,864 (50,331,648)
//          cA @117,440,512 (67,108,864) | cB @184,549,376 (33,554,432)
//          wproj @218,103,808 (196,608)
// phase B: transpose -> cAT @0, cBT @67,108,864 | to_fp8 -> cAT8 @117,440,512
// phase C: conv1 -> x1 @184,549,376; conv3/5/7 (fp8) -> x3 @0, x5 @33,554,432,
//          x7 @67,108,864
// parts @234,881,024 (32 KB): conv3 @0, conv5 @+2048, conv7 @+4096, conv1 @+6144
// wf3 @234,913,792 | wf5 @236,093,440 | wf7 @239,370,240 | wb1 @245,792,768

DI u8 f32_fp8(float v) {
  return (u8)(__builtin_amdgcn_cvt_pk_fp8_f32(v, 0.f, 0, false) & 0xff);
}

// ---------------------------------------------------------------- weight prep
__global__ __launch_bounds__(256) void prep_w_kernel(
    const float* __restrict__ w3, const float* __restrict__ w5,
    const float* __restrict__ w7, const float* __restrict__ w1,
    const float* __restrict__ wq_st, const float* __restrict__ wk_st,
    const float* __restrict__ wv_st, const float* __restrict__ wq_phy,
    const float* __restrict__ wk_phy, const float* __restrict__ wv_phy,
    u8* __restrict__ wf3, u8* __restrict__ wf5,
    u8* __restrict__ wf7, bf16* __restrict__ wb1, bf16* __restrict__ wp)
{
  const int N3 = 9 * 65536, N5 = 25 * 65536, N7 = 49 * 65536, N1 = 65536;
  const int NP = 6 * 16384;
  const int total = N3 + N5 + N7 + N1 + NP;
  for (int i = blockIdx.x * 256 + threadIdx.x; i < total; i += gridDim.x * 256) {
    if (i < N3 + N5 + N7) {
      const float* w; int k; int taps;
      u8* dst;
      if (i < N3)           { w = w3; k = i;            taps = 9;  dst = wf3; }
      else if (i < N3 + N5) { w = w5; k = i - N3;       taps = 25; dst = wf5; }
      else                  { w = w7; k = i - N3 - N5;  taps = 49; dst = wf7; }
      int tap = k >> 16, rem = k & 65535;
      int cc = rem >> 12, r2 = rem & 4095;
      int kg = r2 >> 11, r3 = r2 & 2047;
      int oc = r3 >> 4, r4 = r3 & 15;
      int kt = r4 >> 3, j = r4 & 7;
      int ic = cc * 32 + kt * 16 + kg * 8 + j;
      dst[k] = f32_fp8(w[(size_t)(oc * 512 + ic) * taps + tap] * 256.0f);
    } else if (i < N3 + N5 + N7 + N1) {
      int k = i - N3 - N5 - N7;
      int icg = k >> 10, oc = (k >> 3) & 127, j = k & 7;
      wb1[k] = __float2bfloat16(w1[(size_t)oc * 512 + icg * 8 + j]);
    } else {
      int k = i - N3 - N5 - N7 - N1;
      int m = k >> 14, r = k & 16383;
      float v;
      switch (m) {
        case 0: v = wq_st[r]; break;
        case 1: v = wk_st[r]; break;
        case 2: v = wv_st[r]; break;
        case 3: v = wq_phy[r]; break;
        case 4: v = wk_phy[r]; break;
        default: v = wv_phy[r]; break;
      }
      wp[k] = __float2bfloat16(v);
    }
  }
}

// ---------------------------------------------------------------- input transpose
__global__ __launch_bounds__(256) void xpose_in_kernel(
    const float* __restrict__ st, const float* __restrict__ phy,
    bf16* __restrict__ Xt)
{
  __shared__ __align__(16) short Tb[64 * 72];
  const int x = blockIdx.x, b = blockIdx.y;
  const int t = x >> 5, rem = x & 31;
  const int ict = rem >> 4, post = rem & 15;
  const int ic0 = ict * 64, pos0 = post * 64;
  const int tid = threadIdx.x;
  const int rowi = tid >> 2, sub = tid & 3;
  const float* X = t ? phy : st;

  const float* src = X + ((size_t)b * 128 + ic0 + rowi) * 1024 + pos0 + sub * 16;
  #pragma unroll
  for (int q = 0; q < 4; ++q) {
    float4 v = *(const float4*)(src + q * 4);
    BF4 pk;
    pk.h[0] = __float2bfloat16(v.x); pk.h[1] = __float2bfloat16(v.y);
    pk.h[2] = __float2bfloat16(v.z); pk.h[3] = __float2bfloat16(v.w);
    *(u64*)&Tb[rowi * 72 + sub * 16 + q * 4] = pk.u;
  }
  __syncthreads();
  short tmp[16];
  #pragma unroll
  for (int j = 0; j < 16; ++j) tmp[j] = Tb[(sub * 16 + j) * 72 + rowi];
  bf16* dst = Xt + (((size_t)t * 128 + b) * 1024 + pos0 + rowi) * 128 + ic0 + sub * 16;
  *(int4*)dst       = ((int4*)tmp)[0];
  *(int4*)(dst + 8) = ((int4*)tmp)[1];
}

// ---------------------------------------------------------------- MFMA projections
__global__ __launch_bounds__(256) void proj_mfma(
    const bf16* __restrict__ Xt, const bf16* __restrict__ wproj,
    const float* __restrict__ b0, const float* __restrict__ b1,
    const float* __restrict__ b2, const float* __restrict__ b3,
    const float* __restrict__ b4, const float* __restrict__ b5,
    bf16* __restrict__ pc, int cb)
{
  const int pt = blockIdx.x, b = blockIdx.y;
  const int tid = threadIdx.x, wave = tid >> 6, lane = tid & 63;
  const int col = lane & 31, kg = lane >> 5;
  const int pos = pt * 128 + wave * 32 + col;

  f32x16 acc[6];
  #pragma unroll
  for (int m = 0; m < 6; ++m)
    #pragma unroll
    for (int e = 0; e < 16; ++e) acc[m][e] = 0.f;

  const bf16* xst = Xt + ((size_t)b * 1024 + pos) * 128 + kg * 8;
  const bf16* xph = xst + (size_t)128 * 1024 * 128;
  const bf16* wl = wproj + (size_t)(cb + col) * 128 + kg * 8;

  #pragma unroll
  for (int kst = 0; kst < 8; ++kst) {
    short8 bst = *(const short8*)&xst[kst * 16];
    short8 bph = *(const short8*)&xph[kst * 16];
    #pragma unroll
    for (int m = 0; m < 6; ++m) {
      BF8 a; a.v = *(const int4*)&wl[(size_t)m * 16384 + kst * 16];
      acc[m] = __builtin_amdgcn_mfma_f32_32x32x16_bf16(a.s, m < 3 ? bst : bph, acc[m], 0, 0, 0);
    }
  }
  const float* biases[6] = { b0, b1, b2, b3, b4, b5 };
  #pragma unroll
  for (int m = 0; m < 6; ++m) {
    #pragma unroll
    for (int r = 0; r < 16; ++r) {
      const int ocl = (r & 3) + 8 * (r >> 2) + 4 * kg;
      float v = acc[m][r] + biases[m][cb + ocl];
      pc[(((size_t)m * 128 + b) * 32 + ocl) * 1024 + pos] = __float2bfloat16(v);
    }
  }
}

// ---------------------------------------------------------------- MFMA attention
DI void softmax_rows(float p[16])
{
  #pragma unroll
  for (int r = 0; r < 16; ++r) {
    float m = p[r];
    m = fmaxf(m, __shfl_xor(m, 1));
    m = fmaxf(m, __shfl_xor(m, 2));
    m = fmaxf(m, __shfl_xor(m, 4));
    m = fmaxf(m, __shfl_xor(m, 8));
    m = fmaxf(m, __shfl_xor(m, 16));
    float e = __expf(p[r] - m);
    float s = e;
    s += __shfl_xor(s, 1); s += __shfl_xor(s, 2); s += __shfl_xor(s, 4);
    s += __shfl_xor(s, 8); s += __shfl_xor(s, 16);
    p[r] = __fdividef(e, s);
  }
}

template<bool U8OUT>
DI void attn_one_mfma(const BF8& qa0, const BF8& qa1,
                      const bf16* __restrict__ KT, const bf16* __restrict__ VT,
                      bf16* __restrict__ P,
                      const float* __restrict__ resid, void* outp, int lane)
{
  const int col = lane & 31, kg = lane >> 5;
  f32x16 acc;
  #pragma unroll
  for (int e = 0; e < 16; ++e) acc[e] = 0.f;
  BF8 kb0, kb1;
  kb0.v = *(const int4*)&KT[col * 40 + kg * 8];
  kb1.v = *(const int4*)&KT[col * 40 + 16 + kg * 8];
  acc = __builtin_amdgcn_mfma_f32_32x32x16_bf16(qa0.s, kb0.s, acc, 0, 0, 0);
  acc = __builtin_amdgcn_mfma_f32_32x32x16_bf16(qa1.s, kb1.s, acc, 0, 0, 0);
  float p[16];
  #pragma unroll
  for (int r = 0; r < 16; ++r) p[r] = acc[r];
  softmax_rows(p);
  __syncthreads();
  #pragma unroll
  for (int r = 0; r < 16; ++r) {
    int row = (r & 3) + 8 * (r >> 2) + 4 * kg;
    P[row * 40 + col] = __float2bfloat16(p[r]);
  }
  __syncthreads();
  BF8 pa0, pa1, vb0, vb1;
  pa0.v = *(const int4*)&P[col * 40 + kg * 8];
  pa1.v = *(const int4*)&P[col * 40 + 16 + kg * 8];
  vb0.v = *(const int4*)&VT[col * 40 + kg * 8];
  vb1.v = *(const int4*)&VT[col * 40 + 16 + kg * 8];
  #pragma unroll
  for (int e = 0; e < 16; ++e) acc[e] = 0.f;
  acc = __builtin_amdgcn_mfma_f32_32x32x16_bf16(pa0.s, vb0.s, acc, 0, 0, 0);
  acc = __builtin_amdgcn_mfma_f32_32x32x16_bf16(pa1.s, vb1.s, acc, 0, 0, 0);
  #pragma unroll
  for (int r = 0; r < 16; ++r) p[r] = acc[r];
  softmax_rows(p);
  if constexpr (!U8OUT) {
    bf16* op = (bf16*)outp;
    #pragma unroll
    for (int r = 0; r < 16; ++r) {
      int row = (r & 3) + 8 * (r >> 2) + 4 * kg;
      int off = row * 32 + col;
      op[off] = __float2bfloat16(p[r] + resid[off]);
    }
  } else {
    u8* op = (u8*)outp;
    #pragma unroll
    for (int r = 0; r < 16; ++r) {
      int row = (r & 3) + 8 * (r >> 2) + 4 * kg;
      op[row * 32 + col] = (u8)fminf(p[r] * 256.f + 0.5f, 255.f);
    }
  }
}

__global__ __launch_bounds__(64) void attn_mfma_kernel(
    const bf16* __restrict__ pc,
    const float* __restrict__ st, const float* __restrict__ phy,
    bf16* __restrict__ cA, u8* __restrict__ cB, int cb)
{
  __shared__ __align__(16) bf16 KTst[32 * 40], VTst[32 * 40];
  __shared__ __align__(16) bf16 KTph[32 * 40], VTph[32 * 40];
  __shared__ __align__(16) bf16 P[32 * 40];
  const int cl = blockIdx.x, b = blockIdx.y;
  const int c = cb + cl;
  const int lane = threadIdx.x;
  const size_t mstride = (size_t)128 * 32 * 1024;
  const bf16* p0 = pc + ((size_t)b * 32 + cl) * 1024;
  const size_t bc = ((size_t)b * 128 + c) * 1024;

  {
    const int w = lane >> 1, k0 = (lane & 1) * 16;
    const int off = w * 32 + k0;
    bf16* dsts[4] = { KTst, VTst, KTph, VTph };
    const int ms[4] = { 1, 2, 4, 5 };
    #pragma unroll
    for (int t = 0; t < 4; ++t) {
      BF8 r0, r1;
      r0.v = *(const int4*)&p0[(size_t)ms[t] * mstride + off];
      r1.v = *(const int4*)&p0[(size_t)ms[t] * mstride + off + 8];
      #pragma unroll
      for (int j = 0; j < 8; ++j) {
        dsts[t][(k0 + j) * 40 + w]     = r0.h[j];
        dsts[t][(k0 + 8 + j) * 40 + w] = r1.h[j];
      }
    }
  }
  const int col = lane & 31, kg = lane >> 5;
  BF8 qst0, qst1, qph0, qph1;
  qst0.v = *(const int4*)&p0[col * 32 + kg * 8];
  qst1.v = *(const int4*)&p0[col * 32 + 16 + kg * 8];
  qph0.v = *(const int4*)&p0[3 * mstride + col * 32 + kg * 8];
  qph1.v = *(const int4*)&p0[3 * mstride + col * 32 + 16 + kg * 8];
  __syncthreads();

  bf16* aA = cA + (size_t)b * 256 * 1024 + (size_t)c * 1024;
  u8*   aB = cB + (size_t)b * 256 * 1024 + (size_t)c * 1024;
  attn_one_mfma<false>(qst0, qst1, KTst, VTst, P, st + bc,  aA,          lane);
  attn_one_mfma<false>(qph0, qph1, KTph, VTph, P, phy + bc, aA + 131072, lane);
  attn_one_mfma<true >(qph0, qph1, KTst, VTst, P, nullptr,  aB,          lane);
  attn_one_mfma<true >(qst0, qst1, KTph, VTph, P, nullptr,  aB + 131072, lane);
}

// ---------------------------------------------------------------- concat transpose
__global__ __launch_bounds__(256) void transpose_kernel(
    const bf16* __restrict__ cA, const u8* __restrict__ cB,
    bf16* __restrict__ cAT, u8* __restrict__ cBT)
{
  __shared__ __align__(16) short Tb[64 * 72];
  __shared__ __align__(16) u8 T8[64 * 80];
  const int x = blockIdx.x, b = blockIdx.y;
  const int cht = x >> 4, post = x & 15;
  const int pos0 = post * 64;
  const int tid = threadIdx.x;
  const int rowi = tid >> 2, sub = tid & 3;

  if (cht < 4) {
    const int ch0 = cht * 64;
    const bf16* src = cA + ((size_t)b * 256 + ch0 + rowi) * 1024 + pos0 + sub * 16;
    *(int4*)&Tb[rowi * 72 + sub * 16]     = *(const int4*)src;
    *(int4*)&Tb[rowi * 72 + sub * 16 + 8] = *(const int4*)(src + 8);
    __syncthreads();
    short tmp[16];
    #pragma unroll
    for (int j = 0; j < 16; ++j) tmp[j] = Tb[(sub * 16 + j) * 72 + rowi];
    bf16* dst = cAT + ((size_t)b * 1024 + pos0 + rowi) * 256 + ch0 + sub * 16;
    *(int4*)dst       = ((int4*)tmp)[0];
    *(int4*)(dst + 8) = ((int4*)tmp)[1];
  } else {
    const int ch0 = (cht - 4) * 64;
    const u8* src = cB + ((size_t)b * 256 + ch0 + rowi) * 1024 + pos0 + sub * 16;
    *(int4*)&T8[rowi * 80 + sub * 16] = *(const int4*)src;
    __syncthreads();
    u8 tmp[16];
    #pragma unroll
    for (int j = 0; j < 16; ++j) tmp[j] = T8[(sub * 16 + j) * 80 + rowi];
    u8* dst = cBT + ((size_t)b * 1024 + pos0 + rowi) * 256 + ch0 + sub * 16;
    *(int4*)dst = *(int4*)tmp;
  }
}

// ---------------------------------------------------------------- fp8 conversion pass
__global__ __launch_bounds__(256) void to_fp8_kernel(
    const bf16* __restrict__ cAT, const u8* __restrict__ cBT,
    u8* __restrict__ cAT8)
{
  const int idx = blockIdx.x * 256 + threadIdx.x;
  const int g = idx & 31;
  const size_t bp = (size_t)(idx >> 5);
  const int c0 = g * 16;
  float v[16];
  if (c0 < 256) {
    BF8 lo, hi;
    lo.v = *(const int4*)&cAT[bp * 256 + c0];
    hi.v = *(const int4*)&cAT[bp * 256 + c0 + 8];
    #pragma unroll
    for (int j = 0; j < 8; ++j) {
      v[j]     = __bfloat162float(lo.h[j]) * 16.0f;
      v[8 + j] = __bfloat162float(hi.h[j]) * 16.0f;
    }
  } else {
    u64 raw0 = *(const u64*)&cBT[bp * 256 + (c0 - 256)];
    u64 raw1 = *(const u64*)&cBT[bp * 256 + (c0 - 256) + 8];
    #pragma unroll
    for (int j = 0; j < 8; ++j) {
      v[j]     = (float)((raw0 >> (8 * j)) & 255u) * 0.0625f;
      v[8 + j] = (float)((raw1 >> (8 * j)) & 255u) * 0.0625f;
    }
  }
  unsigned lo0 = (__builtin_amdgcn_cvt_pk_fp8_f32(v[0], v[1], 0, false) & 0xffff)
               | ((__builtin_amdgcn_cvt_pk_fp8_f32(v[2], v[3], 0, false) & 0xffff) << 16);
  unsigned hi0 = (__builtin_amdgcn_cvt_pk_fp8_f32(v[4], v[5], 0, false) & 0xffff)
               | ((__builtin_amdgcn_cvt_pk_fp8_f32(v[6], v[7], 0, false) & 0xffff) << 16);
  unsigned lo1 = (__builtin_amdgcn_cvt_pk_fp8_f32(v[8], v[9], 0, false) & 0xffff)
               | ((__builtin_amdgcn_cvt_pk_fp8_f32(v[10], v[11], 0, false) & 0xffff) << 16);
  unsigned hi1 = (__builtin_amdgcn_cvt_pk_fp8_f32(v[12], v[13], 0, false) & 0xffff)
               | ((__builtin_amdgcn_cvt_pk_fp8_f32(v[14], v[15], 0, false) & 0xffff) << 16);
  u64 run0 = (u64)lo0 | ((u64)hi0 << 32);
  u64 run1 = (u64)lo1 | ((u64)hi1 << 32);
  const int sp = (c0 >> 4) & 1;
  u8* d = cAT8 + bp * 512 + (c0 & ~31);
  *(u64*)(d + 8 * sp)      = run0;
  *(u64*)(d + 16 + 8 * sp) = run1;
}

// ---------------------------------------------------------------- staging (bf16)
template<int PCX, int NIT, int H0>
DI void stage_tile(const bf16* cAT, const u8* cBT, short* Xs,
                   int b, int r0, int ic0, int tid)
{
  for (int e = tid; e < NIT; e += 256) {
    int i = e / (PCX * 4);
    int rem = e - i * (PCX * 4);
    int cx = rem >> 2, part = rem & 3;
    int ir = r0 - H0 + i, c = cx - H0;
    int4 val = make_int4(0, 0, 0, 0);
    if ((unsigned)ir < 32u && (unsigned)c < 32u) {
      size_t pbase = ((size_t)b * 1024 + ir * 32 + c) * 256;
      if (ic0 < 256) {
        val = *(const int4*)&cAT[pbase + ic0 + part * 8];
      } else {
        u64 u = *(const u64*)&cBT[pbase + (ic0 - 256) + part * 8];
        BF8 t;
        #pragma unroll
        for (int j = 0; j < 8; ++j)
          t.h[j] = __float2bfloat16((float)((u >> (8 * j)) & 255u) * 0.00390625f);
        val = t.v;
      }
    }
    *(int4*)&Xs[(i * PCX + cx) * 40 + part * 8] = val;
  }
}

// ---------------------------------------------------------------- bf16 MFMA conv (conv1)
// 1-D grid 512, XCD-swizzled: logical = (h%8)*64 + h/8; b = logical>>2, tix = logical&3.
template<int KS>
__global__ __launch_bounds__(256, 2) void conv_mfma(
    const bf16* __restrict__ cAT, const u8* __restrict__ cBT,
    const bf16* __restrict__ wt, const float* __restrict__ bias,
    bf16* __restrict__ xout, float* __restrict__ partials)
{
  constexpr int H0 = KS / 2;
  constexpr int PCX = 32 + 2 * H0;
  constexpr int ROWS = 16 + 2 * H0;
  constexpr int NIT = ROWS * PCX * 4;
  __shared__ __align__(16) short Xs[ROWS * PCX * 40];
  __shared__ float rs[256], rq[256];
  const int h = blockIdx.x;
  const int logical = (h & 7) * 64 + (h >> 3);
  const int b = logical >> 2, tix = logical & 3;
  const int ot = tix >> 1, rt = tix & 1;
  const int oc0 = ot * 64, r0 = rt * 16;
  const int tid = threadIdx.x;
  const int wv = tid >> 6, lane = tid & 63;
  const int col = lane & 31, kg = lane >> 5;

  f32x16 acc[2][4];
  #pragma unroll
  for (int i = 0; i < 2; ++i)
    #pragma unroll
    for (int j = 0; j < 4; ++j)
      #pragma unroll
      for (int e = 0; e < 16; ++e) acc[i][j][e] = 0.f;

  for (int cc = 0; cc < 16; ++cc) {
    const int ic0 = cc * 32;
    stage_tile<PCX, NIT, H0>(cAT, cBT, Xs, b, r0, ic0, tid);
    __syncthreads();

    #pragma unroll 1
    for (int ky = 0; ky < KS; ++ky) {
      #pragma unroll
      for (int kx = 0; kx < KS; ++kx) {
        const int tap = ky * KS + kx;
        BF8 a[2][2];
        #pragma unroll
        for (int ob = 0; ob < 2; ++ob)
          #pragma unroll
          for (int kt = 0; kt < 2; ++kt) {
            int icg = cc * 4 + kt * 2 + kg;
            a[ob][kt].v = *(const int4*)&wt[(((size_t)tap * 64 + icg) * 128 + oc0 + ob * 32 + col) * 8];
          }
        #pragma unroll
        for (int rr = 0; rr < 4; ++rr) {
          int entry = ((wv * 4 + rr + ky) * PCX + col + kx) * 40;
          #pragma unroll
          for (int kt = 0; kt < 2; ++kt) {
            short8 bf = *(const short8*)&Xs[entry + (kt * 2 + kg) * 8];
            acc[0][rr] = __builtin_amdgcn_mfma_f32_32x32x16_bf16(a[0][kt].s, bf, acc[0][rr], 0, 0, 0);
            acc[1][rr] = __builtin_amdgcn_mfma_f32_32x32x16_bf16(a[1][kt].s, bf, acc[1][rr], 0, 0, 0);
          }
        }
      }
    }
    __syncthreads();
  }

  float lsum = 0.f, lsq = 0.f;
  #pragma unroll
  for (int ob = 0; ob < 2; ++ob)
    #pragma unroll
    for (int rr = 0; rr < 4; ++rr) {
      const int row = r0 + wv * 4 + rr;
      #pragma unroll
      for (int r = 0; r < 16; ++r) {
        const int oc = oc0 + ob * 32 + (r & 3) + 8 * (r >> 2) + 4 * kg;
        float v = acc[ob][rr][r];
        if (bias) v += bias[oc];
        xout[((size_t)b * 128 + oc) * 1024 + row * 32 + col] = __float2bfloat16(v);
        lsum += v; lsq += v * v;
      }
    }
  rs[tid] = lsum; rq[tid] = lsq;
  __syncthreads();
  for (int s = 128; s > 0; s >>= 1) {
    if (tid < s) { rs[tid] += rs[tid + s]; rq[tid] += rq[tid + s]; }
    __syncthreads();
  }
  if (tid == 0) {
    partials[((size_t)b * 4 + tix) * 2]     = rs[0];
    partials[((size_t)b * 4 + tix) * 2 + 1] = rq[0];
  }
}

// ---------------------------------------------------------------- fp8 MFMA conv (KS=3,5,7)
// 1-D grid 1024, XCD-swizzled: logical = (h%8)*128 + h/8; b = logical>>3,
// tix = logical&7. XCD x owns b in [16x, 16x+16) -> all 8 row-tiles of one
// image co-resident on one XCD -> halo re-reads hit L2 (512 KB/image).
template<int KS>
__global__ __launch_bounds__(256, 4) void conv_mfma8(
    const u8* __restrict__ cAT8, const u8* __restrict__ wf,
    bf16* __restrict__ xout, float* __restrict__ partials)
{
  constexpr int H0 = KS / 2;
  constexpr int PCX = 32 + 2 * H0;
  constexpr int ROWS = 8 + 2 * H0;
  constexpr int NIT = ROWS * PCX * 2;
  __shared__ __align__(16) u8 Xs[ROWS * PCX * 48];
  __shared__ float rs[256], rq[256];
  const int h = blockIdx.x;
  const int logical = (h & 7) * 128 + (h >> 3);
  const int b = logical >> 3, tix = logical & 7;
  const int ot = tix >> 2, rt = tix & 3;
  const int oc0 = ot * 64, r0 = rt * 8;
  const int tid = threadIdx.x;
  const int wv = tid >> 6, lane = tid & 63;
  const int col = lane & 31, kg = lane >> 5;

  f32x16 acc[2][2];
  #pragma unroll
  for (int i = 0; i < 2; ++i)
    #pragma unroll
    for (int j = 0; j < 2; ++j)
      #pragma unroll
      for (int e = 0; e < 16; ++e) acc[i][j][e] = 0.f;

  for (int cc = 0; cc < 16; ++cc) {
    const int ic0 = cc * 32;
    for (int e = tid; e < NIT; e += 256) {
      int entry = e >> 1, hf = e & 1;
      int i = entry / PCX, cx = entry - i * PCX;
      int ir = r0 - H0 + i, c = cx - H0;
      int4 val = make_int4(0, 0, 0, 0);
      if ((unsigned)ir < 32u && (unsigned)c < 32u)
        val = *(const int4*)&cAT8[((size_t)b * 1024 + ir * 32 + c) * 512 + ic0 + hf * 16];
      *(int4*)&Xs[entry * 48 + hf * 16] = val;
    }
    __syncthreads();

    #pragma unroll 1
    for (int ky = 0; ky < KS; ++ky) {
      #pragma unroll
      for (int kx = 0; kx < KS; ++kx) {
        const int tap = ky * KS + kx;
        I4LL a0, a1, bf0, bf1;
        a0.v = *(const int4*)&wf[((((size_t)tap * 16 + cc) * 2 + kg) * 128 + oc0 + col) * 16];
        a1.v = *(const int4*)&wf[((((size_t)tap * 16 + cc) * 2 + kg) * 128 + oc0 + 32 + col) * 16];
        bf0.v = *(const int4*)&Xs[((wv * 2 + 0 + ky) * PCX + col + kx) * 48 + kg * 16];
        bf1.v = *(const int4*)&Xs[((wv * 2 + 1 + ky) * PCX + col + kx) * 48 + kg * 16];
        acc[0][0] = __builtin_amdgcn_mfma_f32_32x32x16_fp8_fp8(a0.l[0], bf0.l[0], acc[0][0], 0, 0, 0);
        acc[1][0] = __builtin_amdgcn_mfma_f32_32x32x16_fp8_fp8(a1.l[0], bf0.l[0], acc[1][0], 0, 0, 0);
        acc[0][1] = __builtin_amdgcn_mfma_f32_32x32x16_fp8_fp8(a0.l[0], bf1.l[0], acc[0][1], 0, 0, 0);
        acc[1][1] = __builtin_amdgcn_mfma_f32_32x32x16_fp8_fp8(a1.l[0], bf1.l[0], acc[1][1], 0, 0, 0);
        acc[0][0] = __builtin_amdgcn_mfma_f32_32x32x16_fp8_fp8(a0.l[1], bf0.l[1], acc[0][0], 0, 0, 0);
        acc[1][0] = __builtin_amdgcn_mfma_f32_32x32x16_fp8_fp8(a1.l[1], bf0.l[1], acc[1][0], 0, 0, 0);
        acc[0][1] = __builtin_amdgcn_mfma_f32_32x32x16_fp8_fp8(a0.l[1], bf1.l[1], acc[0][1], 0, 0, 0);
        acc[1][1] = __builtin_amdgcn_mfma_f32_32x32x16_fp8_fp8(a1.l[1], bf1.l[1], acc[1][1], 0, 0, 0);
      }
    }
    __syncthreads();
  }

  float lsum = 0.f, lsq = 0.f;
  #pragma unroll
  for (int ob = 0; ob < 2; ++ob)
    #pragma unroll
    for (int rr = 0; rr < 2; ++rr) {
      const int row = r0 + wv * 2 + rr;
      #pragma unroll
      for (int r = 0; r < 16; ++r) {
        const int oc = oc0 + ob * 32 + (r & 3) + 8 * (r >> 2) + 4 * kg;
        float v = acc[ob][rr][r] * (1.0f / 4096.0f);
        xout[((size_t)b * 128 + oc) * 1024 + row * 32 + col] = __float2bfloat16(v);
        lsum += v; lsq += v * v;
      }
    }
  rs[tid] = lsum; rq[tid] = lsq;
  __syncthreads();
  for (int s = 128; s > 0; s >>= 1) {
    if (tid < s) { rs[tid] += rs[tid + s]; rq[tid] += rq[tid + s]; }
    __syncthreads();
  }
  if (tid == 0) {
    partials[((size_t)b * 8 + tix) * 2]     = rs[0];
    partials[((size_t)b * 8 + tix) * 2 + 1] = rq[0];
  }
}

// ---------------------------------------------------------------- LN + combine
__global__ __launch_bounds__(256) void final_kernel(
    const bf16* __restrict__ x3, const bf16* __restrict__ x5,
    const bf16* __restrict__ x7, const bf16* __restrict__ x1c,
    const float* __restrict__ p3, const float* __restrict__ p5,
    const float* __restrict__ p7, const float* __restrict__ p1,
    const float* __restrict__ g3, const float* __restrict__ be3,
    const float* __restrict__ g5, const float* __restrict__ be5,
    const float* __restrict__ g7, const float* __restrict__ be7,
    const float* __restrict__ g1, const float* __restrict__ be1,
    float* __restrict__ out)
{
  const int blk = blockIdx.x, b = blockIdx.y, tid = threadIdx.x;
  float s3 = 0, q3 = 0, s5 = 0, q5 = 0, s7 = 0, q7 = 0, s1 = 0, q1 = 0;
  #pragma unroll
  for (int i = 0; i < 8; ++i) {
    int o = (b * 8 + i) * 2;
    s3 += p3[o]; q3 += p3[o + 1];
    s5 += p5[o]; q5 += p5[o + 1];
    s7 += p7[o]; q7 += p7[o + 1];
  }
  #pragma unroll
  for (int i = 0; i < 4; ++i) {
    int o = (b * 4 + i) * 2;
    s1 += p1[o]; q1 += p1[o + 1];
  }
  const float inv = 1.0f / 131072.0f;
  float mu3 = s3 * inv, r3 = rsqrtf(fmaxf(q3 * inv - mu3 * mu3, 0.f) + 1e-5f);
  float mu5 = s5 * inv, r5 = rsqrtf(fmaxf(q5 * inv - mu5 * mu5, 0.f) + 1e-5f);
  float mu7 = s7 * inv, r7 = rsqrtf(fmaxf(q7 * inv - mu7 * mu7, 0.f) + 1e-5f);
  float mu1 = s1 * inv, r1 = rsqrtf(fmaxf(q1 * inv - mu1 * mu1, 0.f) + 1e-5f);
  const size_t bb = (size_t)b * 131072;
  for (int it = 0; it < 8; ++it) {
    int e0 = (it * 2048 + blk * 256 + tid) * 8;
    BF8 a3, a5, a7, a1;
    a3.v = *(const int4*)&x3[bb + e0];
    a5.v = *(const int4*)&x5[bb + e0];
    a7.v = *(const int4*)&x7[bb + e0];
    a1.v = *(const int4*)&x1c[bb + e0];
    float G3[8], B3[8], G5[8], B5[8], G7[8], B7[8], G1[8], B1[8];
    *(float4*)&G3[0] = *(const float4*)&g3[e0];  *(float4*)&G3[4] = *(const float4*)&g3[e0 + 4];
    *(float4*)&B3[0] = *(const float4*)&be3[e0]; *(float4*)&B3[4] = *(const float4*)&be3[e0 + 4];
    *(float4*)&G5[0] = *(const float4*)&g5[e0];  *(float4*)&G5[4] = *(const float4*)&g5[e0 + 4];
    *(float4*)&B5[0] = *(const float4*)&be5[e0]; *(float4*)&B5[4] = *(const float4*)&be5[e0 + 4];
    *(float4*)&G7[0] = *(const float4*)&g7[e0];  *(float4*)&G7[4] = *(const float4*)&g7[e0 + 4];
    *(float4*)&B7[0] = *(const float4*)&be7[e0]; *(float4*)&B7[4] = *(const float4*)&be7[e0 + 4];
    *(float4*)&G1[0] = *(const float4*)&g1[e0];  *(float4*)&G1[4] = *(const float4*)&g1[e0 + 4];
    *(float4*)&B1[0] = *(const float4*)&be1[e0]; *(float4*)&B1[4] = *(const float4*)&be1[e0 + 4];
    float res[8];
    #pragma unroll
    for (int j = 0; j < 8; ++j) {
      float v3 = (__bfloat162float(a3.h[j]) - mu3) * r3 * G3[j] + B3[j];
      float v5 = (__bfloat162float(a5.h[j]) - mu5) * r5 * G5[j] + B5[j];
      float v7 = (__bfloat162float(a7.h[j]) - mu7) * r7 * G7[j] + B7[j];
      float m = (v3 + v5 + v7) * (1.0f / 3.0f);
      float sg = 1.0f / (1.0f + __expf(-m));
      float v1 = (__bfloat162float(a1.h[j]) - mu1) * r1 * G1[j] + B1[j];
      res[j] = sg + v1;
    }
    *(float4*)&out[bb + e0]     = make_float4(res[0], res[1], res[2], res[3]);
    *(float4*)&out[bb + e0 + 4] = make_float4(res[4], res[5], res[6], res[7]);
  }
}

// ---------------------------------------------------------------- launch
extern "C" void kernel_launch(void* const* d_in, const int* in_sizes, int n_in,
                              void* d_out, int out_size, void* d_ws, size_t ws_size,
                              hipStream_t stream)
{
  (void)in_sizes; (void)n_in; (void)out_size; (void)ws_size;
  const float* st     = (const float*)d_in[0];
  const float* phy    = (const float*)d_in[1];
  const float* wq_st  = (const float*)d_in[2];
  const float* bq_st  = (const float*)d_in[3];
  const float* wk_st  = (const float*)d_in[4];
  const float* bk_st  = (const float*)d_in[5];
  const float* wv_st  = (const float*)d_in[6];
  const float* bv_st  = (const float*)d_in[7];
  const float* wq_phy = (const float*)d_in[8];
  const float* bq_phy = (const float*)d_in[9];
  const float* wk_phy = (const float*)d_in[10];
  const float* bk_phy = (const float*)d_in[11];
  const float* wv_phy = (const float*)d_in[12];
  const float* bv_phy = (const float*)d_in[13];
  const float* w3  = (const float*)d_in[14];
  const float* g3  = (const float*)d_in[15];
  const float* be3 = (const float*)d_in[16];
  const float* w5  = (const float*)d_in[17];
  const float* g5  = (const float*)d_in[18];
  const float* be5 = (const float*)d_in[19];
  const float* w7  = (const float*)d_in[20];
  const float* g7  = (const float*)d_in[21];
  const float* be7 = (const float*)d_in[22];
  const float* w1  = (const float*)d_in[23];
  const float* g1  = (const float*)d_in[24];
  const float* be1 = (const float*)d_in[25];
  const float* b1  = (const float*)d_in[26];

  char* ws = (char*)d_ws;
  // phase A
  bf16* Xt        = (bf16*)ws;
  bf16* projchunk = (bf16*)(ws + 67108864ULL);
  bf16* cA        = (bf16*)(ws + 117440512ULL);
  u8*   cB        = (u8*)(ws + 184549376ULL);
  bf16* wproj     = (bf16*)(ws + 218103808ULL);
  // phase B/C
  bf16* cAT       = (bf16*)ws;
  u8*   cBT       = (u8*)(ws + 67108864ULL);
  u8*   cAT8      = (u8*)(ws + 117440512ULL);     // over dead cA
  bf16* x1b       = (bf16*)(ws + 184549376ULL);   // over dead cB (conv1 first)
  bf16* x3b       = (bf16*)ws;                    // over dead cAT (after conv1)
  bf16* x5b       = (bf16*)(ws + 33554432ULL);
  bf16* x7b       = (bf16*)(ws + 67108864ULL);    // over dead cBT
  float* parts    = (float*)(ws + 234881024ULL);
  u8*   wf3       = (u8*)(ws + 234913792ULL);
  u8*   wf5       = (u8*)(ws + 236093440ULL);
  u8*   wf7       = (u8*)(ws + 239370240ULL);
  bf16* wb1       = (bf16*)(ws + 245792768ULL);

  prep_w_kernel<<<dim3(2048), 256, 0, stream>>>(w3, w5, w7, w1,
      wq_st, wk_st, wv_st, wq_phy, wk_phy, wv_phy,
      wf3, wf5, wf7, wb1, wproj);
  xpose_in_kernel<<<dim3(64, 128), 256, 0, stream>>>(st, phy, Xt);

  for (int g = 0; g < 4; ++g) {
    proj_mfma<<<dim3(8, 128), 256, 0, stream>>>(Xt, wproj,
        bq_st, bk_st, bv_st, bq_phy, bk_phy, bv_phy, projchunk, g * 32);
    attn_mfma_kernel<<<dim3(32, 128), 64, 0, stream>>>(projchunk, st, phy,
        cA, cB, g * 32);
  }
  transpose_kernel<<<dim3(128, 128), 256, 0, stream>>>(cA, cB, cAT, cBT);
  to_fp8_kernel<<<dim3(16384), 256, 0, stream>>>(cAT, cBT, cAT8);

  conv_mfma<1><<<dim3(512), 256, 0, stream>>>(cAT, cBT, wb1, b1, x1b, parts + 6144);
  conv_mfma8<3><<<dim3(1024), 256, 0, stream>>>(cAT8, wf3, x3b, parts);
  conv_mfma8<5><<<dim3(1024), 256, 0, stream>>>(cAT8, wf5, x5b, parts + 2048);
  conv_mfma8<7><<<dim3(1024), 256, 0, stream>>>(cAT8, wf7, x7b, parts + 4096);

  final_kernel<<<dim3(8, 128), 256, 0, stream>>>(x3b, x5b, x7b, x1b,
      parts, parts + 2048, parts + 4096, parts + 6144,
      g3, be3, g5, be5, g7, be7, g1, be1, (float*)d_out);
}

// Round 13
// 1233.437 us; speedup vs baseline: 2.4821x; 1.3298x over previous
//
#include <hip/hip_runtime.h>
#include <hip/hip_bf16.h>

typedef __hip_bfloat16 bf16;
typedef unsigned char u8;
typedef unsigned long long u64;
typedef __attribute__((ext_vector_type(8))) short short8;
typedef __attribute__((ext_vector_type(8))) int i32x8;
typedef __attribute__((ext_vector_type(16))) float f32x16;
#define DI __device__ __forceinline__

union BF8 { int4 v; short8 s; bf16 h[8]; };
union BF4 { u64 u; bf16 h[4]; };
union U32B { int4 v[2]; i32x8 w; };

// ws layout (bytes):
// phase A: Xt @0 | projchunk @67,108,864 | cA @117,440,512 | cB @184,549,376
//          wproj @218,103,808
// phase B: transpose -> cAT @0, cBT @67,108,864 | to_fp8 -> cAT8 @117,440,512
// phase C: conv1 -> x1 @184,549,376; conv3/5/7 (MX fp8) -> x3 @0,
//          x5 @33,554,432, x7 @67,108,864
// parts @234,881,024 (32 KB): conv3 @0, conv5 @+2048, conv7 @+4096, conv1 @+6144
// wf3 @234,913,792 | wf5 @236,093,440 | wf7 @239,370,240 | wb1 @245,792,768

DI u8 f32_fp8(float v) {
  return (u8)(__builtin_amdgcn_cvt_pk_fp8_f32(v, 0.f, 0, false) & 0xff);
}

// ---------------------------------------------------------------- weight prep
// MX layout for wf3/5/7 (x256): addr = (((tap*8+cc2)*2+g)*128+oc)*32 + o,
//   ic = (cc2*2+g)*32 + ((o>>3)&1)*16 + ((o>>4)&1)*8 + (o&7)   [matches cAT8]
__global__ __launch_bounds__(256) void prep_w_kernel(
    const float* __restrict__ w3, const float* __restrict__ w5,
    const float* __restrict__ w7, const float* __restrict__ w1,
    const float* __restrict__ wq_st, const float* __restrict__ wk_st,
    const float* __restrict__ wv_st, const float* __restrict__ wq_phy,
    const float* __restrict__ wk_phy, const float* __restrict__ wv_phy,
    u8* __restrict__ wf3, u8* __restrict__ wf5,
    u8* __restrict__ wf7, bf16* __restrict__ wb1, bf16* __restrict__ wp)
{
  const int N3 = 9 * 65536, N5 = 25 * 65536, N7 = 49 * 65536, N1 = 65536;
  const int NP = 6 * 16384;
  const int total = N3 + N5 + N7 + N1 + NP;
  for (int i = blockIdx.x * 256 + threadIdx.x; i < total; i += gridDim.x * 256) {
    if (i < N3 + N5 + N7) {
      const float* w; int k; int taps;
      u8* dst;
      if (i < N3)           { w = w3; k = i;            taps = 9;  dst = wf3; }
      else if (i < N3 + N5) { w = w5; k = i - N3;       taps = 25; dst = wf5; }
      else                  { w = w7; k = i - N3 - N5;  taps = 49; dst = wf7; }
      int tap = k >> 16, rem = k & 65535;
      int cc2 = rem >> 13, r2 = rem & 8191;
      int g = r2 >> 12, r3 = r2 & 4095;
      int oc = r3 >> 5, o = r3 & 31;
      int ic = (cc2 * 2 + g) * 32 + ((o >> 3) & 1) * 16 + ((o >> 4) & 1) * 8 + (o & 7);
      dst[k] = f32_fp8(w[(size_t)(oc * 512 + ic) * taps + tap] * 256.0f);
    } else if (i < N3 + N5 + N7 + N1) {
      int k = i - N3 - N5 - N7;
      int icg = k >> 10, oc = (k >> 3) & 127, j = k & 7;
      wb1[k] = __float2bfloat16(w1[(size_t)oc * 512 + icg * 8 + j]);
    } else {
      int k = i - N3 - N5 - N7 - N1;
      int m = k >> 14, r = k & 16383;
      float v;
      switch (m) {
        case 0: v = wq_st[r]; break;
        case 1: v = wk_st[r]; break;
        case 2: v = wv_st[r]; break;
        case 3: v = wq_phy[r]; break;
        case 4: v = wk_phy[r]; break;
        default: v = wv_phy[r]; break;
      }
      wp[k] = __float2bfloat16(v);
    }
  }
}

// ---------------------------------------------------------------- input transpose
__global__ __launch_bounds__(256) void xpose_in_kernel(
    const float* __restrict__ st, const float* __restrict__ phy,
    bf16* __restrict__ Xt)
{
  __shared__ __align__(16) short Tb[64 * 72];
  const int x = blockIdx.x, b = blockIdx.y;
  const int t = x >> 5, rem = x & 31;
  const int ict = rem >> 4, post = rem & 15;
  const int ic0 = ict * 64, pos0 = post * 64;
  const int tid = threadIdx.x;
  const int rowi = tid >> 2, sub = tid & 3;
  const float* X = t ? phy : st;

  const float* src = X + ((size_t)b * 128 + ic0 + rowi) * 1024 + pos0 + sub * 16;
  #pragma unroll
  for (int q = 0; q < 4; ++q) {
    float4 v = *(const float4*)(src + q * 4);
    BF4 pk;
    pk.h[0] = __float2bfloat16(v.x); pk.h[1] = __float2bfloat16(v.y);
    pk.h[2] = __float2bfloat16(v.z); pk.h[3] = __float2bfloat16(v.w);
    *(u64*)&Tb[rowi * 72 + sub * 16 + q * 4] = pk.u;
  }
  __syncthreads();
  short tmp[16];
  #pragma unroll
  for (int j = 0; j < 16; ++j) tmp[j] = Tb[(sub * 16 + j) * 72 + rowi];
  bf16* dst = Xt + (((size_t)t * 128 + b) * 1024 + pos0 + rowi) * 128 + ic0 + sub * 16;
  *(int4*)dst       = ((int4*)tmp)[0];
  *(int4*)(dst + 8) = ((int4*)tmp)[1];
}

// ---------------------------------------------------------------- MFMA projections
__global__ __launch_bounds__(256) void proj_mfma(
    const bf16* __restrict__ Xt, const bf16* __restrict__ wproj,
    const float* __restrict__ b0, const float* __restrict__ b1,
    const float* __restrict__ b2, const float* __restrict__ b3,
    const float* __restrict__ b4, const float* __restrict__ b5,
    bf16* __restrict__ pc, int cb)
{
  const int pt = blockIdx.x, b = blockIdx.y;
  const int tid = threadIdx.x, wave = tid >> 6, lane = tid & 63;
  const int col = lane & 31, kg = lane >> 5;
  const int pos = pt * 128 + wave * 32 + col;

  f32x16 acc[6];
  #pragma unroll
  for (int m = 0; m < 6; ++m)
    #pragma unroll
    for (int e = 0; e < 16; ++e) acc[m][e] = 0.f;

  const bf16* xst = Xt + ((size_t)b * 1024 + pos) * 128 + kg * 8;
  const bf16* xph = xst + (size_t)128 * 1024 * 128;
  const bf16* wl = wproj + (size_t)(cb + col) * 128 + kg * 8;

  #pragma unroll
  for (int kst = 0; kst < 8; ++kst) {
    short8 bst = *(const short8*)&xst[kst * 16];
    short8 bph = *(const short8*)&xph[kst * 16];
    #pragma unroll
    for (int m = 0; m < 6; ++m) {
      BF8 a; a.v = *(const int4*)&wl[(size_t)m * 16384 + kst * 16];
      acc[m] = __builtin_amdgcn_mfma_f32_32x32x16_bf16(a.s, m < 3 ? bst : bph, acc[m], 0, 0, 0);
    }
  }
  const float* biases[6] = { b0, b1, b2, b3, b4, b5 };
  #pragma unroll
  for (int m = 0; m < 6; ++m) {
    #pragma unroll
    for (int r = 0; r < 16; ++r) {
      const int ocl = (r & 3) + 8 * (r >> 2) + 4 * kg;
      float v = acc[m][r] + biases[m][cb + ocl];
      pc[(((size_t)m * 128 + b) * 32 + ocl) * 1024 + pos] = __float2bfloat16(v);
    }
  }
}

// ---------------------------------------------------------------- MFMA attention
DI void softmax_rows(float p[16])
{
  #pragma unroll
  for (int r = 0; r < 16; ++r) {
    float m = p[r];
    m = fmaxf(m, __shfl_xor(m, 1));
    m = fmaxf(m, __shfl_xor(m, 2));
    m = fmaxf(m, __shfl_xor(m, 4));
    m = fmaxf(m, __shfl_xor(m, 8));
    m = fmaxf(m, __shfl_xor(m, 16));
    float e = __expf(p[r] - m);
    float s = e;
    s += __shfl_xor(s, 1); s += __shfl_xor(s, 2); s += __shfl_xor(s, 4);
    s += __shfl_xor(s, 8); s += __shfl_xor(s, 16);
    p[r] = __fdividef(e, s);
  }
}

template<bool U8OUT>
DI void attn_one_mfma(const BF8& qa0, const BF8& qa1,
                      const bf16* __restrict__ KT, const bf16* __restrict__ VT,
                      bf16* __restrict__ P,
                      const float* __restrict__ resid, void* outp, int lane)
{
  const int col = lane & 31, kg = lane >> 5;
  f32x16 acc;
  #pragma unroll
  for (int e = 0; e < 16; ++e) acc[e] = 0.f;
  BF8 kb0, kb1;
  kb0.v = *(const int4*)&KT[col * 40 + kg * 8];
  kb1.v = *(const int4*)&KT[col * 40 + 16 + kg * 8];
  acc = __builtin_amdgcn_mfma_f32_32x32x16_bf16(qa0.s, kb0.s, acc, 0, 0, 0);
  acc = __builtin_amdgcn_mfma_f32_32x32x16_bf16(qa1.s, kb1.s, acc, 0, 0, 0);
  float p[16];
  #pragma unroll
  for (int r = 0; r < 16; ++r) p[r] = acc[r];
  softmax_rows(p);
  __syncthreads();
  #pragma unroll
  for (int r = 0; r < 16; ++r) {
    int row = (r & 3) + 8 * (r >> 2) + 4 * kg;
    P[row * 40 + col] = __float2bfloat16(p[r]);
  }
  __syncthreads();
  BF8 pa0, pa1, vb0, vb1;
  pa0.v = *(const int4*)&P[col * 40 + kg * 8];
  pa1.v = *(const int4*)&P[col * 40 + 16 + kg * 8];
  vb0.v = *(const int4*)&VT[col * 40 + kg * 8];
  vb1.v = *(const int4*)&VT[col * 40 + 16 + kg * 8];
  #pragma unroll
  for (int e = 0; e < 16; ++e) acc[e] = 0.f;
  acc = __builtin_amdgcn_mfma_f32_32x32x16_bf16(pa0.s, vb0.s, acc, 0, 0, 0);
  acc = __builtin_amdgcn_mfma_f32_32x32x16_bf16(pa1.s, vb1.s, acc, 0, 0, 0);
  #pragma unroll
  for (int r = 0; r < 16; ++r) p[r] = acc[r];
  softmax_rows(p);
  if constexpr (!U8OUT) {
    bf16* op = (bf16*)outp;
    #pragma unroll
    for (int r = 0; r < 16; ++r) {
      int row = (r & 3) + 8 * (r >> 2) + 4 * kg;
      int off = row * 32 + col;
      op[off] = __float2bfloat16(p[r] + resid[off]);
    }
  } else {
    u8* op = (u8*)outp;
    #pragma unroll
    for (int r = 0; r < 16; ++r) {
      int row = (r & 3) + 8 * (r >> 2) + 4 * kg;
      op[row * 32 + col] = (u8)fminf(p[r] * 256.f + 0.5f, 255.f);
    }
  }
}

__global__ __launch_bounds__(64) void attn_mfma_kernel(
    const bf16* __restrict__ pc,
    const float* __restrict__ st, const float* __restrict__ phy,
    bf16* __restrict__ cA, u8* __restrict__ cB, int cb)
{
  __shared__ __align__(16) bf16 KTst[32 * 40], VTst[32 * 40];
  __shared__ __align__(16) bf16 KTph[32 * 40], VTph[32 * 40];
  __shared__ __align__(16) bf16 P[32 * 40];
  const int cl = blockIdx.x, b = blockIdx.y;
  const int c = cb + cl;
  const int lane = threadIdx.x;
  const size_t mstride = (size_t)128 * 32 * 1024;
  const bf16* p0 = pc + ((size_t)b * 32 + cl) * 1024;
  const size_t bc = ((size_t)b * 128 + c) * 1024;

  {
    const int w = lane >> 1, k0 = (lane & 1) * 16;
    const int off = w * 32 + k0;
    bf16* dsts[4] = { KTst, VTst, KTph, VTph };
    const int ms[4] = { 1, 2, 4, 5 };
    #pragma unroll
    for (int t = 0; t < 4; ++t) {
      BF8 r0, r1;
      r0.v = *(const int4*)&p0[(size_t)ms[t] * mstride + off];
      r1.v = *(const int4*)&p0[(size_t)ms[t] * mstride + off + 8];
      #pragma unroll
      for (int j = 0; j < 8; ++j) {
        dsts[t][(k0 + j) * 40 + w]     = r0.h[j];
        dsts[t][(k0 + 8 + j) * 40 + w] = r1.h[j];
      }
    }
  }
  const int col = lane & 31, kg = lane >> 5;
  BF8 qst0, qst1, qph0, qph1;
  qst0.v = *(const int4*)&p0[col * 32 + kg * 8];
  qst1.v = *(const int4*)&p0[col * 32 + 16 + kg * 8];
  qph0.v = *(const int4*)&p0[3 * mstride + col * 32 + kg * 8];
  qph1.v = *(const int4*)&p0[3 * mstride + col * 32 + 16 + kg * 8];
  __syncthreads();

  bf16* aA = cA + (size_t)b * 256 * 1024 + (size_t)c * 1024;
  u8*   aB = cB + (size_t)b * 256 * 1024 + (size_t)c * 1024;
  attn_one_mfma<false>(qst0, qst1, KTst, VTst, P, st + bc,  aA,          lane);
  attn_one_mfma<false>(qph0, qph1, KTph, VTph, P, phy + bc, aA + 131072, lane);
  attn_one_mfma<true >(qph0, qph1, KTst, VTst, P, nullptr,  aB,          lane);
  attn_one_mfma<true >(qst0, qst1, KTph, VTph, P, nullptr,  aB + 131072, lane);
}

// ---------------------------------------------------------------- concat transpose
__global__ __launch_bounds__(256) void transpose_kernel(
    const bf16* __restrict__ cA, const u8* __restrict__ cB,
    bf16* __restrict__ cAT, u8* __restrict__ cBT)
{
  __shared__ __align__(16) short Tb[64 * 72];
  __shared__ __align__(16) u8 T8[64 * 80];
  const int x = blockIdx.x, b = blockIdx.y;
  const int cht = x >> 4, post = x & 15;
  const int pos0 = post * 64;
  const int tid = threadIdx.x;
  const int rowi = tid >> 2, sub = tid & 3;

  if (cht < 4) {
    const int ch0 = cht * 64;
    const bf16* src = cA + ((size_t)b * 256 + ch0 + rowi) * 1024 + pos0 + sub * 16;
    *(int4*)&Tb[rowi * 72 + sub * 16]     = *(const int4*)src;
    *(int4*)&Tb[rowi * 72 + sub * 16 + 8] = *(const int4*)(src + 8);
    __syncthreads();
    short tmp[16];
    #pragma unroll
    for (int j = 0; j < 16; ++j) tmp[j] = Tb[(sub * 16 + j) * 72 + rowi];
    bf16* dst = cAT + ((size_t)b * 1024 + pos0 + rowi) * 256 + ch0 + sub * 16;
    *(int4*)dst       = ((int4*)tmp)[0];
    *(int4*)(dst + 8) = ((int4*)tmp)[1];
  } else {
    const int ch0 = (cht - 4) * 64;
    const u8* src = cB + ((size_t)b * 256 + ch0 + rowi) * 1024 + pos0 + sub * 16;
    *(int4*)&T8[rowi * 80 + sub * 16] = *(const int4*)src;
    __syncthreads();
    u8 tmp[16];
    #pragma unroll
    for (int j = 0; j < 16; ++j) tmp[j] = T8[(sub * 16 + j) * 80 + rowi];
    u8* dst = cBT + ((size_t)b * 1024 + pos0 + rowi) * 256 + ch0 + sub * 16;
    *(int4*)dst = *(int4*)tmp;
  }
}

// ---------------------------------------------------------------- fp8 conversion pass
__global__ __launch_bounds__(256) void to_fp8_kernel(
    const bf16* __restrict__ cAT, const u8* __restrict__ cBT,
    u8* __restrict__ cAT8)
{
  const int idx = blockIdx.x * 256 + threadIdx.x;
  const int g = idx & 31;
  const size_t bp = (size_t)(idx >> 5);
  const int c0 = g * 16;
  float v[16];
  if (c0 < 256) {
    BF8 lo, hi;
    lo.v = *(const int4*)&cAT[bp * 256 + c0];
    hi.v = *(const int4*)&cAT[bp * 256 + c0 + 8];
    #pragma unroll
    for (int j = 0; j < 8; ++j) {
      v[j]     = __bfloat162float(lo.h[j]) * 16.0f;
      v[8 + j] = __bfloat162float(hi.h[j]) * 16.0f;
    }
  } else {
    u64 raw0 = *(const u64*)&cBT[bp * 256 + (c0 - 256)];
    u64 raw1 = *(const u64*)&cBT[bp * 256 + (c0 - 256) + 8];
    #pragma unroll
    for (int j = 0; j < 8; ++j) {
      v[j]     = (float)((raw0 >> (8 * j)) & 255u) * 0.0625f;
      v[8 + j] = (float)((raw1 >> (8 * j)) & 255u) * 0.0625f;
    }
  }
  unsigned lo0 = (__builtin_amdgcn_cvt_pk_fp8_f32(v[0], v[1], 0, false) & 0xffff)
               | ((__builtin_amdgcn_cvt_pk_fp8_f32(v[2], v[3], 0, false) & 0xffff) << 16);
  unsigned hi0 = (__builtin_amdgcn_cvt_pk_fp8_f32(v[4], v[5], 0, false) & 0xffff)
               | ((__builtin_amdgcn_cvt_pk_fp8_f32(v[6], v[7], 0, false) & 0xffff) << 16);
  unsigned lo1 = (__builtin_amdgcn_cvt_pk_fp8_f32(v[8], v[9], 0, false) & 0xffff)
               | ((__builtin_amdgcn_cvt_pk_fp8_f32(v[10], v[11], 0, false) & 0xffff) << 16);
  unsigned hi1 = (__builtin_amdgcn_cvt_pk_fp8_f32(v[12], v[13], 0, false) & 0xffff)
               | ((__builtin_amdgcn_cvt_pk_fp8_f32(v[14], v[15], 0, false) & 0xffff) << 16);
  u64 run0 = (u64)lo0 | ((u64)hi0 << 32);
  u64 run1 = (u64)lo1 | ((u64)hi1 << 32);
  const int sp = (c0 >> 4) & 1;
  u8* d = cAT8 + bp * 512 + (c0 & ~31);
  *(u64*)(d + 8 * sp)      = run0;
  *(u64*)(d + 16 + 8 * sp) = run1;
}

// ---------------------------------------------------------------- staging (bf16)
template<int PCX, int NIT, int H0>
DI void stage_tile(const bf16* cAT, const u8* cBT, short* Xs,
                   int b, int r0, int ic0, int tid)
{
  for (int e = tid; e < NIT; e += 256) {
    int i = e / (PCX * 4);
    int rem = e - i * (PCX * 4);
    int cx = rem >> 2, part = rem & 3;
    int ir = r0 - H0 + i, c = cx - H0;
    int4 val = make_int4(0, 0, 0, 0);
    if ((unsigned)ir < 32u && (unsigned)c < 32u) {
      size_t pbase = ((size_t)b * 1024 + ir * 32 + c) * 256;
      if (ic0 < 256) {
        val = *(const int4*)&cAT[pbase + ic0 + part * 8];
      } else {
        u64 u = *(const u64*)&cBT[pbase + (ic0 - 256) + part * 8];
        BF8 t;
        #pragma unroll
        for (int j = 0; j < 8; ++j)
          t.h[j] = __float2bfloat16((float)((u >> (8 * j)) & 255u) * 0.00390625f);
        val = t.v;
      }
    }
    *(int4*)&Xs[(i * PCX + cx) * 40 + part * 8] = val;
  }
}

// ---------------------------------------------------------------- bf16 MFMA conv (conv1)
template<int KS>
__global__ __launch_bounds__(256, 2) void conv_mfma(
    const bf16* __restrict__ cAT, const u8* __restrict__ cBT,
    const bf16* __restrict__ wt, const float* __restrict__ bias,
    bf16* __restrict__ xout, float* __restrict__ partials)
{
  constexpr int H0 = KS / 2;
  constexpr int PCX = 32 + 2 * H0;
  constexpr int ROWS = 16 + 2 * H0;
  constexpr int NIT = ROWS * PCX * 4;
  __shared__ __align__(16) short Xs[ROWS * PCX * 40];
  __shared__ float rs[256], rq[256];
  const int h = blockIdx.x;
  const int logical = (h & 7) * 64 + (h >> 3);
  const int b = logical >> 2, tix = logical & 3;
  const int ot = tix >> 1, rt = tix & 1;
  const int oc0 = ot * 64, r0 = rt * 16;
  const int tid = threadIdx.x;
  const int wv = tid >> 6, lane = tid & 63;
  const int col = lane & 31, kg = lane >> 5;

  f32x16 acc[2][4];
  #pragma unroll
  for (int i = 0; i < 2; ++i)
    #pragma unroll
    for (int j = 0; j < 4; ++j)
      #pragma unroll
      for (int e = 0; e < 16; ++e) acc[i][j][e] = 0.f;

  for (int cc = 0; cc < 16; ++cc) {
    const int ic0 = cc * 32;
    stage_tile<PCX, NIT, H0>(cAT, cBT, Xs, b, r0, ic0, tid);
    __syncthreads();

    #pragma unroll 1
    for (int ky = 0; ky < KS; ++ky) {
      #pragma unroll
      for (int kx = 0; kx < KS; ++kx) {
        const int tap = ky * KS + kx;
        BF8 a[2][2];
        #pragma unroll
        for (int ob = 0; ob < 2; ++ob)
          #pragma unroll
          for (int kt = 0; kt < 2; ++kt) {
            int icg = cc * 4 + kt * 2 + kg;
            a[ob][kt].v = *(const int4*)&wt[(((size_t)tap * 64 + icg) * 128 + oc0 + ob * 32 + col) * 8];
          }
        #pragma unroll
        for (int rr = 0; rr < 4; ++rr) {
          int entry = ((wv * 4 + rr + ky) * PCX + col + kx) * 40;
          #pragma unroll
          for (int kt = 0; kt < 2; ++kt) {
            short8 bf = *(const short8*)&Xs[entry + (kt * 2 + kg) * 8];
            acc[0][rr] = __builtin_amdgcn_mfma_f32_32x32x16_bf16(a[0][kt].s, bf, acc[0][rr], 0, 0, 0);
            acc[1][rr] = __builtin_amdgcn_mfma_f32_32x32x16_bf16(a[1][kt].s, bf, acc[1][rr], 0, 0, 0);
          }
        }
      }
    }
    __syncthreads();
  }

  float lsum = 0.f, lsq = 0.f;
  #pragma unroll
  for (int ob = 0; ob < 2; ++ob)
    #pragma unroll
    for (int rr = 0; rr < 4; ++rr) {
      const int row = r0 + wv * 4 + rr;
      #pragma unroll
      for (int r = 0; r < 16; ++r) {
        const int oc = oc0 + ob * 32 + (r & 3) + 8 * (r >> 2) + 4 * kg;
        float v = acc[ob][rr][r];
        if (bias) v += bias[oc];
        xout[((size_t)b * 128 + oc) * 1024 + row * 32 + col] = __float2bfloat16(v);
        lsum += v; lsq += v * v;
      }
    }
  rs[tid] = lsum; rq[tid] = lsq;
  __syncthreads();
  for (int s = 128; s > 0; s >>= 1) {
    if (tid < s) { rs[tid] += rs[tid + s]; rq[tid] += rq[tid + s]; }
    __syncthreads();
  }
  if (tid == 0) {
    partials[((size_t)b * 4 + tix) * 2]     = rs[0];
    partials[((size_t)b * 4 + tix) * 2 + 1] = rq[0];
  }
}

// ---------------------------------------------------------------- MX fp8 conv (KS=3,5,7)
// K=64 block-scaled MFMA (scale=1.0), 2.14x the non-scaled fp8 rate.
// ob=2 x rr=4, 16-row tiles, grid 512 XCD-swizzled, 2 blocks/CU.
// LDS entry = 64 B data + 16 pad (80 B stride, R5-proven conflict pattern).
// Per tap/CU: MFMA ~1100 cy > A-L1 ~512 > B-LDS ~512 -> MFMA-dominant.
template<int KS>
__global__ __launch_bounds__(256, 2) void conv_mx(
    const u8* __restrict__ cAT8, const u8* __restrict__ wf,
    bf16* __restrict__ xout, float* __restrict__ partials)
{
  constexpr int H0 = KS / 2;
  constexpr int PCX = 32 + 2 * H0;
  constexpr int ROWS = 16 + 2 * H0;
  constexpr int NIT = ROWS * PCX * 4;              // 16-B units
  __shared__ __align__(16) u8 Xs[ROWS * PCX * 80];
  __shared__ float rs[256], rq[256];
  const int h = blockIdx.x;
  const int logical = (h & 7) * 64 + (h >> 3);
  const int b = logical >> 2, tix = logical & 3;
  const int ot = tix >> 1, rt = tix & 1;
  const int oc0 = ot * 64, r0 = rt * 16;
  const int tid = threadIdx.x;
  const int wv = tid >> 6, lane = tid & 63;
  const int col = lane & 31, g = lane >> 5;

  f32x16 acc[2][4];
  #pragma unroll
  for (int i = 0; i < 2; ++i)
    #pragma unroll
    for (int j = 0; j < 4; ++j)
      #pragma unroll
      for (int e = 0; e < 16; ++e) acc[i][j][e] = 0.f;

  for (int cc2 = 0; cc2 < 8; ++cc2) {
    for (int e = tid; e < NIT; e += 256) {
      int entry = e >> 2, hf = e & 3;
      int i = entry / PCX, cx = entry - i * PCX;
      int ir = r0 - H0 + i, c = cx - H0;
      int4 val = make_int4(0, 0, 0, 0);
      if ((unsigned)ir < 32u && (unsigned)c < 32u)
        val = *(const int4*)&cAT8[((size_t)b * 1024 + ir * 32 + c) * 512 + cc2 * 64 + hf * 16];
      *(int4*)&Xs[entry * 80 + hf * 16] = val;
    }
    __syncthreads();

    #pragma unroll 1
    for (int ky = 0; ky < KS; ++ky) {
      #pragma unroll
      for (int kx = 0; kx < KS; ++kx) {
        const int tap = ky * KS + kx;
        const size_t wbase = (((size_t)tap * 8 + cc2) * 2 + g) * 128;
        U32B a0, a1;
        a0.v[0] = *(const int4*)&wf[(wbase + oc0 + col) * 32];
        a0.v[1] = *(const int4*)&wf[(wbase + oc0 + col) * 32 + 16];
        a1.v[0] = *(const int4*)&wf[(wbase + oc0 + 32 + col) * 32];
        a1.v[1] = *(const int4*)&wf[(wbase + oc0 + 32 + col) * 32 + 16];
        #pragma unroll
        for (int rr = 0; rr < 4; ++rr) {
          const int ebase = ((wv * 4 + rr + ky) * PCX + col + kx) * 80 + g * 32;
          U32B bf;
          bf.v[0] = *(const int4*)&Xs[ebase];
          bf.v[1] = *(const int4*)&Xs[ebase + 16];
          acc[0][rr] = __builtin_amdgcn_mfma_scale_f32_32x32x64_f8f6f4(
              a0.w, bf.w, acc[0][rr], 0, 0, 0, 0x7f7f7f7f, 0, 0x7f7f7f7f);
          acc[1][rr] = __builtin_amdgcn_mfma_scale_f32_32x32x64_f8f6f4(
              a1.w, bf.w, acc[1][rr], 0, 0, 0, 0x7f7f7f7f, 0, 0x7f7f7f7f);
        }
      }
    }
    __syncthreads();
  }

  float lsum = 0.f, lsq = 0.f;
  #pragma unroll
  for (int ob = 0; ob < 2; ++ob)
    #pragma unroll
    for (int rr = 0; rr < 4; ++rr) {
      const int row = r0 + wv * 4 + rr;
      #pragma unroll
      for (int r = 0; r < 16; ++r) {
        const int oc = oc0 + ob * 32 + (r & 3) + 8 * (r >> 2) + 4 * g;
        float v = acc[ob][rr][r] * (1.0f / 4096.0f);
        xout[((size_t)b * 128 + oc) * 1024 + row * 32 + col] = __float2bfloat16(v);
        lsum += v; lsq += v * v;
      }
    }
  rs[tid] = lsum; rq[tid] = lsq;
  __syncthreads();
  for (int s = 128; s > 0; s >>= 1) {
    if (tid < s) { rs[tid] += rs[tid + s]; rq[tid] += rq[tid + s]; }
    __syncthreads();
  }
  if (tid == 0) {
    partials[((size_t)b * 4 + tix) * 2]     = rs[0];
    partials[((size_t)b * 4 + tix) * 2 + 1] = rq[0];
  }
}

// ---------------------------------------------------------------- LN + combine (4 partials each)
__global__ __launch_bounds__(256) void final_kernel(
    const bf16* __restrict__ x3, const bf16* __restrict__ x5,
    const bf16* __restrict__ x7, const bf16* __restrict__ x1c,
    const float* __restrict__ p3, const float* __restrict__ p5,
    const float* __restrict__ p7, const float* __restrict__ p1,
    const float* __restrict__ g3, const float* __restrict__ be3,
    const float* __restrict__ g5, const float* __restrict__ be5,
    const float* __restrict__ g7, const float* __restrict__ be7,
    const float* __restrict__ g1, const float* __restrict__ be1,
    float* __restrict__ out)
{
  const int blk = blockIdx.x, b = blockIdx.y, tid = threadIdx.x;
  float s3 = 0, q3 = 0, s5 = 0, q5 = 0, s7 = 0, q7 = 0, s1 = 0, q1 = 0;
  #pragma unroll
  for (int i = 0; i < 4; ++i) {
    int o = (b * 4 + i) * 2;
    s3 += p3[o]; q3 += p3[o + 1];
    s5 += p5[o]; q5 += p5[o + 1];
    s7 += p7[o]; q7 += p7[o + 1];
    s1 += p1[o]; q1 += p1[o + 1];
  }
  const float inv = 1.0f / 131072.0f;
  float mu3 = s3 * inv, r3 = rsqrtf(fmaxf(q3 * inv - mu3 * mu3, 0.f) + 1e-5f);
  float mu5 = s5 * inv, r5 = rsqrtf(fmaxf(q5 * inv - mu5 * mu5, 0.f) + 1e-5f);
  float mu7 = s7 * inv, r7 = rsqrtf(fmaxf(q7 * inv - mu7 * mu7, 0.f) + 1e-5f);
  float mu1 = s1 * inv, r1 = rsqrtf(fmaxf(q1 * inv - mu1 * mu1, 0.f) + 1e-5f);
  const size_t bb = (size_t)b * 131072;
  for (int it = 0; it < 8; ++it) {
    int e0 = (it * 2048 + blk * 256 + tid) * 8;
    BF8 a3, a5, a7, a1;
    a3.v = *(const int4*)&x3[bb + e0];
    a5.v = *(const int4*)&x5[bb + e0];
    a7.v = *(const int4*)&x7[bb + e0];
    a1.v = *(const int4*)&x1c[bb + e0];
    float G3[8], B3[8], G5[8], B5[8], G7[8], B7[8], G1[8], B1[8];
    *(float4*)&G3[0] = *(const float4*)&g3[e0];  *(float4*)&G3[4] = *(const float4*)&g3[e0 + 4];
    *(float4*)&B3[0] = *(const float4*)&be3[e0]; *(float4*)&B3[4] = *(const float4*)&be3[e0 + 4];
    *(float4*)&G5[0] = *(const float4*)&g5[e0];  *(float4*)&G5[4] = *(const float4*)&g5[e0 + 4];
    *(float4*)&B5[0] = *(const float4*)&be5[e0]; *(float4*)&B5[4] = *(const float4*)&be5[e0 + 4];
    *(float4*)&G7[0] = *(const float4*)&g7[e0];  *(float4*)&G7[4] = *(const float4*)&g7[e0 + 4];
    *(float4*)&B7[0] = *(const float4*)&be7[e0]; *(float4*)&B7[4] = *(const float4*)&be7[e0 + 4];
    *(float4*)&G1[0] = *(const float4*)&g1[e0];  *(float4*)&G1[4] = *(const float4*)&g1[e0 + 4];
    *(float4*)&B1[0] = *(const float4*)&be1[e0]; *(float4*)&B1[4] = *(const float4*)&be1[e0 + 4];
    float res[8];
    #pragma unroll
    for (int j = 0; j < 8; ++j) {
      float v3 = (__bfloat162float(a3.h[j]) - mu3) * r3 * G3[j] + B3[j];
      float v5 = (__bfloat162float(a5.h[j]) - mu5) * r5 * G5[j] + B5[j];
      float v7 = (__bfloat162float(a7.h[j]) - mu7) * r7 * G7[j] + B7[j];
      float m = (v3 + v5 + v7) * (1.0f / 3.0f);
      float sg = 1.0f / (1.0f + __expf(-m));
      float v1 = (__bfloat162float(a1.h[j]) - mu1) * r1 * G1[j] + B1[j];
      res[j] = sg + v1;
    }
    *(float4*)&out[bb + e0]     = make_float4(res[0], res[1], res[2], res[3]);
    *(float4*)&out[bb + e0 + 4] = make_float4(res[4], res[5], res[6], res[7]);
  }
}

// ---------------------------------------------------------------- launch
extern "C" void kernel_launch(void* const* d_in, const int* in_sizes, int n_in,
                              void* d_out, int out_size, void* d_ws, size_t ws_size,
                              hipStream_t stream)
{
  (void)in_sizes; (void)n_in; (void)out_size; (void)ws_size;
  const float* st     = (const float*)d_in[0];
  const float* phy    = (const float*)d_in[1];
  const float* wq_st  = (const float*)d_in[2];
  const float* bq_st  = (const float*)d_in[3];
  const float* wk_st  = (const float*)d_in[4];
  const float* bk_st  = (const float*)d_in[5];
  const float* wv_st  = (const float*)d_in[6];
  const float* bv_st  = (const float*)d_in[7];
  const float* wq_phy = (const float*)d_in[8];
  const float* bq_phy = (const float*)d_in[9];
  const float* wk_phy = (const float*)d_in[10];
  const float* bk_phy = (const float*)d_in[11];
  const float* wv_phy = (const float*)d_in[12];
  const float* bv_phy = (const float*)d_in[13];
  const float* w3  = (const float*)d_in[14];
  const float* g3  = (const float*)d_in[15];
  const float* be3 = (const float*)d_in[16];
  const float* w5  = (const float*)d_in[17];
  const float* g5  = (const float*)d_in[18];
  const float* be5 = (const float*)d_in[19];
  const float* w7  = (const float*)d_in[20];
  const float* g7  = (const float*)d_in[21];
  const float* be7 = (const float*)d_in[22];
  const float* w1  = (const float*)d_in[23];
  const float* g1  = (const float*)d_in[24];
  const float* be1 = (const float*)d_in[25];
  const float* b1  = (const float*)d_in[26];

  char* ws = (char*)d_ws;
  // phase A
  bf16* Xt        = (bf16*)ws;
  bf16* projchunk = (bf16*)(ws + 67108864ULL);
  bf16* cA        = (bf16*)(ws + 117440512ULL);
  u8*   cB        = (u8*)(ws + 184549376ULL);
  bf16* wproj     = (bf16*)(ws + 218103808ULL);
  // phase B/C
  bf16* cAT       = (bf16*)ws;
  u8*   cBT       = (u8*)(ws + 67108864ULL);
  u8*   cAT8      = (u8*)(ws + 117440512ULL);
  bf16* x1b       = (bf16*)(ws + 184549376ULL);
  bf16* x3b       = (bf16*)ws;
  bf16* x5b       = (bf16*)(ws + 33554432ULL);
  bf16* x7b       = (bf16*)(ws + 67108864ULL);
  float* parts    = (float*)(ws + 234881024ULL);
  u8*   wf3       = (u8*)(ws + 234913792ULL);
  u8*   wf5       = (u8*)(ws + 236093440ULL);
  u8*   wf7       = (u8*)(ws + 239370240ULL);
  bf16* wb1       = (bf16*)(ws + 245792768ULL);

  prep_w_kernel<<<dim3(2048), 256, 0, stream>>>(w3, w5, w7, w1,
      wq_st, wk_st, wv_st, wq_phy, wk_phy, wv_phy,
      wf3, wf5, wf7, wb1, wproj);
  xpose_in_kernel<<<dim3(64, 128), 256, 0, stream>>>(st, phy, Xt);

  for (int g = 0; g < 4; ++g) {
    proj_mfma<<<dim3(8, 128), 256, 0, stream>>>(Xt, wproj,
        bq_st, bk_st, bv_st, bq_phy, bk_phy, bv_phy, projchunk, g * 32);
    attn_mfma_kernel<<<dim3(32, 128), 64, 0, stream>>>(projchunk, st, phy,
        cA, cB, g * 32);
  }
  transpose_kernel<<<dim3(128, 128), 256, 0, stream>>>(cA, cB, cAT, cBT);
  to_fp8_kernel<<<dim3(16384), 256, 0, stream>>>(cAT, cBT, cAT8);

  conv_mfma<1><<<dim3(512), 256, 0, stream>>>(cAT, cBT, wb1, b1, x1b, parts + 6144);
  conv_mx<3><<<dim3(512), 256, 0, stream>>>(cAT8, wf3, x3b, parts);
  conv_mx<5><<<dim3(512), 256, 0, stream>>>(cAT8, wf5, x5b, parts + 2048);
  conv_mx<7><<<dim3(512), 256, 0, stream>>>(cAT8, wf7, x7b, parts + 4096);

  final_kernel<<<dim3(8, 128), 256, 0, stream>>>(x3b, x5b, x7b, x1b,
      parts, parts + 2048, parts + 4096, parts + 6144,
      g3, be3, g5, be5, g7, be7, g1, be1, (float*)d_out);
}